// Round 8
// baseline (315.911 us; speedup 1.0000x reference)
//
#include <hip/hip_runtime.h>
#include <cstdint>

// Problem constants: L=S=1024, N=4, E=1024, H=16, D=64
typedef __bf16 bf16x8 __attribute__((ext_vector_type(8)));
typedef float f32x4 __attribute__((ext_vector_type(4)));

// ws layout (float-unit offsets):
static const size_t OFF_QW2BF = 0;         // [k*64+i][j] bf16 (1M ushort)
static const size_t OFF_KWBF  = 524288;    // [o][j] bf16
static const size_t OFF_VWBF  = 1048576;   // [o][j] bf16
static const size_t OFF_OWTBF = 1572864;   // [o][j] bf16 (out_w^T)
static const size_t OFF_QB2   = 2097152;   // 1024 f32
static const size_t OFF_QWBF  = 2098176;   // [n][k][l][i] bf16 (4M ushort)
static const size_t OFF_KHBF  = 4195328;   // [n][k][s][i] bf16
static const size_t OFF_VTBF  = 6292480;   // [n][k][i][s] bf16 (V^T per head)
static const size_t OFF_ST    = 8389632;   // [n][k][l][{m,Z}] f32 131072
static const size_t OFF_OBF   = 8520704;   // [l*4+n][e] bf16 (4M ushort)
static const size_t OFF_ABF   = 10617856;  // [3][4096][1024] bf16 (12M ushort)

__device__ inline unsigned short f2bf(float f) {
  union { float f; unsigned u; } v; v.f = f;
  const unsigned r = v.u + 0x7FFFu + ((v.u >> 16) & 1u);   // RNE
  return (unsigned short)(r >> 16);
}

// ---------------------------------------------------------------------------
// K0: fold attn_W into q_w (bf16 out): qw2[(k,i),j] = sum_o q_w[o*16+k,j]*attn_W[o,i,k]/32
__global__ __launch_bounds__(256) void k_qw2(const float* __restrict__ qw,
    const float* __restrict__ attnW, const float* __restrict__ bias0,
    unsigned short* __restrict__ qw2, float* __restrict__ qb2) {
  const int b = blockIdx.x;          // = k*64 + i
  const int k = b >> 6, i = b & 63;
  const int tid = threadIdx.x;
  __shared__ float aw[64];
  if (tid < 64) aw[tid] = attnW[(tid * 64 + i) * 16 + k] * 0.03125f; // fold 1/sqrt(E)
  __syncthreads();
  for (int j = tid; j < 1024; j += 256) {
    float acc = 0.f;
#pragma unroll 8
    for (int o = 0; o < 64; ++o) acc = fmaf(qw[(o * 16 + k) * 1024 + j], aw[o], acc);
    qw2[(size_t)b * 1024 + j] = f2bf(acc);
  }
  if (tid == 0) {
    float acc = 0.f;
    for (int o = 0; o < 64; ++o) acc = fmaf(bias0[o * 16 + k], aw[o], acc);
    qb2[b] = acc;
  }
}

// ---------------------------------------------------------------------------
// Convert k_w and v_w to bf16 (row layout preserved: [o][j])
__global__ __launch_bounds__(256) void k_cvt2(const float* __restrict__ a,
    const float* __restrict__ b, unsigned short* __restrict__ oa,
    unsigned short* __restrict__ ob) {
  const int i = blockIdx.x * 256 + threadIdx.x;
  const float4 va = ((const float4*)a)[i];
  ushort4 ha; ha.x = f2bf(va.x); ha.y = f2bf(va.y); ha.z = f2bf(va.z); ha.w = f2bf(va.w);
  ((ushort4*)oa)[i] = ha;
  const float4 vb = ((const float4*)b)[i];
  ushort4 hb; hb.x = f2bf(vb.x); hb.y = f2bf(vb.y); hb.z = f2bf(vb.z); hb.w = f2bf(vb.w);
  ((ushort4*)ob)[i] = hb;
}

// ---------------------------------------------------------------------------
// Convert Q,K,V activations to bf16: Abf[m][4096][1024], m in {0,1,2}
__global__ __launch_bounds__(256) void k_cvtA(const float* __restrict__ Q,
    const float* __restrict__ K, const float* __restrict__ V,
    unsigned short* __restrict__ out) {
  const int b = blockIdx.x;                 // 0..3071
  const int m = b >> 10;
  const float* src = m == 0 ? Q : (m == 1 ? K : V);
  unsigned short* dst = out + (size_t)m * 4194304;
#pragma unroll
  for (int q = 0; q < 4; ++q) {
    const int idx = (b & 1023) * 1024 + q * 256 + threadIdx.x;
    const float4 v = ((const float4*)src)[idx];
    ushort4 h; h.x = f2bf(v.x); h.y = f2bf(v.y); h.z = f2bf(v.z); h.w = f2bf(v.w);
    ((ushort4*)dst)[idx] = h;
  }
}

// ---------------------------------------------------------------------------
// Transpose out_w [j][o] -> owT [o][j] bf16
__global__ __launch_bounds__(256) void k_tr(const float* __restrict__ w,
    unsigned short* __restrict__ wt) {
  __shared__ float t[64][65];
  const int j0 = blockIdx.y * 64, o0 = blockIdx.x * 64;
  const int tid = threadIdx.x;
  const int r = tid >> 4, c4 = tid & 15;
#pragma unroll
  for (int q = 0; q < 4; ++q) {
    const int row = r + q * 16;
    const float4 v = *(const float4*)&w[(size_t)(j0 + row) * 1024 + o0 + c4 * 4];
    t[row][c4 * 4 + 0] = v.x; t[row][c4 * 4 + 1] = v.y;
    t[row][c4 * 4 + 2] = v.z; t[row][c4 * 4 + 3] = v.w;
  }
  __syncthreads();
#pragma unroll
  for (int q = 0; q < 4; ++q) {
    const int orow = r + q * 16;
    ushort4 h;
    h.x = f2bf(t[c4 * 4 + 0][orow]); h.y = f2bf(t[c4 * 4 + 1][orow]);
    h.z = f2bf(t[c4 * 4 + 2][orow]); h.w = f2bf(t[c4 * 4 + 3][orow]);
    *(ushort4*)&wt[(size_t)(o0 + orow) * 1024 + j0 + c4 * 4] = h;
  }
}

// ---------------------------------------------------------------------------
// Merged in-projection GEMMs v3: BK=64 halfs (128B rows, flash-proven staging:
// pre-swizzled source chunk pos^(row&7), linear LDS write, chunk^(row&7) b128
// frag reads -> 0 conflicts). Single 32KB buffer, 2 barriers/step, T14 reg
// prefetch (loads issued after stage barrier, awaited at next stage write).
// MFMA in 2 K-subphases to bound frag VGPRs. id swizzle: 8 o-blocks sharing
// an A-panel land on one XCD.
// bz=0: Qw[n][k][l][i] (o=k*64+i); bz=1: Kh[n][k][s][i]; bz=2: Vt[n][k][i][s].
__global__ __launch_bounds__(256) void k_gemm_in(
    const unsigned short* __restrict__ Abf, const unsigned short* __restrict__ Bq,
    const unsigned short* __restrict__ Bk, const unsigned short* __restrict__ Bv,
    const float* __restrict__ bq, const float* __restrict__ bk,
    const float* __restrict__ bv, unsigned short* __restrict__ Cq,
    unsigned short* __restrict__ Ck, unsigned short* __restrict__ Cv) {
  __shared__ unsigned short As[128 * 64];
  __shared__ unsigned short Bs[128 * 64];
  const int id = blockIdx.x;                     // 0..767
  const int g  = (id & 7) + ((id >> 6) << 3);    // 0..95 (A-panel group)
  const int bx = (id >> 3) & 7;                  // o-block
  const int by = g & 31, bz = g >> 5;
  const unsigned short* A = Abf + (size_t)bz * 4194304;
  const unsigned short* B = bz == 0 ? Bq : (bz == 1 ? Bk : Bv);
  const float* bias       = bz == 0 ? bq : (bz == 1 ? bk : bv);
  unsigned short* C       = bz == 0 ? Cq : (bz == 1 ? Ck : Cv);
  const int m0 = by * 128, o0 = bx * 128;
  const int tid = threadIdx.x;
  const int wid = tid >> 6, lane = tid & 63;
  const int wr = wid >> 1, wc = wid & 1;
  const int lr = lane & 15, lk = lane >> 4;
  // staging: 1024 16B-chunks per tile; thread covers idx=q*256+tid (q=0..3);
  // row = idx>>3, pos = idx&7; source col halfs = (pos^(row&7))<<3
  int srow[4], scol[4];
#pragma unroll
  for (int q = 0; q < 4; ++q) {
    const int idx = q * 256 + tid;
    srow[q] = idx >> 3;
    scol[q] = (((idx & 7) ^ ((idx >> 3) & 7)) << 3);
  }
  f32x4 acc[4][4];
#pragma unroll
  for (int i = 0; i < 4; ++i)
#pragma unroll
    for (int j = 0; j < 4; ++j) acc[i][j] = (f32x4){0.f, 0.f, 0.f, 0.f};

  int4 areg[4], breg[4];
#pragma unroll
  for (int q = 0; q < 4; ++q) {
    areg[q] = *(const int4*)&A[(size_t)(m0 + srow[q]) * 1024 + scol[q]];
    breg[q] = *(const int4*)&B[(size_t)(o0 + srow[q]) * 1024 + scol[q]];
  }

  for (int t = 0; t < 16; ++t) {
#pragma unroll
    for (int q = 0; q < 4; ++q) {
      *(int4*)&As[(q * 256 + tid) * 8] = areg[q];
      *(int4*)&Bs[(q * 256 + tid) * 8] = breg[q];
    }
    __syncthreads();
    if (t < 15) {    // T14: issue next tile's loads; awaited at next stage write
      const int k1 = (t + 1) * 64;
#pragma unroll
      for (int q = 0; q < 4; ++q) {
        areg[q] = *(const int4*)&A[(size_t)(m0 + srow[q]) * 1024 + k1 + scol[q]];
        breg[q] = *(const int4*)&B[(size_t)(o0 + srow[q]) * 1024 + k1 + scol[q]];
      }
    }
    // subphase 0: k-chunk lk
    {
      bf16x8 af[4], bfr[4];
#pragma unroll
      for (int f = 0; f < 4; ++f) {
        const int ra = wr * 64 + f * 16 + lr;
        af[f] = *(const bf16x8*)&As[ra * 64 + ((lk ^ (ra & 7)) << 3)];
        const int rb = wc * 64 + f * 16 + lr;
        bfr[f] = *(const bf16x8*)&Bs[rb * 64 + ((lk ^ (rb & 7)) << 3)];
      }
#pragma unroll
      for (int i = 0; i < 4; ++i)
#pragma unroll
        for (int j = 0; j < 4; ++j)
          acc[i][j] = __builtin_amdgcn_mfma_f32_16x16x32_bf16(af[i], bfr[j], acc[i][j], 0, 0, 0);
    }
    // subphase 1: k-chunk 4+lk
    {
      bf16x8 af[4], bfr[4];
#pragma unroll
      for (int f = 0; f < 4; ++f) {
        const int ra = wr * 64 + f * 16 + lr;
        af[f] = *(const bf16x8*)&As[ra * 64 + (((4 + lk) ^ (ra & 7)) << 3)];
        const int rb = wc * 64 + f * 16 + lr;
        bfr[f] = *(const bf16x8*)&Bs[rb * 64 + (((4 + lk) ^ (rb & 7)) << 3)];
      }
#pragma unroll
      for (int i = 0; i < 4; ++i)
#pragma unroll
        for (int j = 0; j < 4; ++j)
          acc[i][j] = __builtin_amdgcn_mfma_f32_16x16x32_bf16(af[i], bfr[j], acc[i][j], 0, 0, 0);
    }
    __syncthreads();
  }
#pragma unroll
  for (int fi = 0; fi < 4; ++fi)
#pragma unroll
    for (int fj = 0; fj < 4; ++fj) {
      const int o = o0 + wc * 64 + fj * 16 + lr;
      const float bo = bias[o];
#pragma unroll
      for (int t = 0; t < 4; ++t) {
        const int m = m0 + wr * 64 + fi * 16 + lk * 4 + t;
        const float v = acc[fi][fj][t] + bo;
        const int l = m >> 2, nn = m & 3;
        if (bz == 0) {
          const int kk = o >> 6, ii = o & 63;
          C[(((size_t)(nn * 16 + kk) * 1024 + l) << 6) + ii] = f2bf(v);
        } else if (bz == 1) {
          const int kk = o & 15, ii = o >> 4;
          C[(((size_t)(nn * 16 + kk) * 1024 + l) << 6) + ii] = f2bf(v);
        } else {
          const int kk = o & 15, ii = o >> 4;
          C[(((size_t)(nn * 16 + kk) * 64 + ii) << 10) + l] = f2bf(v);
        }
      }
    }
}

// ---------------------------------------------------------------------------
// Out-projection GEMM v3: 64x128 tile, BK=64, same flash-style staging + T14.
// f32 out. Same XCD-chunked id swizzle.
__global__ __launch_bounds__(256) void k_gemm_out(
    const unsigned short* __restrict__ A, const unsigned short* __restrict__ B,
    const float* __restrict__ bias, float* __restrict__ C) {
  __shared__ unsigned short As[64 * 64];
  __shared__ unsigned short Bs[128 * 64];
  const int id = blockIdx.x;                     // 0..511
  const int g  = (id & 7) + ((id >> 6) << 3);    // 0..63 m-block
  const int bx = (id >> 3) & 7;                  // o-block
  const int m0 = g * 64, o0 = bx * 128;
  const int tid = threadIdx.x;
  const int wid = tid >> 6, lane = tid & 63;
  const int wr = wid >> 1, wc = wid & 1;
  const int lr = lane & 15, lk = lane >> 4;
  int srow[4], scol[4];
#pragma unroll
  for (int q = 0; q < 4; ++q) {
    const int idx = q * 256 + tid;
    srow[q] = idx >> 3;
    scol[q] = (((idx & 7) ^ ((idx >> 3) & 7)) << 3);
  }
  f32x4 acc[2][4];
#pragma unroll
  for (int i = 0; i < 2; ++i)
#pragma unroll
    for (int j = 0; j < 4; ++j) acc[i][j] = (f32x4){0.f, 0.f, 0.f, 0.f};

  int4 areg[2], breg[4];
#pragma unroll
  for (int q = 0; q < 2; ++q)
    areg[q] = *(const int4*)&A[(size_t)(m0 + srow[q]) * 1024 + scol[q]];
#pragma unroll
  for (int q = 0; q < 4; ++q)
    breg[q] = *(const int4*)&B[(size_t)(o0 + srow[q]) * 1024 + scol[q]];

  for (int t = 0; t < 16; ++t) {
#pragma unroll
    for (int q = 0; q < 2; ++q)
      *(int4*)&As[(q * 256 + tid) * 8] = areg[q];
#pragma unroll
    for (int q = 0; q < 4; ++q)
      *(int4*)&Bs[(q * 256 + tid) * 8] = breg[q];
    __syncthreads();
    if (t < 15) {
      const int k1 = (t + 1) * 64;
#pragma unroll
      for (int q = 0; q < 2; ++q)
        areg[q] = *(const int4*)&A[(size_t)(m0 + srow[q]) * 1024 + k1 + scol[q]];
#pragma unroll
      for (int q = 0; q < 4; ++q)
        breg[q] = *(const int4*)&B[(size_t)(o0 + srow[q]) * 1024 + k1 + scol[q]];
    }
#pragma unroll
    for (int ph = 0; ph < 2; ++ph) {
      const int ck = ph * 4 + lk;
      bf16x8 af[2], bfr[4];
#pragma unroll
      for (int f = 0; f < 2; ++f) {
        const int ra = wr * 32 + f * 16 + lr;
        af[f] = *(const bf16x8*)&As[ra * 64 + ((ck ^ (ra & 7)) << 3)];
      }
#pragma unroll
      for (int f = 0; f < 4; ++f) {
        const int rb = wc * 64 + f * 16 + lr;
        bfr[f] = *(const bf16x8*)&Bs[rb * 64 + ((ck ^ (rb & 7)) << 3)];
      }
#pragma unroll
      for (int i = 0; i < 2; ++i)
#pragma unroll
        for (int j = 0; j < 4; ++j)
          acc[i][j] = __builtin_amdgcn_mfma_f32_16x16x32_bf16(af[i], bfr[j], acc[i][j], 0, 0, 0);
    }
    __syncthreads();
  }
#pragma unroll
  for (int fi = 0; fi < 2; ++fi)
#pragma unroll
    for (int fj = 0; fj < 4; ++fj) {
      const int o = o0 + wc * 64 + fj * 16 + lr;
      const float bo = bias[o];
#pragma unroll
      for (int t = 0; t < 4; ++t) {
        const int m = m0 + wr * 32 + fi * 16 + lk * 4 + t;
        C[(size_t)m * 1024 + o] = acc[fi][fj][t] + bo;
      }
    }
}

// ---------------------------------------------------------------------------
// MFMA flash v5 (unchanged): per (n,k,l-tile=64); 4 waves x 16 q-rows.
__global__ __launch_bounds__(256) void k_flash(
    const unsigned short* __restrict__ Qbf, const unsigned short* __restrict__ Khbf,
    const unsigned short* __restrict__ Vtbf, float* __restrict__ stats,
    unsigned short* __restrict__ Obf) {
  __shared__ unsigned short Kd[2][64 * 64];
  __shared__ unsigned short Vd[2][64 * 64];
  __shared__ unsigned short Ps[4][16 * 64];
  const int ob = blockIdx.x;
  const int b = (ob & 7) * 128 + (ob >> 3);   // bijective XCD swizzle
  const int lt = b & 15, k = (b >> 4) & 15, n = b >> 8;
  const int l0 = lt * 64;
  const int tid = threadIdx.x, w = tid >> 6, lane = tid & 63;
  const int lr = lane & 15, lk = lane >> 4;
  const size_t hb = (size_t)(n * 16 + k) * 65536;
  const unsigned short* qrow = Qbf + hb + (size_t)(l0 + w * 16 + lr) * 64;
  const bf16x8 qa0 = *(const bf16x8*)(qrow + lk * 8);
  const bf16x8 qa1 = *(const bf16x8*)(qrow + 32 + lk * 8);
  const int swz = lr & 7;
  int srow[2], scol[2];
#pragma unroll
  for (int q = 0; q < 2; ++q) {
    const int idx = q * 256 + tid;
    srow[q] = idx >> 3;
    scol[q] = (((idx & 7) ^ ((idx >> 3) & 7)) << 3);
  }
  const unsigned short* Kb = Khbf + hb;
  const unsigned short* Vb = Vtbf + hb;
  int4 kreg[2], vreg[2];
#pragma unroll
  for (int q = 0; q < 2; ++q) {
    kreg[q] = *(const int4*)(Kb + (size_t)srow[q] * 64 + scol[q]);
    vreg[q] = *(const int4*)(Vb + (size_t)srow[q] * 1024 + scol[q]);
  }
#pragma unroll
  for (int q = 0; q < 2; ++q) {
    *(int4*)&Kd[0][(q * 256 + tid) * 8] = kreg[q];
    *(int4*)&Vd[0][(q * 256 + tid) * 8] = vreg[q];
  }
  float m_ = -1e30f, Z_ = 0.f;
  f32x4 oacc[4];
#pragma unroll
  for (int it = 0; it < 4; ++it) oacc[it] = (f32x4){0.f, 0.f, 0.f, 0.f};
  __syncthreads();

  for (int t0 = 0; t0 < 16; ++t0) {
    const int cur = t0 & 1;
    if (t0 < 15) {
      const int s1 = (t0 + 1) * 64;
#pragma unroll
      for (int q = 0; q < 2; ++q) {
        kreg[q] = *(const int4*)(Kb + (size_t)(s1 + srow[q]) * 64 + scol[q]);
        vreg[q] = *(const int4*)(Vb + (size_t)srow[q] * 1024 + s1 + scol[q]);
      }
    }
    f32x4 sc[4];
#pragma unroll
    for (int st = 0; st < 4; ++st) {
      const int r = st * 16 + lr;
      const bf16x8 kb0 = *(const bf16x8*)&Kd[cur][r * 64 + ((lk ^ (r & 7)) << 3)];
      const bf16x8 kb1 = *(const bf16x8*)&Kd[cur][r * 64 + (((4 + lk) ^ (r & 7)) << 3)];
      f32x4 z = (f32x4){0.f, 0.f, 0.f, 0.f};
      z = __builtin_amdgcn_mfma_f32_16x16x32_bf16(kb0, qa0, z, 0, 0, 0);
      sc[st] = __builtin_amdgcn_mfma_f32_16x16x32_bf16(kb1, qa1, z, 0, 0, 0);
    }
    float tm = fmaxf(fmaxf(fmaxf(sc[0][0], sc[0][1]), fmaxf(sc[0][2], sc[0][3])),
                     fmaxf(fmaxf(sc[1][0], sc[1][1]), fmaxf(sc[1][2], sc[1][3])));
    tm = fmaxf(tm, fmaxf(fmaxf(fmaxf(sc[2][0], sc[2][1]), fmaxf(sc[2][2], sc[2][3])),
                         fmaxf(fmaxf(sc[3][0], sc[3][1]), fmaxf(sc[3][2], sc[3][3]))));
    tm = fmaxf(tm, __shfl_xor(tm, 16));
    tm = fmaxf(tm, __shfl_xor(tm, 32));
    const float mn = fmaxf(m_, tm);
    const float fac = __expf(m_ - mn);
    m_ = mn;
    float rs = 0.f;
    float p[4][4];
#pragma unroll
    for (int st = 0; st < 4; ++st)
#pragma unroll
      for (int t = 0; t < 4; ++t) {
        p[st][t] = __expf(sc[st][t] - mn);
        rs += p[st][t];
      }
    rs += __shfl_xor(rs, 16);
    rs += __shfl_xor(rs, 32);
    Z_ = Z_ * fac + rs;
#pragma unroll
    for (int st = 0; st < 4; ++st) {
      ushort4 pk;
      pk.x = f2bf(p[st][0]); pk.y = f2bf(p[st][1]);
      pk.z = f2bf(p[st][2]); pk.w = f2bf(p[st][3]);
      const int c = (st * 4 + lk) ^ (swz << 1);
      *(ushort4*)&Ps[w][lr * 64 + c * 4] = pk;
    }
    float fr[4];
#pragma unroll
    for (int t = 0; t < 4; ++t) fr[t] = __shfl(fac, lk * 4 + t);
    const f32x4 facv = {fr[0], fr[1], fr[2], fr[3]};
    const bf16x8 pa0 = *(const bf16x8*)&Ps[w][lr * 64 + ((lk ^ swz) << 3)];
    const bf16x8 pa1 = *(const bf16x8*)&Ps[w][lr * 64 + (((4 + lk) ^ swz) << 3)];
#pragma unroll
    for (int it = 0; it < 4; ++it) {
      const int r = it * 16 + lr;
      const bf16x8 bv0 = *(const bf16x8*)&Vd[cur][r * 64 + ((lk ^ (r & 7)) << 3)];
      const bf16x8 bv1 = *(const bf16x8*)&Vd[cur][r * 64 + (((4 + lk) ^ (r & 7)) << 3)];
      f32x4 o = oacc[it] * facv;
      o = __builtin_amdgcn_mfma_f32_16x16x32_bf16(pa0, bv0, o, 0, 0, 0);
      oacc[it] = __builtin_amdgcn_mfma_f32_16x16x32_bf16(pa1, bv1, o, 0, 0, 0);
    }
    if (t0 < 15) {
#pragma unroll
      for (int q = 0; q < 2; ++q) {
        *(int4*)&Kd[cur ^ 1][(q * 256 + tid) * 8] = kreg[q];
        *(int4*)&Vd[cur ^ 1][(q * 256 + tid) * 8] = vreg[q];
      }
    }
    __syncthreads();
  }

  if (lane < 16) {
    const size_t so = ((size_t)(n * 16 + k) * 1024 + l0 + w * 16 + lr) * 2;
    stats[so] = m_;
    stats[so + 1] = Z_;
  }
  const float iz = 1.f / Z_;
  float izr[4];
#pragma unroll
  for (int t = 0; t < 4; ++t) izr[t] = __shfl(iz, lk * 4 + t);
#pragma unroll
  for (int it = 0; it < 4; ++it)
#pragma unroll
    for (int t = 0; t < 4; ++t) {
      const int l = l0 + w * 16 + lk * 4 + t;
      const int i = it * 16 + lr;
      Obf[(size_t)(l * 4 + n) * 1024 + i * 16 + k] = f2bf(oacc[it][t] * izr[t]);
    }
}

// ---------------------------------------------------------------------------
// Wmap v4 (unchanged).
__global__ __launch_bounds__(256) void k_wmap(const unsigned short* __restrict__ Qbf,
    const unsigned short* __restrict__ Khbf, const float* __restrict__ stats,
    float* __restrict__ Wmap) {
  __shared__ unsigned short Kst[2][64 * 64];
  const int ob = blockIdx.x;
  const int b = (ob & 7) * 128 + (ob >> 3);
  const int st = b & 15, lt = (b >> 4) & 15, n = b >> 8;
  const int l0 = lt * 64, s0 = st * 64;
  const int tid = threadIdx.x, w = tid >> 6, lane = tid & 63;
  const int lr = lane & 15, lk = lane >> 4;
  int srow[2], scol[2];
#pragma unroll
  for (int q = 0; q < 2; ++q) {
    const int idx = q * 256 + tid;
    srow[q] = idx >> 3;
    scol[q] = (((idx & 7) ^ ((idx >> 3) & 7)) << 3);
  }
  int4 kreg[2];
#pragma unroll
  for (int q = 0; q < 2; ++q)
    kreg[q] = *(const int4*)(Khbf + (size_t)(n * 16) * 65536 +
                             (size_t)(s0 + srow[q]) * 64 + scol[q]);
#pragma unroll
  for (int q = 0; q < 2; ++q)
    *(int4*)&Kst[0][(q * 256 + tid) * 8] = kreg[q];
  f32x4 wsum[4];
#pragma unroll
  for (int i = 0; i < 4; ++i) wsum[i] = (f32x4){0.f, 0.f, 0.f, 0.f};
  __syncthreads();

  for (int k = 0; k < 16; ++k) {
    const int cur = k & 1;
    const size_t hb = (size_t)(n * 16 + k) * 65536;
    if (k < 15) {
      const size_t hb1 = (size_t)(n * 16 + k + 1) * 65536;
#pragma unroll
      for (int q = 0; q < 2; ++q)
        kreg[q] = *(const int4*)(Khbf + hb1 + (size_t)(s0 + srow[q]) * 64 + scol[q]);
    }
    const unsigned short* qrow = Qbf + hb + (size_t)(l0 + w * 16 + lr) * 64;
    const bf16x8 a0 = *(const bf16x8*)(qrow + lk * 8);
    const bf16x8 a1 = *(const bf16x8*)(qrow + 32 + lk * 8);
    float mv[4], izv[4];
#pragma unroll
    for (int t = 0; t < 4; ++t) {
      const float2 mz = *(const float2*)(stats +
          ((size_t)(n * 16 + k) * 1024 + l0 + w * 16 + lk * 4 + t) * 2);
      mv[t] = mz.x; izv[t] = 1.f / mz.y;
    }
#pragma unroll
    for (int st2 = 0; st2 < 4; ++st2) {
      const int r = st2 * 16 + lr;
      const bf16x8 kb0 = *(const bf16x8*)&Kst[cur][r * 64 + ((lk ^ (r & 7)) << 3)];
      const bf16x8 kb1 = *(const bf16x8*)&Kst[cur][r * 64 + (((4 + lk) ^ (r & 7)) << 3)];
      f32x4 z = (f32x4){0.f, 0.f, 0.f, 0.f};
      z = __builtin_amdgcn_mfma_f32_16x16x32_bf16(a0, kb0, z, 0, 0, 0);
      z = __builtin_amdgcn_mfma_f32_16x16x32_bf16(a1, kb1, z, 0, 0, 0);
#pragma unroll
      for (int t = 0; t < 4; ++t)
        wsum[st2][t] += __expf(z[t] - mv[t]) * izv[t];
    }
    if (k < 15) {
#pragma unroll
      for (int q = 0; q < 2; ++q)
        *(int4*)&Kst[cur ^ 1][(q * 256 + tid) * 8] = kreg[q];
    }
    __syncthreads();
  }
#pragma unroll
  for (int st2 = 0; st2 < 4; ++st2)
#pragma unroll
    for (int t = 0; t < 4; ++t) {
      const int l = l0 + w * 16 + lk * 4 + t;
      const int s = s0 + st2 * 16 + lr;
      Wmap[((size_t)l * 1024 + s) * 4 + n] = wsum[st2][t] * 0.0625f;
    }
}

// ---------------------------------------------------------------------------
extern "C" void kernel_launch(void* const* d_in, const int* in_sizes, int n_in,
                              void* d_out, int out_size, void* d_ws, size_t ws_size,
                              hipStream_t stream) {
  (void)in_sizes; (void)n_in; (void)out_size; (void)ws_size;
  const float* Q        = (const float*)d_in[0];
  const float* K        = (const float*)d_in[1];
  const float* V        = (const float*)d_in[2];
  const float* q_w      = (const float*)d_in[3];
  const float* k_w      = (const float*)d_in[4];
  const float* v_w      = (const float*)d_in[5];
  const float* out_w    = (const float*)d_in[6];
  const float* in_bias  = (const float*)d_in[7];
  const float* out_bias = (const float*)d_in[8];
  const float* attn_W   = (const float*)d_in[9];
  float* ws = (float*)d_ws;
  unsigned short* qw2bf = (unsigned short*)(ws + OFF_QW2BF);
  unsigned short* kwbf  = (unsigned short*)(ws + OFF_KWBF);
  unsigned short* vwbf  = (unsigned short*)(ws + OFF_VWBF);
  unsigned short* owtbf = (unsigned short*)(ws + OFF_OWTBF);
  float* qb2 = ws + OFF_QB2;
  unsigned short* Qwbf = (unsigned short*)(ws + OFF_QWBF);
  unsigned short* Khbf = (unsigned short*)(ws + OFF_KHBF);
  unsigned short* Vtbf = (unsigned short*)(ws + OFF_VTBF);
  float* st = ws + OFF_ST;
  unsigned short* Obf  = (unsigned short*)(ws + OFF_OBF);
  unsigned short* Abf  = (unsigned short*)(ws + OFF_ABF);
  float* out  = (float*)d_out;
  float* Wmap = out + 4194304;

  k_qw2<<<1024, 256, 0, stream>>>(q_w, attn_W, in_bias, qw2bf, qb2);
  k_cvt2<<<1024, 256, 0, stream>>>(k_w, v_w, kwbf, vwbf);
  k_cvtA<<<3072, 256, 0, stream>>>(Q, K, V, Abf);
  k_tr<<<dim3(16, 16), 256, 0, stream>>>(out_w, owtbf);
  k_gemm_in<<<768, 256, 0, stream>>>(Abf, qw2bf, kwbf, vwbf,
                                     qb2, in_bias + 1024, in_bias + 2048,
                                     Qwbf, Khbf, Vtbf);
  k_flash<<<1024, 256, 0, stream>>>(Qwbf, Khbf, Vtbf, st, Obf);
  k_wmap<<<1024, 256, 0, stream>>>(Qwbf, Khbf, st, Wmap);
  k_gemm_out<<<512, 256, 0, stream>>>(Obf, owtbf, out_bias, out);
}

// Round 9
// 301.722 us; speedup vs baseline: 1.0470x; 1.0470x over previous
//
#include <hip/hip_runtime.h>
#include <cstdint>

// Problem constants: L=S=1024, N=4, E=1024, H=16, D=64
typedef __bf16 bf16x8 __attribute__((ext_vector_type(8)));
typedef float f32x4 __attribute__((ext_vector_type(4)));

// ws layout (float-unit offsets):
static const size_t OFF_QW2BF = 0;         // [k*64+i][j] bf16 (1M ushort)
static const size_t OFF_KWBF  = 524288;    // [k*64+i][j] bf16 (head-major)
static const size_t OFF_VWBF  = 1048576;   // [k*64+i][j] bf16 (head-major)
static const size_t OFF_OWTBF = 1572864;   // [o][j] bf16 (out_w^T)
static const size_t OFF_QB2   = 2097152;   // 1024 f32
static const size_t OFF_QWBF  = 2098176;   // [n][k][l][i] bf16 (4M ushort)
static const size_t OFF_KHBF  = 4195328;   // [n][k][s][i] bf16
static const size_t OFF_VTBF  = 6292480;   // [n][k][i][s] bf16 (V^T per head)
static const size_t OFF_ST    = 8389632;   // [n][k][l][{m,Z}] f32 131072
static const size_t OFF_OBF   = 8520704;   // [l*4+n][e] bf16 (4M ushort)
static const size_t OFF_ABF   = 10617856;  // [3][4096][1024] bf16 (12M ushort)

__device__ inline unsigned short f2bf(float f) {
  union { float f; unsigned u; } v; v.f = f;
  const unsigned r = v.u + 0x7FFFu + ((v.u >> 16) & 1u);   // RNE
  return (unsigned short)(r >> 16);
}

// ---------------------------------------------------------------------------
// K0: fold attn_W into q_w (bf16 out): qw2[(k,i),j] = sum_o q_w[o*16+k,j]*attn_W[o,i,k]/32
__global__ __launch_bounds__(256) void k_qw2(const float* __restrict__ qw,
    const float* __restrict__ attnW, const float* __restrict__ bias0,
    unsigned short* __restrict__ qw2, float* __restrict__ qb2) {
  const int b = blockIdx.x;          // = k*64 + i
  const int k = b >> 6, i = b & 63;
  const int tid = threadIdx.x;
  __shared__ float aw[64];
  if (tid < 64) aw[tid] = attnW[(tid * 64 + i) * 16 + k] * 0.03125f; // fold 1/sqrt(E)
  __syncthreads();
  for (int j = tid; j < 1024; j += 256) {
    float acc = 0.f;
#pragma unroll 8
    for (int o = 0; o < 64; ++o) acc = fmaf(qw[(o * 16 + k) * 1024 + j], aw[o], acc);
    qw2[(size_t)b * 1024 + j] = f2bf(acc);
  }
  if (tid == 0) {
    float acc = 0.f;
    for (int o = 0; o < 64; ++o) acc = fmaf(bias0[o * 16 + k], aw[o], acc);
    qb2[b] = acc;
  }
}

// ---------------------------------------------------------------------------
// Convert k_w and v_w to bf16 AND permute rows to head-major:
// dst row (k*64+i) = src row (i*16+k). One block per src row.
__global__ __launch_bounds__(256) void k_cvt2(const float* __restrict__ a,
    const float* __restrict__ b, unsigned short* __restrict__ oa,
    unsigned short* __restrict__ ob) {
  const int o = blockIdx.x;                    // src row 0..1023 (= i*16+k)
  const int dst = (o & 15) * 64 + (o >> 4);    // head-major row k*64+i
  const int j = threadIdx.x;                   // float4 index 0..255
  const float4 va = ((const float4*)(a + (size_t)o * 1024))[j];
  ushort4 ha; ha.x = f2bf(va.x); ha.y = f2bf(va.y); ha.z = f2bf(va.z); ha.w = f2bf(va.w);
  ((ushort4*)(oa + (size_t)dst * 1024))[j] = ha;
  const float4 vb = ((const float4*)(b + (size_t)o * 1024))[j];
  ushort4 hb; hb.x = f2bf(vb.x); hb.y = f2bf(vb.y); hb.z = f2bf(vb.z); hb.w = f2bf(vb.w);
  ((ushort4*)(ob + (size_t)dst * 1024))[j] = hb;
}

// ---------------------------------------------------------------------------
// Convert Q,K,V activations to bf16: Abf[m][4096][1024], m in {0,1,2}
__global__ __launch_bounds__(256) void k_cvtA(const float* __restrict__ Q,
    const float* __restrict__ K, const float* __restrict__ V,
    unsigned short* __restrict__ out) {
  const int b = blockIdx.x;                 // 0..3071
  const int m = b >> 10;
  const float* src = m == 0 ? Q : (m == 1 ? K : V);
  unsigned short* dst = out + (size_t)m * 4194304;
#pragma unroll
  for (int q = 0; q < 4; ++q) {
    const int idx = (b & 1023) * 1024 + q * 256 + threadIdx.x;
    const float4 v = ((const float4*)src)[idx];
    ushort4 h; h.x = f2bf(v.x); h.y = f2bf(v.y); h.z = f2bf(v.z); h.w = f2bf(v.w);
    ((ushort4*)dst)[idx] = h;
  }
}

// ---------------------------------------------------------------------------
// Transpose out_w [j][o] -> owT [o][j] bf16
__global__ __launch_bounds__(256) void k_tr(const float* __restrict__ w,
    unsigned short* __restrict__ wt) {
  __shared__ float t[64][65];
  const int j0 = blockIdx.y * 64, o0 = blockIdx.x * 64;
  const int tid = threadIdx.x;
  const int r = tid >> 4, c4 = tid & 15;
#pragma unroll
  for (int q = 0; q < 4; ++q) {
    const int row = r + q * 16;
    const float4 v = *(const float4*)&w[(size_t)(j0 + row) * 1024 + o0 + c4 * 4];
    t[row][c4 * 4 + 0] = v.x; t[row][c4 * 4 + 1] = v.y;
    t[row][c4 * 4 + 2] = v.z; t[row][c4 * 4 + 3] = v.w;
  }
  __syncthreads();
#pragma unroll
  for (int q = 0; q < 4; ++q) {
    const int orow = r + q * 16;
    ushort4 h;
    h.x = f2bf(t[c4 * 4 + 0][orow]); h.y = f2bf(t[c4 * 4 + 1][orow]);
    h.z = f2bf(t[c4 * 4 + 2][orow]); h.w = f2bf(t[c4 * 4 + 3][orow]);
    *(ushort4*)&wt[(size_t)(o0 + orow) * 1024 + j0 + c4 * 4] = h;
  }
}

// ---------------------------------------------------------------------------
// Merged in-projection GEMMs v4: all B-matrices head-major (o = k*64+i), so
// every output cacheline is produced by ONE block with wave-coalesced 32B+
// segments (fixes the 280MB scatter write amplification seen in R8).
// BK=64 staging (flash-proven swizzle, 0 conflicts), T14 reg prefetch.
// bz=0: Qw[n][kk][l][ii]; bz=1: Kh[n][kk][s][ii]; bz=2: Vt[n][kk][ii][s].
// Bias: bz=0 indexed by o (qb2 is head-major); bz=1/2 by original ii*16+kk.
__global__ __launch_bounds__(256) void k_gemm_in(
    const unsigned short* __restrict__ Abf, const unsigned short* __restrict__ Bq,
    const unsigned short* __restrict__ Bk, const unsigned short* __restrict__ Bv,
    const float* __restrict__ bq, const float* __restrict__ bk,
    const float* __restrict__ bv, unsigned short* __restrict__ Cq,
    unsigned short* __restrict__ Ck, unsigned short* __restrict__ Cv) {
  __shared__ unsigned short As[128 * 64];
  __shared__ unsigned short Bs[128 * 64];
  const int id = blockIdx.x;                     // 0..767
  const int g  = (id & 7) + ((id >> 6) << 3);    // 0..95 (A-panel group)
  const int bx = (id >> 3) & 7;                  // o-block
  const int by = g & 31, bz = g >> 5;
  const unsigned short* A = Abf + (size_t)bz * 4194304;
  const unsigned short* B = bz == 0 ? Bq : (bz == 1 ? Bk : Bv);
  const float* bias       = bz == 0 ? bq : (bz == 1 ? bk : bv);
  unsigned short* C       = bz == 0 ? Cq : (bz == 1 ? Ck : Cv);
  const int m0 = by * 128, o0 = bx * 128;
  const int tid = threadIdx.x;
  const int wid = tid >> 6, lane = tid & 63;
  const int wr = wid >> 1, wc = wid & 1;
  const int lr = lane & 15, lk = lane >> 4;
  int srow[4], scol[4];
#pragma unroll
  for (int q = 0; q < 4; ++q) {
    const int idx = q * 256 + tid;
    srow[q] = idx >> 3;
    scol[q] = (((idx & 7) ^ ((idx >> 3) & 7)) << 3);
  }
  f32x4 acc[4][4];
#pragma unroll
  for (int i = 0; i < 4; ++i)
#pragma unroll
    for (int j = 0; j < 4; ++j) acc[i][j] = (f32x4){0.f, 0.f, 0.f, 0.f};

  int4 areg[4], breg[4];
#pragma unroll
  for (int q = 0; q < 4; ++q) {
    areg[q] = *(const int4*)&A[(size_t)(m0 + srow[q]) * 1024 + scol[q]];
    breg[q] = *(const int4*)&B[(size_t)(o0 + srow[q]) * 1024 + scol[q]];
  }

  for (int t = 0; t < 16; ++t) {
#pragma unroll
    for (int q = 0; q < 4; ++q) {
      *(int4*)&As[(q * 256 + tid) * 8] = areg[q];
      *(int4*)&Bs[(q * 256 + tid) * 8] = breg[q];
    }
    __syncthreads();
    if (t < 15) {    // T14: issue next tile's loads; awaited at next stage write
      const int k1 = (t + 1) * 64;
#pragma unroll
      for (int q = 0; q < 4; ++q) {
        areg[q] = *(const int4*)&A[(size_t)(m0 + srow[q]) * 1024 + k1 + scol[q]];
        breg[q] = *(const int4*)&B[(size_t)(o0 + srow[q]) * 1024 + k1 + scol[q]];
      }
    }
#pragma unroll
    for (int ph = 0; ph < 2; ++ph) {
      const int ck = ph * 4 + lk;
      bf16x8 af[4], bfr[4];
#pragma unroll
      for (int f = 0; f < 4; ++f) {
        const int ra = wr * 64 + f * 16 + lr;
        af[f] = *(const bf16x8*)&As[ra * 64 + ((ck ^ (ra & 7)) << 3)];
        const int rb = wc * 64 + f * 16 + lr;
        bfr[f] = *(const bf16x8*)&Bs[rb * 64 + ((ck ^ (rb & 7)) << 3)];
      }
#pragma unroll
      for (int i = 0; i < 4; ++i)
#pragma unroll
        for (int j = 0; j < 4; ++j)
          acc[i][j] = __builtin_amdgcn_mfma_f32_16x16x32_bf16(af[i], bfr[j], acc[i][j], 0, 0, 0);
    }
    __syncthreads();
  }
#pragma unroll
  for (int fi = 0; fi < 4; ++fi)
#pragma unroll
    for (int fj = 0; fj < 4; ++fj) {
      const int o = o0 + wc * 64 + fj * 16 + lr;
      const int kk = o >> 6, ii = o & 63;
      const float bo = bz == 0 ? bias[o] : bias[ii * 16 + kk];
#pragma unroll
      for (int t = 0; t < 4; ++t) {
        const int m = m0 + wr * 64 + fi * 16 + lk * 4 + t;
        const float v = acc[fi][fj][t] + bo;
        const int l = m >> 2, nn = m & 3;
        if (bz <= 1) {
          C[(((size_t)(nn * 16 + kk) * 1024 + l) << 6) + ii] = f2bf(v);
        } else {
          C[(((size_t)(nn * 16 + kk) * 64 + ii) << 10) + l] = f2bf(v);
        }
      }
    }
}

// ---------------------------------------------------------------------------
// Out-projection GEMM v3 (unchanged): 64x128 tile, BK=64, flash-style staging.
__global__ __launch_bounds__(256) void k_gemm_out(
    const unsigned short* __restrict__ A, const unsigned short* __restrict__ B,
    const float* __restrict__ bias, float* __restrict__ C) {
  __shared__ unsigned short As[64 * 64];
  __shared__ unsigned short Bs[128 * 64];
  const int id = blockIdx.x;                     // 0..511
  const int g  = (id & 7) + ((id >> 6) << 3);    // 0..63 m-block
  const int bx = (id >> 3) & 7;                  // o-block
  const int m0 = g * 64, o0 = bx * 128;
  const int tid = threadIdx.x;
  const int wid = tid >> 6, lane = tid & 63;
  const int wr = wid >> 1, wc = wid & 1;
  const int lr = lane & 15, lk = lane >> 4;
  int srow[4], scol[4];
#pragma unroll
  for (int q = 0; q < 4; ++q) {
    const int idx = q * 256 + tid;
    srow[q] = idx >> 3;
    scol[q] = (((idx & 7) ^ ((idx >> 3) & 7)) << 3);
  }
  f32x4 acc[2][4];
#pragma unroll
  for (int i = 0; i < 2; ++i)
#pragma unroll
    for (int j = 0; j < 4; ++j) acc[i][j] = (f32x4){0.f, 0.f, 0.f, 0.f};

  int4 areg[2], breg[4];
#pragma unroll
  for (int q = 0; q < 2; ++q)
    areg[q] = *(const int4*)&A[(size_t)(m0 + srow[q]) * 1024 + scol[q]];
#pragma unroll
  for (int q = 0; q < 4; ++q)
    breg[q] = *(const int4*)&B[(size_t)(o0 + srow[q]) * 1024 + scol[q]];

  for (int t = 0; t < 16; ++t) {
#pragma unroll
    for (int q = 0; q < 2; ++q)
      *(int4*)&As[(q * 256 + tid) * 8] = areg[q];
#pragma unroll
    for (int q = 0; q < 4; ++q)
      *(int4*)&Bs[(q * 256 + tid) * 8] = breg[q];
    __syncthreads();
    if (t < 15) {
      const int k1 = (t + 1) * 64;
#pragma unroll
      for (int q = 0; q < 2; ++q)
        areg[q] = *(const int4*)&A[(size_t)(m0 + srow[q]) * 1024 + k1 + scol[q]];
#pragma unroll
      for (int q = 0; q < 4; ++q)
        breg[q] = *(const int4*)&B[(size_t)(o0 + srow[q]) * 1024 + k1 + scol[q]];
    }
#pragma unroll
    for (int ph = 0; ph < 2; ++ph) {
      const int ck = ph * 4 + lk;
      bf16x8 af[2], bfr[4];
#pragma unroll
      for (int f = 0; f < 2; ++f) {
        const int ra = wr * 32 + f * 16 + lr;
        af[f] = *(const bf16x8*)&As[ra * 64 + ((ck ^ (ra & 7)) << 3)];
      }
#pragma unroll
      for (int f = 0; f < 4; ++f) {
        const int rb = wc * 64 + f * 16 + lr;
        bfr[f] = *(const bf16x8*)&Bs[rb * 64 + ((ck ^ (rb & 7)) << 3)];
      }
#pragma unroll
      for (int i = 0; i < 2; ++i)
#pragma unroll
        for (int j = 0; j < 4; ++j)
          acc[i][j] = __builtin_amdgcn_mfma_f32_16x16x32_bf16(af[i], bfr[j], acc[i][j], 0, 0, 0);
    }
    __syncthreads();
  }
#pragma unroll
  for (int fi = 0; fi < 2; ++fi)
#pragma unroll
    for (int fj = 0; fj < 4; ++fj) {
      const int o = o0 + wc * 64 + fj * 16 + lr;
      const float bo = bias[o];
#pragma unroll
      for (int t = 0; t < 4; ++t) {
        const int m = m0 + wr * 32 + fi * 16 + lk * 4 + t;
        C[(size_t)m * 1024 + o] = acc[fi][fj][t] + bo;
      }
    }
}

// ---------------------------------------------------------------------------
// MFMA flash v5 (unchanged): per (n,k,l-tile=64); 4 waves x 16 q-rows.
__global__ __launch_bounds__(256) void k_flash(
    const unsigned short* __restrict__ Qbf, const unsigned short* __restrict__ Khbf,
    const unsigned short* __restrict__ Vtbf, float* __restrict__ stats,
    unsigned short* __restrict__ Obf) {
  __shared__ unsigned short Kd[2][64 * 64];
  __shared__ unsigned short Vd[2][64 * 64];
  __shared__ unsigned short Ps[4][16 * 64];
  const int ob = blockIdx.x;
  const int b = (ob & 7) * 128 + (ob >> 3);   // bijective XCD swizzle
  const int lt = b & 15, k = (b >> 4) & 15, n = b >> 8;
  const int l0 = lt * 64;
  const int tid = threadIdx.x, w = tid >> 6, lane = tid & 63;
  const int lr = lane & 15, lk = lane >> 4;
  const size_t hb = (size_t)(n * 16 + k) * 65536;
  const unsigned short* qrow = Qbf + hb + (size_t)(l0 + w * 16 + lr) * 64;
  const bf16x8 qa0 = *(const bf16x8*)(qrow + lk * 8);
  const bf16x8 qa1 = *(const bf16x8*)(qrow + 32 + lk * 8);
  const int swz = lr & 7;
  int srow[2], scol[2];
#pragma unroll
  for (int q = 0; q < 2; ++q) {
    const int idx = q * 256 + tid;
    srow[q] = idx >> 3;
    scol[q] = (((idx & 7) ^ ((idx >> 3) & 7)) << 3);
  }
  const unsigned short* Kb = Khbf + hb;
  const unsigned short* Vb = Vtbf + hb;
  int4 kreg[2], vreg[2];
#pragma unroll
  for (int q = 0; q < 2; ++q) {
    kreg[q] = *(const int4*)(Kb + (size_t)srow[q] * 64 + scol[q]);
    vreg[q] = *(const int4*)(Vb + (size_t)srow[q] * 1024 + scol[q]);
  }
#pragma unroll
  for (int q = 0; q < 2; ++q) {
    *(int4*)&Kd[0][(q * 256 + tid) * 8] = kreg[q];
    *(int4*)&Vd[0][(q * 256 + tid) * 8] = vreg[q];
  }
  float m_ = -1e30f, Z_ = 0.f;
  f32x4 oacc[4];
#pragma unroll
  for (int it = 0; it < 4; ++it) oacc[it] = (f32x4){0.f, 0.f, 0.f, 0.f};
  __syncthreads();

  for (int t0 = 0; t0 < 16; ++t0) {
    const int cur = t0 & 1;
    if (t0 < 15) {
      const int s1 = (t0 + 1) * 64;
#pragma unroll
      for (int q = 0; q < 2; ++q) {
        kreg[q] = *(const int4*)(Kb + (size_t)(s1 + srow[q]) * 64 + scol[q]);
        vreg[q] = *(const int4*)(Vb + (size_t)srow[q] * 1024 + s1 + scol[q]);
      }
    }
    f32x4 sc[4];
#pragma unroll
    for (int st = 0; st < 4; ++st) {
      const int r = st * 16 + lr;
      const bf16x8 kb0 = *(const bf16x8*)&Kd[cur][r * 64 + ((lk ^ (r & 7)) << 3)];
      const bf16x8 kb1 = *(const bf16x8*)&Kd[cur][r * 64 + (((4 + lk) ^ (r & 7)) << 3)];
      f32x4 z = (f32x4){0.f, 0.f, 0.f, 0.f};
      z = __builtin_amdgcn_mfma_f32_16x16x32_bf16(kb0, qa0, z, 0, 0, 0);
      sc[st] = __builtin_amdgcn_mfma_f32_16x16x32_bf16(kb1, qa1, z, 0, 0, 0);
    }
    float tm = fmaxf(fmaxf(fmaxf(sc[0][0], sc[0][1]), fmaxf(sc[0][2], sc[0][3])),
                     fmaxf(fmaxf(sc[1][0], sc[1][1]), fmaxf(sc[1][2], sc[1][3])));
    tm = fmaxf(tm, fmaxf(fmaxf(fmaxf(sc[2][0], sc[2][1]), fmaxf(sc[2][2], sc[2][3])),
                         fmaxf(fmaxf(sc[3][0], sc[3][1]), fmaxf(sc[3][2], sc[3][3]))));
    tm = fmaxf(tm, __shfl_xor(tm, 16));
    tm = fmaxf(tm, __shfl_xor(tm, 32));
    const float mn = fmaxf(m_, tm);
    const float fac = __expf(m_ - mn);
    m_ = mn;
    float rs = 0.f;
    float p[4][4];
#pragma unroll
    for (int st = 0; st < 4; ++st)
#pragma unroll
      for (int t = 0; t < 4; ++t) {
        p[st][t] = __expf(sc[st][t] - mn);
        rs += p[st][t];
      }
    rs += __shfl_xor(rs, 16);
    rs += __shfl_xor(rs, 32);
    Z_ = Z_ * fac + rs;
#pragma unroll
    for (int st = 0; st < 4; ++st) {
      ushort4 pk;
      pk.x = f2bf(p[st][0]); pk.y = f2bf(p[st][1]);
      pk.z = f2bf(p[st][2]); pk.w = f2bf(p[st][3]);
      const int c = (st * 4 + lk) ^ (swz << 1);
      *(ushort4*)&Ps[w][lr * 64 + c * 4] = pk;
    }
    float fr[4];
#pragma unroll
    for (int t = 0; t < 4; ++t) fr[t] = __shfl(fac, lk * 4 + t);
    const f32x4 facv = {fr[0], fr[1], fr[2], fr[3]};
    const bf16x8 pa0 = *(const bf16x8*)&Ps[w][lr * 64 + ((lk ^ swz) << 3)];
    const bf16x8 pa1 = *(const bf16x8*)&Ps[w][lr * 64 + (((4 + lk) ^ swz) << 3)];
#pragma unroll
    for (int it = 0; it < 4; ++it) {
      const int r = it * 16 + lr;
      const bf16x8 bv0 = *(const bf16x8*)&Vd[cur][r * 64 + ((lk ^ (r & 7)) << 3)];
      const bf16x8 bv1 = *(const bf16x8*)&Vd[cur][r * 64 + (((4 + lk) ^ (r & 7)) << 3)];
      f32x4 o = oacc[it] * facv;
      o = __builtin_amdgcn_mfma_f32_16x16x32_bf16(pa0, bv0, o, 0, 0, 0);
      oacc[it] = __builtin_amdgcn_mfma_f32_16x16x32_bf16(pa1, bv1, o, 0, 0, 0);
    }
    if (t0 < 15) {
#pragma unroll
      for (int q = 0; q < 2; ++q) {
        *(int4*)&Kd[cur ^ 1][(q * 256 + tid) * 8] = kreg[q];
        *(int4*)&Vd[cur ^ 1][(q * 256 + tid) * 8] = vreg[q];
      }
    }
    __syncthreads();
  }

  if (lane < 16) {
    const size_t so = ((size_t)(n * 16 + k) * 1024 + l0 + w * 16 + lr) * 2;
    stats[so] = m_;
    stats[so + 1] = Z_;
  }
  const float iz = 1.f / Z_;
  float izr[4];
#pragma unroll
  for (int t = 0; t < 4; ++t) izr[t] = __shfl(iz, lk * 4 + t);
#pragma unroll
  for (int it = 0; it < 4; ++it)
#pragma unroll
    for (int t = 0; t < 4; ++t) {
      const int l = l0 + w * 16 + lk * 4 + t;
      const int i = it * 16 + lr;
      Obf[(size_t)(l * 4 + n) * 1024 + i * 16 + k] = f2bf(oacc[it][t] * izr[t]);
    }
}

// ---------------------------------------------------------------------------
// Wmap v4 (unchanged).
__global__ __launch_bounds__(256) void k_wmap(const unsigned short* __restrict__ Qbf,
    const unsigned short* __restrict__ Khbf, const float* __restrict__ stats,
    float* __restrict__ Wmap) {
  __shared__ unsigned short Kst[2][64 * 64];
  const int ob = blockIdx.x;
  const int b = (ob & 7) * 128 + (ob >> 3);
  const int st = b & 15, lt = (b >> 4) & 15, n = b >> 8;
  const int l0 = lt * 64, s0 = st * 64;
  const int tid = threadIdx.x, w = tid >> 6, lane = tid & 63;
  const int lr = lane & 15, lk = lane >> 4;
  int srow[2], scol[2];
#pragma unroll
  for (int q = 0; q < 2; ++q) {
    const int idx = q * 256 + tid;
    srow[q] = idx >> 3;
    scol[q] = (((idx & 7) ^ ((idx >> 3) & 7)) << 3);
  }
  int4 kreg[2];
#pragma unroll
  for (int q = 0; q < 2; ++q)
    kreg[q] = *(const int4*)(Khbf + (size_t)(n * 16) * 65536 +
                             (size_t)(s0 + srow[q]) * 64 + scol[q]);
#pragma unroll
  for (int q = 0; q < 2; ++q)
    *(int4*)&Kst[0][(q * 256 + tid) * 8] = kreg[q];
  f32x4 wsum[4];
#pragma unroll
  for (int i = 0; i < 4; ++i) wsum[i] = (f32x4){0.f, 0.f, 0.f, 0.f};
  __syncthreads();

  for (int k = 0; k < 16; ++k) {
    const int cur = k & 1;
    const size_t hb = (size_t)(n * 16 + k) * 65536;
    if (k < 15) {
      const size_t hb1 = (size_t)(n * 16 + k + 1) * 65536;
#pragma unroll
      for (int q = 0; q < 2; ++q)
        kreg[q] = *(const int4*)(Khbf + hb1 + (size_t)(s0 + srow[q]) * 64 + scol[q]);
    }
    const unsigned short* qrow = Qbf + hb + (size_t)(l0 + w * 16 + lr) * 64;
    const bf16x8 a0 = *(const bf16x8*)(qrow + lk * 8);
    const bf16x8 a1 = *(const bf16x8*)(qrow + 32 + lk * 8);
    float mv[4], izv[4];
#pragma unroll
    for (int t = 0; t < 4; ++t) {
      const float2 mz = *(const float2*)(stats +
          ((size_t)(n * 16 + k) * 1024 + l0 + w * 16 + lk * 4 + t) * 2);
      mv[t] = mz.x; izv[t] = 1.f / mz.y;
    }
#pragma unroll
    for (int st2 = 0; st2 < 4; ++st2) {
      const int r = st2 * 16 + lr;
      const bf16x8 kb0 = *(const bf16x8*)&Kst[cur][r * 64 + ((lk ^ (r & 7)) << 3)];
      const bf16x8 kb1 = *(const bf16x8*)&Kst[cur][r * 64 + (((4 + lk) ^ (r & 7)) << 3)];
      f32x4 z = (f32x4){0.f, 0.f, 0.f, 0.f};
      z = __builtin_amdgcn_mfma_f32_16x16x32_bf16(a0, kb0, z, 0, 0, 0);
      z = __builtin_amdgcn_mfma_f32_16x16x32_bf16(a1, kb1, z, 0, 0, 0);
#pragma unroll
      for (int t = 0; t < 4; ++t)
        wsum[st2][t] += __expf(z[t] - mv[t]) * izv[t];
    }
    if (k < 15) {
#pragma unroll
      for (int q = 0; q < 2; ++q)
        *(int4*)&Kst[cur ^ 1][(q * 256 + tid) * 8] = kreg[q];
    }
    __syncthreads();
  }
#pragma unroll
  for (int st2 = 0; st2 < 4; ++st2)
#pragma unroll
    for (int t = 0; t < 4; ++t) {
      const int l = l0 + w * 16 + lk * 4 + t;
      const int s = s0 + st2 * 16 + lr;
      Wmap[((size_t)l * 1024 + s) * 4 + n] = wsum[st2][t] * 0.0625f;
    }
}

// ---------------------------------------------------------------------------
extern "C" void kernel_launch(void* const* d_in, const int* in_sizes, int n_in,
                              void* d_out, int out_size, void* d_ws, size_t ws_size,
                              hipStream_t stream) {
  (void)in_sizes; (void)n_in; (void)out_size; (void)ws_size;
  const float* Q        = (const float*)d_in[0];
  const float* K        = (const float*)d_in[1];
  const float* V        = (const float*)d_in[2];
  const float* q_w      = (const float*)d_in[3];
  const float* k_w      = (const float*)d_in[4];
  const float* v_w      = (const float*)d_in[5];
  const float* out_w    = (const float*)d_in[6];
  const float* in_bias  = (const float*)d_in[7];
  const float* out_bias = (const float*)d_in[8];
  const float* attn_W   = (const float*)d_in[9];
  float* ws = (float*)d_ws;
  unsigned short* qw2bf = (unsigned short*)(ws + OFF_QW2BF);
  unsigned short* kwbf  = (unsigned short*)(ws + OFF_KWBF);
  unsigned short* vwbf  = (unsigned short*)(ws + OFF_VWBF);
  unsigned short* owtbf = (unsigned short*)(ws + OFF_OWTBF);
  float* qb2 = ws + OFF_QB2;
  unsigned short* Qwbf = (unsigned short*)(ws + OFF_QWBF);
  unsigned short* Khbf = (unsigned short*)(ws + OFF_KHBF);
  unsigned short* Vtbf = (unsigned short*)(ws + OFF_VTBF);
  float* st = ws + OFF_ST;
  unsigned short* Obf  = (unsigned short*)(ws + OFF_OBF);
  unsigned short* Abf  = (unsigned short*)(ws + OFF_ABF);
  float* out  = (float*)d_out;
  float* Wmap = out + 4194304;

  k_qw2<<<1024, 256, 0, stream>>>(q_w, attn_W, in_bias, qw2bf, qb2);
  k_cvt2<<<1024, 256, 0, stream>>>(k_w, v_w, kwbf, vwbf);
  k_cvtA<<<3072, 256, 0, stream>>>(Q, K, V, Abf);
  k_tr<<<dim3(16, 16), 256, 0, stream>>>(out_w, owtbf);
  k_gemm_in<<<768, 256, 0, stream>>>(Abf, qw2bf, kwbf, vwbf,
                                     qb2, in_bias + 1024, in_bias + 2048,
                                     Qwbf, Khbf, Vtbf);
  k_flash<<<1024, 256, 0, stream>>>(Qwbf, Khbf, Vtbf, st, Obf);
  k_wmap<<<1024, 256, 0, stream>>>(Qwbf, Khbf, st, Wmap);
  k_gemm_out<<<512, 256, 0, stream>>>(Obf, owtbf, out_bias, out);
}

// Round 10
// 196.555 us; speedup vs baseline: 1.6072x; 1.5351x over previous
//
#include <hip/hip_runtime.h>
#include <cstdint>

// Problem constants: L=S=1024, N=4, E=1024, H=16, D=64
typedef __bf16 bf16x8 __attribute__((ext_vector_type(8)));
typedef float f32x4 __attribute__((ext_vector_type(4)));

#define GLOAD_LDS16(gptr, lptr)                                              \
  __builtin_amdgcn_global_load_lds(                                          \
      (const __attribute__((address_space(1))) void*)(gptr),                 \
      (__attribute__((address_space(3))) void*)(lptr), 16, 0, 0)

// ws layout (float-unit offsets):
static const size_t OFF_QW2BF = 0;         // [k*64+i][j] bf16 (1M ushort)
static const size_t OFF_KWBF  = 524288;    // [k*64+i][j] bf16 (head-major)
static const size_t OFF_VWBF  = 1048576;   // [k*64+i][j] bf16 (head-major)
static const size_t OFF_OWTBF = 1572864;   // [o][j] bf16 (out_w^T)
static const size_t OFF_QB2   = 2097152;   // 1024 f32
static const size_t OFF_QWBF  = 2098176;   // [n][k][l][i] bf16 (4M ushort)
static const size_t OFF_KHBF  = 4195328;   // [n][k][s][i] bf16
static const size_t OFF_VTBF  = 6292480;   // [n][k][i][s] bf16 (V^T per head)
static const size_t OFF_ST    = 8389632;   // [n][k][l][{m,Z}] f32 131072
static const size_t OFF_OBF   = 8520704;   // [l*4+n][e] bf16 (4M ushort)
static const size_t OFF_ABF   = 10617856;  // [3][4096][1024] bf16 (12M ushort)

__device__ inline unsigned short f2bf(float f) {
  union { float f; unsigned u; } v; v.f = f;
  const unsigned r = v.u + 0x7FFFu + ((v.u >> 16) & 1u);   // RNE
  return (unsigned short)(r >> 16);
}

// ---------------------------------------------------------------------------
// K0: fold attn_W into q_w (bf16 out): qw2[(k,i),j] = sum_o q_w[o*16+k,j]*attn_W[o,i,k]/32
__global__ __launch_bounds__(256) void k_qw2(const float* __restrict__ qw,
    const float* __restrict__ attnW, const float* __restrict__ bias0,
    unsigned short* __restrict__ qw2, float* __restrict__ qb2) {
  const int b = blockIdx.x;          // = k*64 + i
  const int k = b >> 6, i = b & 63;
  const int tid = threadIdx.x;
  __shared__ float aw[64];
  if (tid < 64) aw[tid] = attnW[(tid * 64 + i) * 16 + k] * 0.03125f; // fold 1/sqrt(E)
  __syncthreads();
  for (int j = tid; j < 1024; j += 256) {
    float acc = 0.f;
#pragma unroll 8
    for (int o = 0; o < 64; ++o) acc = fmaf(qw[(o * 16 + k) * 1024 + j], aw[o], acc);
    qw2[(size_t)b * 1024 + j] = f2bf(acc);
  }
  if (tid == 0) {
    float acc = 0.f;
    for (int o = 0; o < 64; ++o) acc = fmaf(bias0[o * 16 + k], aw[o], acc);
    qb2[b] = acc;
  }
}

// ---------------------------------------------------------------------------
// Convert k_w and v_w to bf16 AND permute rows to head-major:
// dst row (k*64+i) = src row (i*16+k). One block per src row.
__global__ __launch_bounds__(256) void k_cvt2(const float* __restrict__ a,
    const float* __restrict__ b, unsigned short* __restrict__ oa,
    unsigned short* __restrict__ ob) {
  const int o = blockIdx.x;                    // src row 0..1023 (= i*16+k)
  const int dst = (o & 15) * 64 + (o >> 4);    // head-major row k*64+i
  const int j = threadIdx.x;                   // float4 index 0..255
  const float4 va = ((const float4*)(a + (size_t)o * 1024))[j];
  ushort4 ha; ha.x = f2bf(va.x); ha.y = f2bf(va.y); ha.z = f2bf(va.z); ha.w = f2bf(va.w);
  ((ushort4*)(oa + (size_t)dst * 1024))[j] = ha;
  const float4 vb = ((const float4*)(b + (size_t)o * 1024))[j];
  ushort4 hb; hb.x = f2bf(vb.x); hb.y = f2bf(vb.y); hb.z = f2bf(vb.z); hb.w = f2bf(vb.w);
  ((ushort4*)(ob + (size_t)dst * 1024))[j] = hb;
}

// ---------------------------------------------------------------------------
// Convert Q,K,V activations to bf16: Abf[m][4096][1024], m in {0,1,2}
__global__ __launch_bounds__(256) void k_cvtA(const float* __restrict__ Q,
    const float* __restrict__ K, const float* __restrict__ V,
    unsigned short* __restrict__ out) {
  const int b = blockIdx.x;                 // 0..3071
  const int m = b >> 10;
  const float* src = m == 0 ? Q : (m == 1 ? K : V);
  unsigned short* dst = out + (size_t)m * 4194304;
#pragma unroll
  for (int q = 0; q < 4; ++q) {
    const int idx = (b & 1023) * 1024 + q * 256 + threadIdx.x;
    const float4 v = ((const float4*)src)[idx];
    ushort4 h; h.x = f2bf(v.x); h.y = f2bf(v.y); h.z = f2bf(v.z); h.w = f2bf(v.w);
    ((ushort4*)dst)[idx] = h;
  }
}

// ---------------------------------------------------------------------------
// Transpose out_w [j][o] -> owT [o][j] bf16
__global__ __launch_bounds__(256) void k_tr(const float* __restrict__ w,
    unsigned short* __restrict__ wt) {
  __shared__ float t[64][65];
  const int j0 = blockIdx.y * 64, o0 = blockIdx.x * 64;
  const int tid = threadIdx.x;
  const int r = tid >> 4, c4 = tid & 15;
#pragma unroll
  for (int q = 0; q < 4; ++q) {
    const int row = r + q * 16;
    const float4 v = *(const float4*)&w[(size_t)(j0 + row) * 1024 + o0 + c4 * 4];
    t[row][c4 * 4 + 0] = v.x; t[row][c4 * 4 + 1] = v.y;
    t[row][c4 * 4 + 2] = v.z; t[row][c4 * 4 + 3] = v.w;
  }
  __syncthreads();
#pragma unroll
  for (int q = 0; q < 4; ++q) {
    const int orow = r + q * 16;
    ushort4 h;
    h.x = f2bf(t[c4 * 4 + 0][orow]); h.y = f2bf(t[c4 * 4 + 1][orow]);
    h.z = f2bf(t[c4 * 4 + 2][orow]); h.w = f2bf(t[c4 * 4 + 3][orow]);
    *(ushort4*)&wt[(size_t)(o0 + orow) * 1024 + j0 + c4 * 4] = h;
  }
}

// ---------------------------------------------------------------------------
// Merged in-projection GEMMs v5: m97 structure — global_load_lds (16B) direct
// global->LDS staging (no VGPR round trip => no spill; fixes R8/R9's 270MB
// scratch WRITE_SIZE), single 32KB buffer, 2 barriers/step, BK=64 flash-proven
// swizzle (pre-swizzled source, linear LDS, swizzled b128 reads, 0 conflicts).
// bz=0: Qw[n][kk][l][ii]; bz=1: Kh[n][kk][s][ii]; bz=2: Vt[n][kk][ii][s].
__global__ __launch_bounds__(256) void k_gemm_in(
    const unsigned short* __restrict__ Abf, const unsigned short* __restrict__ Bq,
    const unsigned short* __restrict__ Bk, const unsigned short* __restrict__ Bv,
    const float* __restrict__ bq, const float* __restrict__ bk,
    const float* __restrict__ bv, unsigned short* __restrict__ Cq,
    unsigned short* __restrict__ Ck, unsigned short* __restrict__ Cv) {
  __shared__ unsigned short As[128 * 64];
  __shared__ unsigned short Bs[128 * 64];
  const int id = blockIdx.x;                     // 0..767
  const int g  = (id & 7) + ((id >> 6) << 3);    // 0..95 (A-panel group)
  const int bx = (id >> 3) & 7;                  // o-block
  const int by = g & 31, bz = g >> 5;
  const unsigned short* A = Abf + (size_t)bz * 4194304;
  const unsigned short* B = bz == 0 ? Bq : (bz == 1 ? Bk : Bv);
  const float* bias       = bz == 0 ? bq : (bz == 1 ? bk : bv);
  unsigned short* C       = bz == 0 ? Cq : (bz == 1 ? Ck : Cv);
  const int m0 = by * 128, o0 = bx * 128;
  const int tid = threadIdx.x;
  const int wid = tid >> 6, lane = tid & 63;
  const int wr = wid >> 1, wc = wid & 1;
  const int lr = lane & 15, lk = lane >> 4;
  int srow[4], scol[4];
#pragma unroll
  for (int q = 0; q < 4; ++q) {
    const int idx = q * 256 + tid;
    srow[q] = idx >> 3;
    scol[q] = (((idx & 7) ^ ((idx >> 3) & 7)) << 3);
  }
  f32x4 acc[4][4];
#pragma unroll
  for (int i = 0; i < 4; ++i)
#pragma unroll
    for (int j = 0; j < 4; ++j) acc[i][j] = (f32x4){0.f, 0.f, 0.f, 0.f};

  for (int t = 0; t < 16; ++t) {
    const int kb = t * 64;
#pragma unroll
    for (int q = 0; q < 4; ++q) {
      GLOAD_LDS16(&A[(size_t)(m0 + srow[q]) * 1024 + kb + scol[q]],
                  &As[(q * 256 + tid) * 8]);
      GLOAD_LDS16(&B[(size_t)(o0 + srow[q]) * 1024 + kb + scol[q]],
                  &Bs[(q * 256 + tid) * 8]);
    }
    __syncthreads();   // compiler drains vmcnt before barrier -> LDS valid
#pragma unroll
    for (int ph = 0; ph < 2; ++ph) {
      const int ck = ph * 4 + lk;
      bf16x8 af[4], bfr[4];
#pragma unroll
      for (int f = 0; f < 4; ++f) {
        const int ra = wr * 64 + f * 16 + lr;
        af[f] = *(const bf16x8*)&As[ra * 64 + ((ck ^ (ra & 7)) << 3)];
        const int rb = wc * 64 + f * 16 + lr;
        bfr[f] = *(const bf16x8*)&Bs[rb * 64 + ((ck ^ (rb & 7)) << 3)];
      }
#pragma unroll
      for (int i = 0; i < 4; ++i)
#pragma unroll
        for (int j = 0; j < 4; ++j)
          acc[i][j] = __builtin_amdgcn_mfma_f32_16x16x32_bf16(af[i], bfr[j], acc[i][j], 0, 0, 0);
    }
    __syncthreads();   // reads done before next tile's loads land
  }
#pragma unroll
  for (int fi = 0; fi < 4; ++fi)
#pragma unroll
    for (int fj = 0; fj < 4; ++fj) {
      const int o = o0 + wc * 64 + fj * 16 + lr;
      const int kk = o >> 6, ii = o & 63;
      const float bo = bz == 0 ? bias[o] : bias[ii * 16 + kk];
#pragma unroll
      for (int t = 0; t < 4; ++t) {
        const int m = m0 + wr * 64 + fi * 16 + lk * 4 + t;
        const float v = acc[fi][fj][t] + bo;
        const int l = m >> 2, nn = m & 3;
        if (bz <= 1) {
          C[(((size_t)(nn * 16 + kk) * 1024 + l) << 6) + ii] = f2bf(v);
        } else {
          C[(((size_t)(nn * 16 + kk) * 64 + ii) << 10) + l] = f2bf(v);
        }
      }
    }
}

// ---------------------------------------------------------------------------
// Out-projection GEMM v4: 64x128 tile, BK=64, global_load_lds staging (same
// m97 structure as k_gemm_in). f32 out. Same XCD-chunked id swizzle.
__global__ __launch_bounds__(256) void k_gemm_out(
    const unsigned short* __restrict__ A, const unsigned short* __restrict__ B,
    const float* __restrict__ bias, float* __restrict__ C) {
  __shared__ unsigned short As[64 * 64];
  __shared__ unsigned short Bs[128 * 64];
  const int id = blockIdx.x;                     // 0..511
  const int g  = (id & 7) + ((id >> 6) << 3);    // 0..63 m-block
  const int bx = (id >> 3) & 7;                  // o-block
  const int m0 = g * 64, o0 = bx * 128;
  const int tid = threadIdx.x;
  const int wid = tid >> 6, lane = tid & 63;
  const int wr = wid >> 1, wc = wid & 1;
  const int lr = lane & 15, lk = lane >> 4;
  int srow[4], scol[4];
#pragma unroll
  for (int q = 0; q < 4; ++q) {
    const int idx = q * 256 + tid;
    srow[q] = idx >> 3;
    scol[q] = (((idx & 7) ^ ((idx >> 3) & 7)) << 3);
  }
  f32x4 acc[2][4];
#pragma unroll
  for (int i = 0; i < 2; ++i)
#pragma unroll
    for (int j = 0; j < 4; ++j) acc[i][j] = (f32x4){0.f, 0.f, 0.f, 0.f};

  for (int t = 0; t < 16; ++t) {
    const int kb = t * 64;
#pragma unroll
    for (int q = 0; q < 2; ++q)
      GLOAD_LDS16(&A[(size_t)(m0 + srow[q]) * 1024 + kb + scol[q]],
                  &As[(q * 256 + tid) * 8]);
#pragma unroll
    for (int q = 0; q < 4; ++q)
      GLOAD_LDS16(&B[(size_t)(o0 + srow[q]) * 1024 + kb + scol[q]],
                  &Bs[(q * 256 + tid) * 8]);
    __syncthreads();
#pragma unroll
    for (int ph = 0; ph < 2; ++ph) {
      const int ck = ph * 4 + lk;
      bf16x8 af[2], bfr[4];
#pragma unroll
      for (int f = 0; f < 2; ++f) {
        const int ra = wr * 32 + f * 16 + lr;
        af[f] = *(const bf16x8*)&As[ra * 64 + ((ck ^ (ra & 7)) << 3)];
      }
#pragma unroll
      for (int f = 0; f < 4; ++f) {
        const int rb = wc * 64 + f * 16 + lr;
        bfr[f] = *(const bf16x8*)&Bs[rb * 64 + ((ck ^ (rb & 7)) << 3)];
      }
#pragma unroll
      for (int i = 0; i < 2; ++i)
#pragma unroll
        for (int j = 0; j < 4; ++j)
          acc[i][j] = __builtin_amdgcn_mfma_f32_16x16x32_bf16(af[i], bfr[j], acc[i][j], 0, 0, 0);
    }
    __syncthreads();
  }
#pragma unroll
  for (int fi = 0; fi < 2; ++fi)
#pragma unroll
    for (int fj = 0; fj < 4; ++fj) {
      const int o = o0 + wc * 64 + fj * 16 + lr;
      const float bo = bias[o];
#pragma unroll
      for (int t = 0; t < 4; ++t) {
        const int m = m0 + wr * 32 + fi * 16 + lk * 4 + t;
        C[(size_t)m * 1024 + o] = acc[fi][fj][t] + bo;
      }
    }
}

// ---------------------------------------------------------------------------
// MFMA flash v5 (unchanged): per (n,k,l-tile=64); 4 waves x 16 q-rows.
__global__ __launch_bounds__(256) void k_flash(
    const unsigned short* __restrict__ Qbf, const unsigned short* __restrict__ Khbf,
    const unsigned short* __restrict__ Vtbf, float* __restrict__ stats,
    unsigned short* __restrict__ Obf) {
  __shared__ unsigned short Kd[2][64 * 64];
  __shared__ unsigned short Vd[2][64 * 64];
  __shared__ unsigned short Ps[4][16 * 64];
  const int ob = blockIdx.x;
  const int b = (ob & 7) * 128 + (ob >> 3);   // bijective XCD swizzle
  const int lt = b & 15, k = (b >> 4) & 15, n = b >> 8;
  const int l0 = lt * 64;
  const int tid = threadIdx.x, w = tid >> 6, lane = tid & 63;
  const int lr = lane & 15, lk = lane >> 4;
  const size_t hb = (size_t)(n * 16 + k) * 65536;
  const unsigned short* qrow = Qbf + hb + (size_t)(l0 + w * 16 + lr) * 64;
  const bf16x8 qa0 = *(const bf16x8*)(qrow + lk * 8);
  const bf16x8 qa1 = *(const bf16x8*)(qrow + 32 + lk * 8);
  const int swz = lr & 7;
  int srow[2], scol[2];
#pragma unroll
  for (int q = 0; q < 2; ++q) {
    const int idx = q * 256 + tid;
    srow[q] = idx >> 3;
    scol[q] = (((idx & 7) ^ ((idx >> 3) & 7)) << 3);
  }
  const unsigned short* Kb = Khbf + hb;
  const unsigned short* Vb = Vtbf + hb;
  int4 kreg[2], vreg[2];
#pragma unroll
  for (int q = 0; q < 2; ++q) {
    kreg[q] = *(const int4*)(Kb + (size_t)srow[q] * 64 + scol[q]);
    vreg[q] = *(const int4*)(Vb + (size_t)srow[q] * 1024 + scol[q]);
  }
#pragma unroll
  for (int q = 0; q < 2; ++q) {
    *(int4*)&Kd[0][(q * 256 + tid) * 8] = kreg[q];
    *(int4*)&Vd[0][(q * 256 + tid) * 8] = vreg[q];
  }
  float m_ = -1e30f, Z_ = 0.f;
  f32x4 oacc[4];
#pragma unroll
  for (int it = 0; it < 4; ++it) oacc[it] = (f32x4){0.f, 0.f, 0.f, 0.f};
  __syncthreads();

  for (int t0 = 0; t0 < 16; ++t0) {
    const int cur = t0 & 1;
    if (t0 < 15) {
      const int s1 = (t0 + 1) * 64;
#pragma unroll
      for (int q = 0; q < 2; ++q) {
        kreg[q] = *(const int4*)(Kb + (size_t)(s1 + srow[q]) * 64 + scol[q]);
        vreg[q] = *(const int4*)(Vb + (size_t)srow[q] * 1024 + s1 + scol[q]);
      }
    }
    f32x4 sc[4];
#pragma unroll
    for (int st = 0; st < 4; ++st) {
      const int r = st * 16 + lr;
      const bf16x8 kb0 = *(const bf16x8*)&Kd[cur][r * 64 + ((lk ^ (r & 7)) << 3)];
      const bf16x8 kb1 = *(const bf16x8*)&Kd[cur][r * 64 + (((4 + lk) ^ (r & 7)) << 3)];
      f32x4 z = (f32x4){0.f, 0.f, 0.f, 0.f};
      z = __builtin_amdgcn_mfma_f32_16x16x32_bf16(kb0, qa0, z, 0, 0, 0);
      sc[st] = __builtin_amdgcn_mfma_f32_16x16x32_bf16(kb1, qa1, z, 0, 0, 0);
    }
    float tm = fmaxf(fmaxf(fmaxf(sc[0][0], sc[0][1]), fmaxf(sc[0][2], sc[0][3])),
                     fmaxf(fmaxf(sc[1][0], sc[1][1]), fmaxf(sc[1][2], sc[1][3])));
    tm = fmaxf(tm, fmaxf(fmaxf(fmaxf(sc[2][0], sc[2][1]), fmaxf(sc[2][2], sc[2][3])),
                         fmaxf(fmaxf(sc[3][0], sc[3][1]), fmaxf(sc[3][2], sc[3][3]))));
    tm = fmaxf(tm, __shfl_xor(tm, 16));
    tm = fmaxf(tm, __shfl_xor(tm, 32));
    const float mn = fmaxf(m_, tm);
    const float fac = __expf(m_ - mn);
    m_ = mn;
    float rs = 0.f;
    float p[4][4];
#pragma unroll
    for (int st = 0; st < 4; ++st)
#pragma unroll
      for (int t = 0; t < 4; ++t) {
        p[st][t] = __expf(sc[st][t] - mn);
        rs += p[st][t];
      }
    rs += __shfl_xor(rs, 16);
    rs += __shfl_xor(rs, 32);
    Z_ = Z_ * fac + rs;
#pragma unroll
    for (int st = 0; st < 4; ++st) {
      ushort4 pk;
      pk.x = f2bf(p[st][0]); pk.y = f2bf(p[st][1]);
      pk.z = f2bf(p[st][2]); pk.w = f2bf(p[st][3]);
      const int c = (st * 4 + lk) ^ (swz << 1);
      *(ushort4*)&Ps[w][lr * 64 + c * 4] = pk;
    }
    float fr[4];
#pragma unroll
    for (int t = 0; t < 4; ++t) fr[t] = __shfl(fac, lk * 4 + t);
    const f32x4 facv = {fr[0], fr[1], fr[2], fr[3]};
    const bf16x8 pa0 = *(const bf16x8*)&Ps[w][lr * 64 + ((lk ^ swz) << 3)];
    const bf16x8 pa1 = *(const bf16x8*)&Ps[w][lr * 64 + (((4 + lk) ^ swz) << 3)];
#pragma unroll
    for (int it = 0; it < 4; ++it) {
      const int r = it * 16 + lr;
      const bf16x8 bv0 = *(const bf16x8*)&Vd[cur][r * 64 + ((lk ^ (r & 7)) << 3)];
      const bf16x8 bv1 = *(const bf16x8*)&Vd[cur][r * 64 + (((4 + lk) ^ (r & 7)) << 3)];
      f32x4 o = oacc[it] * facv;
      o = __builtin_amdgcn_mfma_f32_16x16x32_bf16(pa0, bv0, o, 0, 0, 0);
      oacc[it] = __builtin_amdgcn_mfma_f32_16x16x32_bf16(pa1, bv1, o, 0, 0, 0);
    }
    if (t0 < 15) {
#pragma unroll
      for (int q = 0; q < 2; ++q) {
        *(int4*)&Kd[cur ^ 1][(q * 256 + tid) * 8] = kreg[q];
        *(int4*)&Vd[cur ^ 1][(q * 256 + tid) * 8] = vreg[q];
      }
    }
    __syncthreads();
  }

  if (lane < 16) {
    const size_t so = ((size_t)(n * 16 + k) * 1024 + l0 + w * 16 + lr) * 2;
    stats[so] = m_;
    stats[so + 1] = Z_;
  }
  const float iz = 1.f / Z_;
  float izr[4];
#pragma unroll
  for (int t = 0; t < 4; ++t) izr[t] = __shfl(iz, lk * 4 + t);
#pragma unroll
  for (int it = 0; it < 4; ++it)
#pragma unroll
    for (int t = 0; t < 4; ++t) {
      const int l = l0 + w * 16 + lk * 4 + t;
      const int i = it * 16 + lr;
      Obf[(size_t)(l * 4 + n) * 1024 + i * 16 + k] = f2bf(oacc[it][t] * izr[t]);
    }
}

// ---------------------------------------------------------------------------
// Wmap v4 (unchanged).
__global__ __launch_bounds__(256) void k_wmap(const unsigned short* __restrict__ Qbf,
    const unsigned short* __restrict__ Khbf, const float* __restrict__ stats,
    float* __restrict__ Wmap) {
  __shared__ unsigned short Kst[2][64 * 64];
  const int ob = blockIdx.x;
  const int b = (ob & 7) * 128 + (ob >> 3);
  const int st = b & 15, lt = (b >> 4) & 15, n = b >> 8;
  const int l0 = lt * 64, s0 = st * 64;
  const int tid = threadIdx.x, w = tid >> 6, lane = tid & 63;
  const int lr = lane & 15, lk = lane >> 4;
  int srow[2], scol[2];
#pragma unroll
  for (int q = 0; q < 2; ++q) {
    const int idx = q * 256 + tid;
    srow[q] = idx >> 3;
    scol[q] = (((idx & 7) ^ ((idx >> 3) & 7)) << 3);
  }
  int4 kreg[2];
#pragma unroll
  for (int q = 0; q < 2; ++q)
    kreg[q] = *(const int4*)(Khbf + (size_t)(n * 16) * 65536 +
                             (size_t)(s0 + srow[q]) * 64 + scol[q]);
#pragma unroll
  for (int q = 0; q < 2; ++q)
    *(int4*)&Kst[0][(q * 256 + tid) * 8] = kreg[q];
  f32x4 wsum[4];
#pragma unroll
  for (int i = 0; i < 4; ++i) wsum[i] = (f32x4){0.f, 0.f, 0.f, 0.f};
  __syncthreads();

  for (int k = 0; k < 16; ++k) {
    const int cur = k & 1;
    const size_t hb = (size_t)(n * 16 + k) * 65536;
    if (k < 15) {
      const size_t hb1 = (size_t)(n * 16 + k + 1) * 65536;
#pragma unroll
      for (int q = 0; q < 2; ++q)
        kreg[q] = *(const int4*)(Khbf + hb1 + (size_t)(s0 + srow[q]) * 64 + scol[q]);
    }
    const unsigned short* qrow = Qbf + hb + (size_t)(l0 + w * 16 + lr) * 64;
    const bf16x8 a0 = *(const bf16x8*)(qrow + lk * 8);
    const bf16x8 a1 = *(const bf16x8*)(qrow + 32 + lk * 8);
    float mv[4], izv[4];
#pragma unroll
    for (int t = 0; t < 4; ++t) {
      const float2 mz = *(const float2*)(stats +
          ((size_t)(n * 16 + k) * 1024 + l0 + w * 16 + lk * 4 + t) * 2);
      mv[t] = mz.x; izv[t] = 1.f / mz.y;
    }
#pragma unroll
    for (int st2 = 0; st2 < 4; ++st2) {
      const int r = st2 * 16 + lr;
      const bf16x8 kb0 = *(const bf16x8*)&Kst[cur][r * 64 + ((lk ^ (r & 7)) << 3)];
      const bf16x8 kb1 = *(const bf16x8*)&Kst[cur][r * 64 + (((4 + lk) ^ (r & 7)) << 3)];
      f32x4 z = (f32x4){0.f, 0.f, 0.f, 0.f};
      z = __builtin_amdgcn_mfma_f32_16x16x32_bf16(a0, kb0, z, 0, 0, 0);
      z = __builtin_amdgcn_mfma_f32_16x16x32_bf16(a1, kb1, z, 0, 0, 0);
#pragma unroll
      for (int t = 0; t < 4; ++t)
        wsum[st2][t] += __expf(z[t] - mv[t]) * izv[t];
    }
    if (k < 15) {
#pragma unroll
      for (int q = 0; q < 2; ++q)
        *(int4*)&Kst[cur ^ 1][(q * 256 + tid) * 8] = kreg[q];
    }
    __syncthreads();
  }
#pragma unroll
  for (int st2 = 0; st2 < 4; ++st2)
#pragma unroll
    for (int t = 0; t < 4; ++t) {
      const int l = l0 + w * 16 + lk * 4 + t;
      const int s = s0 + st2 * 16 + lr;
      Wmap[((size_t)l * 1024 + s) * 4 + n] = wsum[st2][t] * 0.0625f;
    }
}

// ---------------------------------------------------------------------------
extern "C" void kernel_launch(void* const* d_in, const int* in_sizes, int n_in,
                              void* d_out, int out_size, void* d_ws, size_t ws_size,
                              hipStream_t stream) {
  (void)in_sizes; (void)n_in; (void)out_size; (void)ws_size;
  const float* Q        = (const float*)d_in[0];
  const float* K        = (const float*)d_in[1];
  const float* V        = (const float*)d_in[2];
  const float* q_w      = (const float*)d_in[3];
  const float* k_w      = (const float*)d_in[4];
  const float* v_w      = (const float*)d_in[5];
  const float* out_w    = (const float*)d_in[6];
  const float* in_bias  = (const float*)d_in[7];
  const float* out_bias = (const float*)d_in[8];
  const float* attn_W   = (const float*)d_in[9];
  float* ws = (float*)d_ws;
  unsigned short* qw2bf = (unsigned short*)(ws + OFF_QW2BF);
  unsigned short* kwbf  = (unsigned short*)(ws + OFF_KWBF);
  unsigned short* vwbf  = (unsigned short*)(ws + OFF_VWBF);
  unsigned short* owtbf = (unsigned short*)(ws + OFF_OWTBF);
  float* qb2 = ws + OFF_QB2;
  unsigned short* Qwbf = (unsigned short*)(ws + OFF_QWBF);
  unsigned short* Khbf = (unsigned short*)(ws + OFF_KHBF);
  unsigned short* Vtbf = (unsigned short*)(ws + OFF_VTBF);
  float* st = ws + OFF_ST;
  unsigned short* Obf  = (unsigned short*)(ws + OFF_OBF);
  unsigned short* Abf  = (unsigned short*)(ws + OFF_ABF);
  float* out  = (float*)d_out;
  float* Wmap = out + 4194304;

  k_qw2<<<1024, 256, 0, stream>>>(q_w, attn_W, in_bias, qw2bf, qb2);
  k_cvt2<<<1024, 256, 0, stream>>>(k_w, v_w, kwbf, vwbf);
  k_cvtA<<<3072, 256, 0, stream>>>(Q, K, V, Abf);
  k_tr<<<dim3(16, 16), 256, 0, stream>>>(out_w, owtbf);
  k_gemm_in<<<768, 256, 0, stream>>>(Abf, qw2bf, kwbf, vwbf,
                                     qb2, in_bias + 1024, in_bias + 2048,
                                     Qwbf, Khbf, Vtbf);
  k_flash<<<1024, 256, 0, stream>>>(Qwbf, Khbf, Vtbf, st, Obf);
  k_wmap<<<1024, 256, 0, stream>>>(Qwbf, Khbf, st, Wmap);
  k_gemm_out<<<512, 256, 0, stream>>>(Obf, owtbf, out_bias, out);
}

// Round 11
// 181.376 us; speedup vs baseline: 1.7417x; 1.0837x over previous
//
#include <hip/hip_runtime.h>
#include <cstdint>

// Problem constants: L=S=1024, N=4, E=1024, H=16, D=64
typedef __bf16 bf16x8 __attribute__((ext_vector_type(8)));
typedef float f32x4 __attribute__((ext_vector_type(4)));

#define GLOAD_LDS16(gptr, lptr)                                              \
  __builtin_amdgcn_global_load_lds(                                          \
      (const __attribute__((address_space(1))) void*)(gptr),                 \
      (__attribute__((address_space(3))) void*)(lptr), 16, 0, 0)

// ws layout (float-unit offsets):
static const size_t OFF_QW2BF = 0;         // [k*64+i][j] bf16 (1M ushort)
static const size_t OFF_KWBF  = 524288;    // [k*64+i][j] bf16 (head-major)
static const size_t OFF_VWBF  = 1048576;   // [k*64+i][j] bf16 (head-major)
static const size_t OFF_OWTBF = 1572864;   // [o][j] bf16 (out_w^T)
static const size_t OFF_QB2   = 2097152;   // 1024 f32
static const size_t OFF_QWBF  = 2098176;   // [n][k][l][i] bf16 (4M ushort)
static const size_t OFF_KHBF  = 4195328;   // [n][k][s][i] bf16
static const size_t OFF_VTBF  = 6292480;   // [n][k][i][s] bf16 (V^T per head)
static const size_t OFF_ST    = 8389632;   // [n][k][l][{m,Z}] f32 131072
static const size_t OFF_OBF   = 8520704;   // [l*4+n][e] bf16 (4M ushort)
static const size_t OFF_ABF   = 10617856;  // [3][4096][1024] bf16 (12M ushort)

__device__ inline unsigned short f2bf(float f) {
  union { float f; unsigned u; } v; v.f = f;
  const unsigned r = v.u + 0x7FFFu + ((v.u >> 16) & 1u);   // RNE
  return (unsigned short)(r >> 16);
}

// ---------------------------------------------------------------------------
// Fused prep: blocks [0,1024) qw2-fold; [1024,2048) k_w/v_w cvt+permute;
// [2048,5120) Q/K/V f32->bf16; [5120,5376) out_w transpose.
__global__ __launch_bounds__(256) void k_prep(const float* __restrict__ Q,
    const float* __restrict__ K, const float* __restrict__ V,
    const float* __restrict__ qw, const float* __restrict__ kw,
    const float* __restrict__ vw, const float* __restrict__ ow,
    const float* __restrict__ attnW, const float* __restrict__ in_bias,
    unsigned short* __restrict__ qw2, float* __restrict__ qb2,
    unsigned short* __restrict__ kwbf, unsigned short* __restrict__ vwbf,
    unsigned short* __restrict__ owtbf, unsigned short* __restrict__ Abf) {
  __shared__ float sh[64 * 65];
  const int b = blockIdx.x;
  const int tid = threadIdx.x;
  if (b < 1024) {
    // qw2[(k,i),j] = sum_o qw[o*16+k,j]*attnW[o,i,k]/32
    const int k = b >> 6, i = b & 63;
    if (tid < 64) sh[tid] = attnW[(tid * 64 + i) * 16 + k] * 0.03125f;
    __syncthreads();
    for (int j = tid; j < 1024; j += 256) {
      float acc = 0.f;
#pragma unroll 8
      for (int o = 0; o < 64; ++o) acc = fmaf(qw[(o * 16 + k) * 1024 + j], sh[o], acc);
      qw2[(size_t)b * 1024 + j] = f2bf(acc);
    }
    if (tid == 0) {
      float acc = 0.f;
      for (int o = 0; o < 64; ++o) acc = fmaf(in_bias[o * 16 + k], sh[o], acc);
      qb2[b] = acc;
    }
  } else if (b < 2048) {
    // cvt2 + head-major permute: dst row (k*64+i) = src row (i*16+k)
    const int o = b - 1024;
    const int dst = (o & 15) * 64 + (o >> 4);
    const float4 va = ((const float4*)(kw + (size_t)o * 1024))[tid];
    ushort4 ha; ha.x = f2bf(va.x); ha.y = f2bf(va.y); ha.z = f2bf(va.z); ha.w = f2bf(va.w);
    ((ushort4*)(kwbf + (size_t)dst * 1024))[tid] = ha;
    const float4 vb = ((const float4*)(vw + (size_t)o * 1024))[tid];
    ushort4 hb; hb.x = f2bf(vb.x); hb.y = f2bf(vb.y); hb.z = f2bf(vb.z); hb.w = f2bf(vb.w);
    ((ushort4*)(vwbf + (size_t)dst * 1024))[tid] = hb;
  } else if (b < 5120) {
    // cvtA: Q/K/V f32 -> bf16
    const int bb = b - 2048;
    const int m = bb >> 10;
    const float* src = m == 0 ? Q : (m == 1 ? K : V);
    unsigned short* dst = Abf + (size_t)m * 4194304;
#pragma unroll
    for (int q = 0; q < 4; ++q) {
      const int idx = (bb & 1023) * 1024 + q * 256 + tid;
      const float4 v = ((const float4*)src)[idx];
      ushort4 h; h.x = f2bf(v.x); h.y = f2bf(v.y); h.z = f2bf(v.z); h.w = f2bf(v.w);
      ((ushort4*)dst)[idx] = h;
    }
  } else {
    // tr: out_w [j][o] -> owT [o][j]
    float (*t)[65] = (float(*)[65])sh;
    const int tb = b - 5120;
    const int o0 = (tb & 15) * 64, j0 = (tb >> 4) * 64;
    const int r = tid >> 4, c4 = tid & 15;
#pragma unroll
    for (int q = 0; q < 4; ++q) {
      const int row = r + q * 16;
      const float4 v = *(const float4*)&ow[(size_t)(j0 + row) * 1024 + o0 + c4 * 4];
      t[row][c4 * 4 + 0] = v.x; t[row][c4 * 4 + 1] = v.y;
      t[row][c4 * 4 + 2] = v.z; t[row][c4 * 4 + 3] = v.w;
    }
    __syncthreads();
#pragma unroll
    for (int q = 0; q < 4; ++q) {
      const int orow = r + q * 16;
      ushort4 h;
      h.x = f2bf(t[c4 * 4 + 0][orow]); h.y = f2bf(t[c4 * 4 + 1][orow]);
      h.z = f2bf(t[c4 * 4 + 2][orow]); h.w = f2bf(t[c4 * 4 + 3][orow]);
      *(ushort4*)&owtbf[(size_t)(o0 + orow) * 1024 + j0 + c4 * 4] = h;
    }
  }
}

// ---------------------------------------------------------------------------
// Merged in-projection GEMMs v6: global_load_lds + LDS DOUBLE buffer with
// counted vmcnt (T4): per iter, issue next tile's 8 loads into buf^1, then
// s_waitcnt vmcnt(8) (waits the 8 OLDEST = current tile; per-wave, before
// barrier so after barrier all waves' tiles landed), raw s_barrier, MFMA on
// buf, s_barrier (protects buf^1 overwrite vs lagging readers). Prefetch
// loads stay in flight across the barrier - removes the vmcnt(0) drain stall.
__global__ __launch_bounds__(256) void k_gemm_in(
    const unsigned short* __restrict__ Abf, const unsigned short* __restrict__ Bq,
    const unsigned short* __restrict__ Bk, const unsigned short* __restrict__ Bv,
    const float* __restrict__ bq, const float* __restrict__ bk,
    const float* __restrict__ bv, unsigned short* __restrict__ Cq,
    unsigned short* __restrict__ Ck, unsigned short* __restrict__ Cv) {
  __shared__ unsigned short As[2][128 * 64];
  __shared__ unsigned short Bs[2][128 * 64];
  const int id = blockIdx.x;                     // 0..767
  const int g  = (id & 7) + ((id >> 6) << 3);    // 0..95 (A-panel group)
  const int bx = (id >> 3) & 7;                  // o-block
  const int by = g & 31, bz = g >> 5;
  const unsigned short* A = Abf + (size_t)bz * 4194304;
  const unsigned short* B = bz == 0 ? Bq : (bz == 1 ? Bk : Bv);
  const float* bias       = bz == 0 ? bq : (bz == 1 ? bk : bv);
  unsigned short* C       = bz == 0 ? Cq : (bz == 1 ? Ck : Cv);
  const int m0 = by * 128, o0 = bx * 128;
  const int tid = threadIdx.x;
  const int wid = tid >> 6, lane = tid & 63;
  const int wr = wid >> 1, wc = wid & 1;
  const int lr = lane & 15, lk = lane >> 4;
  int srow[4], scol[4];
#pragma unroll
  for (int q = 0; q < 4; ++q) {
    const int idx = q * 256 + tid;
    srow[q] = idx >> 3;
    scol[q] = (((idx & 7) ^ ((idx >> 3) & 7)) << 3);
  }
  f32x4 acc[4][4];
#pragma unroll
  for (int i = 0; i < 4; ++i)
#pragma unroll
    for (int j = 0; j < 4; ++j) acc[i][j] = (f32x4){0.f, 0.f, 0.f, 0.f};

  // prologue: stage tile 0 into buf 0
#pragma unroll
  for (int q = 0; q < 4; ++q) {
    GLOAD_LDS16(&A[(size_t)(m0 + srow[q]) * 1024 + scol[q]], &As[0][(q * 256 + tid) * 8]);
    GLOAD_LDS16(&B[(size_t)(o0 + srow[q]) * 1024 + scol[q]], &Bs[0][(q * 256 + tid) * 8]);
  }

  for (int t = 0; t < 16; ++t) {
    const int cur = t & 1;
    if (t < 15) {
      const int kb = (t + 1) * 64;
#pragma unroll
      for (int q = 0; q < 4; ++q) {
        GLOAD_LDS16(&A[(size_t)(m0 + srow[q]) * 1024 + kb + scol[q]],
                    &As[cur ^ 1][(q * 256 + tid) * 8]);
        GLOAD_LDS16(&B[(size_t)(o0 + srow[q]) * 1024 + kb + scol[q]],
                    &Bs[cur ^ 1][(q * 256 + tid) * 8]);
      }
      asm volatile("s_waitcnt vmcnt(8)" ::: "memory");   // oldest 8 (cur tile) done
    } else {
      asm volatile("s_waitcnt vmcnt(0)" ::: "memory");
    }
    __builtin_amdgcn_s_barrier();
#pragma unroll
    for (int ph = 0; ph < 2; ++ph) {
      const int ck = ph * 4 + lk;
      bf16x8 af[4], bfr[4];
#pragma unroll
      for (int f = 0; f < 4; ++f) {
        const int ra = wr * 64 + f * 16 + lr;
        af[f] = *(const bf16x8*)&As[cur][ra * 64 + ((ck ^ (ra & 7)) << 3)];
        const int rb = wc * 64 + f * 16 + lr;
        bfr[f] = *(const bf16x8*)&Bs[cur][rb * 64 + ((ck ^ (rb & 7)) << 3)];
      }
#pragma unroll
      for (int i = 0; i < 4; ++i)
#pragma unroll
        for (int j = 0; j < 4; ++j)
          acc[i][j] = __builtin_amdgcn_mfma_f32_16x16x32_bf16(af[i], bfr[j], acc[i][j], 0, 0, 0);
    }
    __builtin_amdgcn_s_barrier();   // readers done before buf^1 gets overwritten
  }
#pragma unroll
  for (int fi = 0; fi < 4; ++fi)
#pragma unroll
    for (int fj = 0; fj < 4; ++fj) {
      const int o = o0 + wc * 64 + fj * 16 + lr;
      const int kk = o >> 6, ii = o & 63;
      const float bo = bz == 0 ? bias[o] : bias[ii * 16 + kk];
#pragma unroll
      for (int t = 0; t < 4; ++t) {
        const int m = m0 + wr * 64 + fi * 16 + lk * 4 + t;
        const float v = acc[fi][fj][t] + bo;
        const int l = m >> 2, nn = m & 3;
        if (bz <= 1) {
          C[(((size_t)(nn * 16 + kk) * 1024 + l) << 6) + ii] = f2bf(v);
        } else {
          C[(((size_t)(nn * 16 + kk) * 64 + ii) << 10) + l] = f2bf(v);
        }
      }
    }
}

// ---------------------------------------------------------------------------
// Out-projection GEMM v5: 64x128 tile, same counted-vmcnt dbuf structure
// (6 loads/iter -> vmcnt(6)). f32 out. Same XCD-chunked id swizzle.
__global__ __launch_bounds__(256) void k_gemm_out(
    const unsigned short* __restrict__ A, const unsigned short* __restrict__ B,
    const float* __restrict__ bias, float* __restrict__ C) {
  __shared__ unsigned short As[2][64 * 64];
  __shared__ unsigned short Bs[2][128 * 64];
  const int id = blockIdx.x;                     // 0..511
  const int g  = (id & 7) + ((id >> 6) << 3);    // 0..63 m-block
  const int bx = (id >> 3) & 7;                  // o-block
  const int m0 = g * 64, o0 = bx * 128;
  const int tid = threadIdx.x;
  const int wid = tid >> 6, lane = tid & 63;
  const int wr = wid >> 1, wc = wid & 1;
  const int lr = lane & 15, lk = lane >> 4;
  int srow[4], scol[4];
#pragma unroll
  for (int q = 0; q < 4; ++q) {
    const int idx = q * 256 + tid;
    srow[q] = idx >> 3;
    scol[q] = (((idx & 7) ^ ((idx >> 3) & 7)) << 3);
  }
  f32x4 acc[2][4];
#pragma unroll
  for (int i = 0; i < 2; ++i)
#pragma unroll
    for (int j = 0; j < 4; ++j) acc[i][j] = (f32x4){0.f, 0.f, 0.f, 0.f};

#pragma unroll
  for (int q = 0; q < 2; ++q)
    GLOAD_LDS16(&A[(size_t)(m0 + srow[q]) * 1024 + scol[q]], &As[0][(q * 256 + tid) * 8]);
#pragma unroll
  for (int q = 0; q < 4; ++q)
    GLOAD_LDS16(&B[(size_t)(o0 + srow[q]) * 1024 + scol[q]], &Bs[0][(q * 256 + tid) * 8]);

  for (int t = 0; t < 16; ++t) {
    const int cur = t & 1;
    if (t < 15) {
      const int kb = (t + 1) * 64;
#pragma unroll
      for (int q = 0; q < 2; ++q)
        GLOAD_LDS16(&A[(size_t)(m0 + srow[q]) * 1024 + kb + scol[q]],
                    &As[cur ^ 1][(q * 256 + tid) * 8]);
#pragma unroll
      for (int q = 0; q < 4; ++q)
        GLOAD_LDS16(&B[(size_t)(o0 + srow[q]) * 1024 + kb + scol[q]],
                    &Bs[cur ^ 1][(q * 256 + tid) * 8]);
      asm volatile("s_waitcnt vmcnt(6)" ::: "memory");
    } else {
      asm volatile("s_waitcnt vmcnt(0)" ::: "memory");
    }
    __builtin_amdgcn_s_barrier();
#pragma unroll
    for (int ph = 0; ph < 2; ++ph) {
      const int ck = ph * 4 + lk;
      bf16x8 af[2], bfr[4];
#pragma unroll
      for (int f = 0; f < 2; ++f) {
        const int ra = wr * 32 + f * 16 + lr;
        af[f] = *(const bf16x8*)&As[cur][ra * 64 + ((ck ^ (ra & 7)) << 3)];
      }
#pragma unroll
      for (int f = 0; f < 4; ++f) {
        const int rb = wc * 64 + f * 16 + lr;
        bfr[f] = *(const bf16x8*)&Bs[cur][rb * 64 + ((ck ^ (rb & 7)) << 3)];
      }
#pragma unroll
      for (int i = 0; i < 2; ++i)
#pragma unroll
        for (int j = 0; j < 4; ++j)
          acc[i][j] = __builtin_amdgcn_mfma_f32_16x16x32_bf16(af[i], bfr[j], acc[i][j], 0, 0, 0);
    }
    __builtin_amdgcn_s_barrier();
  }
#pragma unroll
  for (int fi = 0; fi < 2; ++fi)
#pragma unroll
    for (int fj = 0; fj < 4; ++fj) {
      const int o = o0 + wc * 64 + fj * 16 + lr;
      const float bo = bias[o];
#pragma unroll
      for (int t = 0; t < 4; ++t) {
        const int m = m0 + wr * 32 + fi * 16 + lk * 4 + t;
        C[(size_t)m * 1024 + o] = acc[fi][fj][t] + bo;
      }
    }
}

// ---------------------------------------------------------------------------
// MFMA flash v5 (unchanged): per (n,k,l-tile=64); 4 waves x 16 q-rows.
__global__ __launch_bounds__(256) void k_flash(
    const unsigned short* __restrict__ Qbf, const unsigned short* __restrict__ Khbf,
    const unsigned short* __restrict__ Vtbf, float* __restrict__ stats,
    unsigned short* __restrict__ Obf) {
  __shared__ unsigned short Kd[2][64 * 64];
  __shared__ unsigned short Vd[2][64 * 64];
  __shared__ unsigned short Ps[4][16 * 64];
  const int ob = blockIdx.x;
  const int b = (ob & 7) * 128 + (ob >> 3);   // bijective XCD swizzle
  const int lt = b & 15, k = (b >> 4) & 15, n = b >> 8;
  const int l0 = lt * 64;
  const int tid = threadIdx.x, w = tid >> 6, lane = tid & 63;
  const int lr = lane & 15, lk = lane >> 4;
  const size_t hb = (size_t)(n * 16 + k) * 65536;
  const unsigned short* qrow = Qbf + hb + (size_t)(l0 + w * 16 + lr) * 64;
  const bf16x8 qa0 = *(const bf16x8*)(qrow + lk * 8);
  const bf16x8 qa1 = *(const bf16x8*)(qrow + 32 + lk * 8);
  const int swz = lr & 7;
  int srow[2], scol[2];
#pragma unroll
  for (int q = 0; q < 2; ++q) {
    const int idx = q * 256 + tid;
    srow[q] = idx >> 3;
    scol[q] = (((idx & 7) ^ ((idx >> 3) & 7)) << 3);
  }
  const unsigned short* Kb = Khbf + hb;
  const unsigned short* Vb = Vtbf + hb;
  int4 kreg[2], vreg[2];
#pragma unroll
  for (int q = 0; q < 2; ++q) {
    kreg[q] = *(const int4*)(Kb + (size_t)srow[q] * 64 + scol[q]);
    vreg[q] = *(const int4*)(Vb + (size_t)srow[q] * 1024 + scol[q]);
  }
#pragma unroll
  for (int q = 0; q < 2; ++q) {
    *(int4*)&Kd[0][(q * 256 + tid) * 8] = kreg[q];
    *(int4*)&Vd[0][(q * 256 + tid) * 8] = vreg[q];
  }
  float m_ = -1e30f, Z_ = 0.f;
  f32x4 oacc[4];
#pragma unroll
  for (int it = 0; it < 4; ++it) oacc[it] = (f32x4){0.f, 0.f, 0.f, 0.f};
  __syncthreads();

  for (int t0 = 0; t0 < 16; ++t0) {
    const int cur = t0 & 1;
    if (t0 < 15) {
      const int s1 = (t0 + 1) * 64;
#pragma unroll
      for (int q = 0; q < 2; ++q) {
        kreg[q] = *(const int4*)(Kb + (size_t)(s1 + srow[q]) * 64 + scol[q]);
        vreg[q] = *(const int4*)(Vb + (size_t)srow[q] * 1024 + s1 + scol[q]);
      }
    }
    f32x4 sc[4];
#pragma unroll
    for (int st = 0; st < 4; ++st) {
      const int r = st * 16 + lr;
      const bf16x8 kb0 = *(const bf16x8*)&Kd[cur][r * 64 + ((lk ^ (r & 7)) << 3)];
      const bf16x8 kb1 = *(const bf16x8*)&Kd[cur][r * 64 + (((4 + lk) ^ (r & 7)) << 3)];
      f32x4 z = (f32x4){0.f, 0.f, 0.f, 0.f};
      z = __builtin_amdgcn_mfma_f32_16x16x32_bf16(kb0, qa0, z, 0, 0, 0);
      sc[st] = __builtin_amdgcn_mfma_f32_16x16x32_bf16(kb1, qa1, z, 0, 0, 0);
    }
    float tm = fmaxf(fmaxf(fmaxf(sc[0][0], sc[0][1]), fmaxf(sc[0][2], sc[0][3])),
                     fmaxf(fmaxf(sc[1][0], sc[1][1]), fmaxf(sc[1][2], sc[1][3])));
    tm = fmaxf(tm, fmaxf(fmaxf(fmaxf(sc[2][0], sc[2][1]), fmaxf(sc[2][2], sc[2][3])),
                         fmaxf(fmaxf(sc[3][0], sc[3][1]), fmaxf(sc[3][2], sc[3][3]))));
    tm = fmaxf(tm, __shfl_xor(tm, 16));
    tm = fmaxf(tm, __shfl_xor(tm, 32));
    const float mn = fmaxf(m_, tm);
    const float fac = __expf(m_ - mn);
    m_ = mn;
    float rs = 0.f;
    float p[4][4];
#pragma unroll
    for (int st = 0; st < 4; ++st)
#pragma unroll
      for (int t = 0; t < 4; ++t) {
        p[st][t] = __expf(sc[st][t] - mn);
        rs += p[st][t];
      }
    rs += __shfl_xor(rs, 16);
    rs += __shfl_xor(rs, 32);
    Z_ = Z_ * fac + rs;
#pragma unroll
    for (int st = 0; st < 4; ++st) {
      ushort4 pk;
      pk.x = f2bf(p[st][0]); pk.y = f2bf(p[st][1]);
      pk.z = f2bf(p[st][2]); pk.w = f2bf(p[st][3]);
      const int c = (st * 4 + lk) ^ (swz << 1);
      *(ushort4*)&Ps[w][lr * 64 + c * 4] = pk;
    }
    float fr[4];
#pragma unroll
    for (int t = 0; t < 4; ++t) fr[t] = __shfl(fac, lk * 4 + t);
    const f32x4 facv = {fr[0], fr[1], fr[2], fr[3]};
    const bf16x8 pa0 = *(const bf16x8*)&Ps[w][lr * 64 + ((lk ^ swz) << 3)];
    const bf16x8 pa1 = *(const bf16x8*)&Ps[w][lr * 64 + (((4 + lk) ^ swz) << 3)];
#pragma unroll
    for (int it = 0; it < 4; ++it) {
      const int r = it * 16 + lr;
      const bf16x8 bv0 = *(const bf16x8*)&Vd[cur][r * 64 + ((lk ^ (r & 7)) << 3)];
      const bf16x8 bv1 = *(const bf16x8*)&Vd[cur][r * 64 + (((4 + lk) ^ (r & 7)) << 3)];
      f32x4 o = oacc[it] * facv;
      o = __builtin_amdgcn_mfma_f32_16x16x32_bf16(pa0, bv0, o, 0, 0, 0);
      oacc[it] = __builtin_amdgcn_mfma_f32_16x16x32_bf16(pa1, bv1, o, 0, 0, 0);
    }
    if (t0 < 15) {
#pragma unroll
      for (int q = 0; q < 2; ++q) {
        *(int4*)&Kd[cur ^ 1][(q * 256 + tid) * 8] = kreg[q];
        *(int4*)&Vd[cur ^ 1][(q * 256 + tid) * 8] = vreg[q];
      }
    }
    __syncthreads();
  }

  if (lane < 16) {
    const size_t so = ((size_t)(n * 16 + k) * 1024 + l0 + w * 16 + lr) * 2;
    stats[so] = m_;
    stats[so + 1] = Z_;
  }
  const float iz = 1.f / Z_;
  float izr[4];
#pragma unroll
  for (int t = 0; t < 4; ++t) izr[t] = __shfl(iz, lk * 4 + t);
#pragma unroll
  for (int it = 0; it < 4; ++it)
#pragma unroll
    for (int t = 0; t < 4; ++t) {
      const int l = l0 + w * 16 + lk * 4 + t;
      const int i = it * 16 + lr;
      Obf[(size_t)(l * 4 + n) * 1024 + i * 16 + k] = f2bf(oacc[it][t] * izr[t]);
    }
}

// ---------------------------------------------------------------------------
// Wmap v4 (unchanged).
__global__ __launch_bounds__(256) void k_wmap(const unsigned short* __restrict__ Qbf,
    const unsigned short* __restrict__ Khbf, const float* __restrict__ stats,
    float* __restrict__ Wmap) {
  __shared__ unsigned short Kst[2][64 * 64];
  const int ob = blockIdx.x;
  const int b = (ob & 7) * 128 + (ob >> 3);
  const int st = b & 15, lt = (b >> 4) & 15, n = b >> 8;
  const int l0 = lt * 64, s0 = st * 64;
  const int tid = threadIdx.x, w = tid >> 6, lane = tid & 63;
  const int lr = lane & 15, lk = lane >> 4;
  int srow[2], scol[2];
#pragma unroll
  for (int q = 0; q < 2; ++q) {
    const int idx = q * 256 + tid;
    srow[q] = idx >> 3;
    scol[q] = (((idx & 7) ^ ((idx >> 3) & 7)) << 3);
  }
  int4 kreg[2];
#pragma unroll
  for (int q = 0; q < 2; ++q)
    kreg[q] = *(const int4*)(Khbf + (size_t)(n * 16) * 65536 +
                             (size_t)(s0 + srow[q]) * 64 + scol[q]);
#pragma unroll
  for (int q = 0; q < 2; ++q)
    *(int4*)&Kst[0][(q * 256 + tid) * 8] = kreg[q];
  f32x4 wsum[4];
#pragma unroll
  for (int i = 0; i < 4; ++i) wsum[i] = (f32x4){0.f, 0.f, 0.f, 0.f};
  __syncthreads();

  for (int k = 0; k < 16; ++k) {
    const int cur = k & 1;
    const size_t hb = (size_t)(n * 16 + k) * 65536;
    if (k < 15) {
      const size_t hb1 = (size_t)(n * 16 + k + 1) * 65536;
#pragma unroll
      for (int q = 0; q < 2; ++q)
        kreg[q] = *(const int4*)(Khbf + hb1 + (size_t)(s0 + srow[q]) * 64 + scol[q]);
    }
    const unsigned short* qrow = Qbf + hb + (size_t)(l0 + w * 16 + lr) * 64;
    const bf16x8 a0 = *(const bf16x8*)(qrow + lk * 8);
    const bf16x8 a1 = *(const bf16x8*)(qrow + 32 + lk * 8);
    float mv[4], izv[4];
#pragma unroll
    for (int t = 0; t < 4; ++t) {
      const float2 mz = *(const float2*)(stats +
          ((size_t)(n * 16 + k) * 1024 + l0 + w * 16 + lk * 4 + t) * 2);
      mv[t] = mz.x; izv[t] = 1.f / mz.y;
    }
#pragma unroll
    for (int st2 = 0; st2 < 4; ++st2) {
      const int r = st2 * 16 + lr;
      const bf16x8 kb0 = *(const bf16x8*)&Kst[cur][r * 64 + ((lk ^ (r & 7)) << 3)];
      const bf16x8 kb1 = *(const bf16x8*)&Kst[cur][r * 64 + (((4 + lk) ^ (r & 7)) << 3)];
      f32x4 z = (f32x4){0.f, 0.f, 0.f, 0.f};
      z = __builtin_amdgcn_mfma_f32_16x16x32_bf16(a0, kb0, z, 0, 0, 0);
      z = __builtin_amdgcn_mfma_f32_16x16x32_bf16(a1, kb1, z, 0, 0, 0);
#pragma unroll
      for (int t = 0; t < 4; ++t)
        wsum[st2][t] += __expf(z[t] - mv[t]) * izv[t];
    }
    if (k < 15) {
#pragma unroll
      for (int q = 0; q < 2; ++q)
        *(int4*)&Kst[cur ^ 1][(q * 256 + tid) * 8] = kreg[q];
    }
    __syncthreads();
  }
#pragma unroll
  for (int st2 = 0; st2 < 4; ++st2)
#pragma unroll
    for (int t = 0; t < 4; ++t) {
      const int l = l0 + w * 16 + lk * 4 + t;
      const int s = s0 + st2 * 16 + lr;
      Wmap[((size_t)l * 1024 + s) * 4 + n] = wsum[st2][t] * 0.0625f;
    }
}

// ---------------------------------------------------------------------------
extern "C" void kernel_launch(void* const* d_in, const int* in_sizes, int n_in,
                              void* d_out, int out_size, void* d_ws, size_t ws_size,
                              hipStream_t stream) {
  (void)in_sizes; (void)n_in; (void)out_size; (void)ws_size;
  const float* Q        = (const float*)d_in[0];
  const float* K        = (const float*)d_in[1];
  const float* V        = (const float*)d_in[2];
  const float* q_w      = (const float*)d_in[3];
  const float* k_w      = (const float*)d_in[4];
  const float* v_w      = (const float*)d_in[5];
  const float* out_w    = (const float*)d_in[6];
  const float* in_bias  = (const float*)d_in[7];
  const float* out_bias = (const float*)d_in[8];
  const float* attn_W   = (const float*)d_in[9];
  float* ws = (float*)d_ws;
  unsigned short* qw2bf = (unsigned short*)(ws + OFF_QW2BF);
  unsigned short* kwbf  = (unsigned short*)(ws + OFF_KWBF);
  unsigned short* vwbf  = (unsigned short*)(ws + OFF_VWBF);
  unsigned short* owtbf = (unsigned short*)(ws + OFF_OWTBF);
  float* qb2 = ws + OFF_QB2;
  unsigned short* Qwbf = (unsigned short*)(ws + OFF_QWBF);
  unsigned short* Khbf = (unsigned short*)(ws + OFF_KHBF);
  unsigned short* Vtbf = (unsigned short*)(ws + OFF_VTBF);
  float* st = ws + OFF_ST;
  unsigned short* Obf  = (unsigned short*)(ws + OFF_OBF);
  unsigned short* Abf  = (unsigned short*)(ws + OFF_ABF);
  float* out  = (float*)d_out;
  float* Wmap = out + 4194304;

  k_prep<<<5376, 256, 0, stream>>>(Q, K, V, q_w, k_w, v_w, out_w, attn_W,
                                   in_bias, qw2bf, qb2, kwbf, vwbf, owtbf, Abf);
  k_gemm_in<<<768, 256, 0, stream>>>(Abf, qw2bf, kwbf, vwbf,
                                     qb2, in_bias + 1024, in_bias + 2048,
                                     Qwbf, Khbf, Vtbf);
  k_flash<<<1024, 256, 0, stream>>>(Qwbf, Khbf, Vtbf, st, Obf);
  k_wmap<<<1024, 256, 0, stream>>>(Qwbf, Khbf, st, Wmap);
  k_gemm_out<<<512, 256, 0, stream>>>(Obf, owtbf, out_bias, out);
}

// Round 14
// 180.804 us; speedup vs baseline: 1.7473x; 1.0032x over previous
//
#include <hip/hip_runtime.h>
#include <cstdint>

// Problem constants: L=S=1024, N=4, E=1024, H=16, D=64
typedef __bf16 bf16x8 __attribute__((ext_vector_type(8)));
typedef float f32x4 __attribute__((ext_vector_type(4)));

#define GLOAD_LDS16(gptr, lptr)                                              \
  __builtin_amdgcn_global_load_lds(                                          \
      (const __attribute__((address_space(1))) void*)(gptr),                 \
      (__attribute__((address_space(3))) void*)(lptr), 16, 0, 0)

#define MAX3(a, b, c) fmaxf(fmaxf((a), (b)), (c))

// ws layout (float-unit offsets):
static const size_t OFF_QW2BF = 0;         // [k*64+i][j] bf16 (1M ushort)
static const size_t OFF_KWBF  = 524288;    // [k*64+i][j] bf16 (head-major)
static const size_t OFF_VWBF  = 1048576;   // [k*64+i][j] bf16 (head-major)
static const size_t OFF_OWTBF = 1572864;   // [o][j] bf16 (out_w^T)
static const size_t OFF_QB2   = 2097152;   // 1024 f32
static const size_t OFF_QWBF  = 2098176;   // [n][k][l][i] bf16 (4M ushort)
static const size_t OFF_KHBF  = 4195328;   // [n][k][s][i] bf16
static const size_t OFF_VTBF  = 6292480;   // [n][k][i][s] bf16 (V^T per head)
static const size_t OFF_ST    = 8389632;   // [n][k][l][{m,Z}] f32 131072
static const size_t OFF_OBF   = 8520704;   // [l*4+n][e] bf16 (4M ushort)
static const size_t OFF_ABF   = 10617856;  // [3][4096][1024] bf16 (12M ushort)

// Hand-rolled RNE f32->bf16 (keep; R12 native-cast experiment regressed).
__device__ inline unsigned short f2bf(float f) {
  union { float f; unsigned u; } v; v.f = f;
  const unsigned r = v.u + 0x7FFFu + ((v.u >> 16) & 1u);   // RNE
  return (unsigned short)(r >> 16);
}

// ---------------------------------------------------------------------------
// Fused prep: blocks [0,1024) qw2-fold; [1024,2048) k_w/v_w cvt+permute;
// [2048,5120) Q/K/V f32->bf16; [5120,5376) out_w transpose.
__global__ __launch_bounds__(256) void k_prep(const float* __restrict__ Q,
    const float* __restrict__ K, const float* __restrict__ V,
    const float* __restrict__ qw, const float* __restrict__ kw,
    const float* __restrict__ vw, const float* __restrict__ ow,
    const float* __restrict__ attnW, const float* __restrict__ in_bias,
    unsigned short* __restrict__ qw2, float* __restrict__ qb2,
    unsigned short* __restrict__ kwbf, unsigned short* __restrict__ vwbf,
    unsigned short* __restrict__ owtbf, unsigned short* __restrict__ Abf) {
  __shared__ float sh[64 * 65];
  const int b = blockIdx.x;
  const int tid = threadIdx.x;
  if (b < 1024) {
    const int k = b >> 6, i = b & 63;
    if (tid < 64) sh[tid] = attnW[(tid * 64 + i) * 16 + k] * 0.03125f;
    __syncthreads();
    for (int j = tid; j < 1024; j += 256) {
      float acc = 0.f;
#pragma unroll 8
      for (int o = 0; o < 64; ++o) acc = fmaf(qw[(o * 16 + k) * 1024 + j], sh[o], acc);
      qw2[(size_t)b * 1024 + j] = f2bf(acc);
    }
    if (tid == 0) {
      float acc = 0.f;
      for (int o = 0; o < 64; ++o) acc = fmaf(in_bias[o * 16 + k], sh[o], acc);
      qb2[b] = acc;
    }
  } else if (b < 2048) {
    const int o = b - 1024;
    const int dst = (o & 15) * 64 + (o >> 4);
    const float4 va = ((const float4*)(kw + (size_t)o * 1024))[tid];
    ushort4 ha; ha.x = f2bf(va.x); ha.y = f2bf(va.y); ha.z = f2bf(va.z); ha.w = f2bf(va.w);
    ((ushort4*)(kwbf + (size_t)dst * 1024))[tid] = ha;
    const float4 vb = ((const float4*)(vw + (size_t)o * 1024))[tid];
    ushort4 hb; hb.x = f2bf(vb.x); hb.y = f2bf(vb.y); hb.z = f2bf(vb.z); hb.w = f2bf(vb.w);
    ((ushort4*)(vwbf + (size_t)dst * 1024))[tid] = hb;
  } else if (b < 5120) {
    const int bb = b - 2048;
    const int m = bb >> 10;
    const float* src = m == 0 ? Q : (m == 1 ? K : V);
    unsigned short* dst = Abf + (size_t)m * 4194304;
#pragma unroll
    for (int q = 0; q < 4; ++q) {
      const int idx = (bb & 1023) * 1024 + q * 256 + tid;
      const float4 v = ((const float4*)src)[idx];
      ushort4 h; h.x = f2bf(v.x); h.y = f2bf(v.y); h.z = f2bf(v.z); h.w = f2bf(v.w);
      ((ushort4*)dst)[idx] = h;
    }
  } else {
    float (*t)[65] = (float(*)[65])sh;
    const int tb = b - 5120;
    const int o0 = (tb & 15) * 64, j0 = (tb >> 4) * 64;
    const int r = tid >> 4, c4 = tid & 15;
#pragma unroll
    for (int q = 0; q < 4; ++q) {
      const int row = r + q * 16;
      const float4 v = *(const float4*)&ow[(size_t)(j0 + row) * 1024 + o0 + c4 * 4];
      t[row][c4 * 4 + 0] = v.x; t[row][c4 * 4 + 1] = v.y;
      t[row][c4 * 4 + 2] = v.z; t[row][c4 * 4 + 3] = v.w;
    }
    __syncthreads();
#pragma unroll
    for (int q = 0; q < 4; ++q) {
      const int orow = r + q * 16;
      ushort4 h;
      h.x = f2bf(t[c4 * 4 + 0][orow]); h.y = f2bf(t[c4 * 4 + 1][orow]);
      h.z = f2bf(t[c4 * 4 + 2][orow]); h.w = f2bf(t[c4 * 4 + 3][orow]);
      *(ushort4*)&owtbf[(size_t)(o0 + orow) * 1024 + j0 + c4 * 4] = h;
    }
  }
}

// ---------------------------------------------------------------------------
// Merged in-projection GEMMs v6 (R11-proven): global_load_lds + LDS double
// buffer with counted vmcnt(8).
__global__ __launch_bounds__(256) void k_gemm_in(
    const unsigned short* __restrict__ Abf, const unsigned short* __restrict__ Bq,
    const unsigned short* __restrict__ Bk, const unsigned short* __restrict__ Bv,
    const float* __restrict__ bq, const float* __restrict__ bk,
    const float* __restrict__ bv, unsigned short* __restrict__ Cq,
    unsigned short* __restrict__ Ck, unsigned short* __restrict__ Cv) {
  __shared__ unsigned short As[2][128 * 64];
  __shared__ unsigned short Bs[2][128 * 64];
  const int id = blockIdx.x;                     // 0..767
  const int g  = (id & 7) + ((id >> 6) << 3);    // 0..95 (A-panel group)
  const int bx = (id >> 3) & 7;                  // o-block
  const int by = g & 31, bz = g >> 5;
  const unsigned short* A = Abf + (size_t)bz * 4194304;
  const unsigned short* B = bz == 0 ? Bq : (bz == 1 ? Bk : Bv);
  const float* bias       = bz == 0 ? bq : (bz == 1 ? bk : bv);
  unsigned short* C       = bz == 0 ? Cq : (bz == 1 ? Ck : Cv);
  const int m0 = by * 128, o0 = bx * 128;
  const int tid = threadIdx.x;
  const int wid = tid >> 6, lane = tid & 63;
  const int wr = wid >> 1, wc = wid & 1;
  const int lr = lane & 15, lk = lane >> 4;
  int srow[4], scol[4];
#pragma unroll
  for (int q = 0; q < 4; ++q) {
    const int idx = q * 256 + tid;
    srow[q] = idx >> 3;
    scol[q] = (((idx & 7) ^ ((idx >> 3) & 7)) << 3);
  }
  f32x4 acc[4][4];
#pragma unroll
  for (int i = 0; i < 4; ++i)
#pragma unroll
    for (int j = 0; j < 4; ++j) acc[i][j] = (f32x4){0.f, 0.f, 0.f, 0.f};

#pragma unroll
  for (int q = 0; q < 4; ++q) {
    GLOAD_LDS16(&A[(size_t)(m0 + srow[q]) * 1024 + scol[q]], &As[0][(q * 256 + tid) * 8]);
    GLOAD_LDS16(&B[(size_t)(o0 + srow[q]) * 1024 + scol[q]], &Bs[0][(q * 256 + tid) * 8]);
  }

  for (int t = 0; t < 16; ++t) {
    const int cur = t & 1;
    if (t < 15) {
      const int kb = (t + 1) * 64;
#pragma unroll
      for (int q = 0; q < 4; ++q) {
        GLOAD_LDS16(&A[(size_t)(m0 + srow[q]) * 1024 + kb + scol[q]],
                    &As[cur ^ 1][(q * 256 + tid) * 8]);
        GLOAD_LDS16(&B[(size_t)(o0 + srow[q]) * 1024 + kb + scol[q]],
                    &Bs[cur ^ 1][(q * 256 + tid) * 8]);
      }
      asm volatile("s_waitcnt vmcnt(8)" ::: "memory");   // oldest 8 (cur tile) done
    } else {
      asm volatile("s_waitcnt vmcnt(0)" ::: "memory");
    }
    __builtin_amdgcn_s_barrier();
#pragma unroll
    for (int ph = 0; ph < 2; ++ph) {
      const int ck = ph * 4 + lk;
      bf16x8 af[4], bfr[4];
#pragma unroll
      for (int f = 0; f < 4; ++f) {
        const int ra = wr * 64 + f * 16 + lr;
        af[f] = *(const bf16x8*)&As[cur][ra * 64 + ((ck ^ (ra & 7)) << 3)];
        const int rb = wc * 64 + f * 16 + lr;
        bfr[f] = *(const bf16x8*)&Bs[cur][rb * 64 + ((ck ^ (rb & 7)) << 3)];
      }
#pragma unroll
      for (int i = 0; i < 4; ++i)
#pragma unroll
        for (int j = 0; j < 4; ++j)
          acc[i][j] = __builtin_amdgcn_mfma_f32_16x16x32_bf16(af[i], bfr[j], acc[i][j], 0, 0, 0);
    }
    __builtin_amdgcn_s_barrier();   // readers done before buf^1 gets overwritten
  }
#pragma unroll
  for (int fi = 0; fi < 4; ++fi)
#pragma unroll
    for (int fj = 0; fj < 4; ++fj) {
      const int o = o0 + wc * 64 + fj * 16 + lr;
      const int kk = o >> 6, ii = o & 63;
      const float bo = bz == 0 ? bias[o] : bias[ii * 16 + kk];
#pragma unroll
      for (int t = 0; t < 4; ++t) {
        const int m = m0 + wr * 64 + fi * 16 + lk * 4 + t;
        const float v = acc[fi][fj][t] + bo;
        const int l = m >> 2, nn = m & 3;
        if (bz <= 1) {
          C[(((size_t)(nn * 16 + kk) * 1024 + l) << 6) + ii] = f2bf(v);
        } else {
          C[(((size_t)(nn * 16 + kk) * 64 + ii) << 10) + l] = f2bf(v);
        }
      }
    }
}

// ---------------------------------------------------------------------------
// Out-projection GEMM v5 (R11-proven): counted-vmcnt dbuf, vmcnt(6).
__global__ __launch_bounds__(256) void k_gemm_out(
    const unsigned short* __restrict__ A, const unsigned short* __restrict__ B,
    const float* __restrict__ bias, float* __restrict__ C) {
  __shared__ unsigned short As[2][64 * 64];
  __shared__ unsigned short Bs[2][128 * 64];
  const int id = blockIdx.x;                     // 0..511
  const int g  = (id & 7) + ((id >> 6) << 3);    // 0..63 m-block
  const int bx = (id >> 3) & 7;                  // o-block
  const int m0 = g * 64, o0 = bx * 128;
  const int tid = threadIdx.x;
  const int wid = tid >> 6, lane = tid & 63;
  const int wr = wid >> 1, wc = wid & 1;
  const int lr = lane & 15, lk = lane >> 4;
  int srow[4], scol[4];
#pragma unroll
  for (int q = 0; q < 4; ++q) {
    const int idx = q * 256 + tid;
    srow[q] = idx >> 3;
    scol[q] = (((idx & 7) ^ ((idx >> 3) & 7)) << 3);
  }
  f32x4 acc[2][4];
#pragma unroll
  for (int i = 0; i < 2; ++i)
#pragma unroll
    for (int j = 0; j < 4; ++j) acc[i][j] = (f32x4){0.f, 0.f, 0.f, 0.f};

#pragma unroll
  for (int q = 0; q < 2; ++q)
    GLOAD_LDS16(&A[(size_t)(m0 + srow[q]) * 1024 + scol[q]], &As[0][(q * 256 + tid) * 8]);
#pragma unroll
  for (int q = 0; q < 4; ++q)
    GLOAD_LDS16(&B[(size_t)(o0 + srow[q]) * 1024 + scol[q]], &Bs[0][(q * 256 + tid) * 8]);

  for (int t = 0; t < 16; ++t) {
    const int cur = t & 1;
    if (t < 15) {
      const int kb = (t + 1) * 64;
#pragma unroll
      for (int q = 0; q < 2; ++q)
        GLOAD_LDS16(&A[(size_t)(m0 + srow[q]) * 1024 + kb + scol[q]],
                    &As[cur ^ 1][(q * 256 + tid) * 8]);
#pragma unroll
      for (int q = 0; q < 4; ++q)
        GLOAD_LDS16(&B[(size_t)(o0 + srow[q]) * 1024 + kb + scol[q]],
                    &Bs[cur ^ 1][(q * 256 + tid) * 8]);
      asm volatile("s_waitcnt vmcnt(6)" ::: "memory");
    } else {
      asm volatile("s_waitcnt vmcnt(0)" ::: "memory");
    }
    __builtin_amdgcn_s_barrier();
#pragma unroll
    for (int ph = 0; ph < 2; ++ph) {
      const int ck = ph * 4 + lk;
      bf16x8 af[2], bfr[4];
#pragma unroll
      for (int f = 0; f < 2; ++f) {
        const int ra = wr * 32 + f * 16 + lr;
        af[f] = *(const bf16x8*)&As[cur][ra * 64 + ((ck ^ (ra & 7)) << 3)];
      }
#pragma unroll
      for (int f = 0; f < 4; ++f) {
        const int rb = wc * 64 + f * 16 + lr;
        bfr[f] = *(const bf16x8*)&Bs[cur][rb * 64 + ((ck ^ (rb & 7)) << 3)];
      }
#pragma unroll
      for (int i = 0; i < 2; ++i)
#pragma unroll
        for (int j = 0; j < 4; ++j)
          acc[i][j] = __builtin_amdgcn_mfma_f32_16x16x32_bf16(af[i], bfr[j], acc[i][j], 0, 0, 0);
    }
    __builtin_amdgcn_s_barrier();
  }
#pragma unroll
  for (int fi = 0; fi < 2; ++fi)
#pragma unroll
    for (int fj = 0; fj < 4; ++fj) {
      const int o = o0 + wc * 64 + fj * 16 + lr;
      const float bo = bias[o];
#pragma unroll
      for (int t = 0; t < 4; ++t) {
        const int m = m0 + wr * 32 + fi * 16 + lk * 4 + t;
        C[(size_t)m * 1024 + o] = acc[fi][fj][t] + bo;
      }
    }
}

// ---------------------------------------------------------------------------
// MFMA flash v5r (R11-proven structure, reverted from the racy v6):
// reg-staged double buffer + __syncthreads. R12/R13 showed gload_lds with raw
// s_barrier races here (compiler hoists next tile's loads past the raw
// barrier; no memory-fence semantics) -> ~4e-3 absmax. DO NOT re-apply
// counted-vmcnt staging to this kernel without sched_barrier(0) pinning and
// a dedicated refcheck round. MAX3 tree kept (numerically identical).
__global__ __launch_bounds__(256) void k_flash(
    const unsigned short* __restrict__ Qbf, const unsigned short* __restrict__ Khbf,
    const unsigned short* __restrict__ Vtbf, float* __restrict__ stats,
    unsigned short* __restrict__ Obf) {
  __shared__ unsigned short Kd[2][64 * 64];
  __shared__ unsigned short Vd[2][64 * 64];
  __shared__ unsigned short Ps[4][16 * 64];
  const int ob = blockIdx.x;
  const int b = (ob & 7) * 128 + (ob >> 3);   // bijective XCD swizzle
  const int lt = b & 15, k = (b >> 4) & 15, n = b >> 8;
  const int l0 = lt * 64;
  const int tid = threadIdx.x, w = tid >> 6, lane = tid & 63;
  const int lr = lane & 15, lk = lane >> 4;
  const size_t hb = (size_t)(n * 16 + k) * 65536;
  const unsigned short* qrow = Qbf + hb + (size_t)(l0 + w * 16 + lr) * 64;
  const bf16x8 qa0 = *(const bf16x8*)(qrow + lk * 8);
  const bf16x8 qa1 = *(const bf16x8*)(qrow + 32 + lk * 8);
  const int swz = lr & 7;
  int srow[2], scol[2];
#pragma unroll
  for (int q = 0; q < 2; ++q) {
    const int idx = q * 256 + tid;
    srow[q] = idx >> 3;
    scol[q] = (((idx & 7) ^ ((idx >> 3) & 7)) << 3);
  }
  const unsigned short* Kb = Khbf + hb;
  const unsigned short* Vb = Vtbf + hb;
  int4 kreg[2], vreg[2];
#pragma unroll
  for (int q = 0; q < 2; ++q) {
    kreg[q] = *(const int4*)(Kb + (size_t)srow[q] * 64 + scol[q]);
    vreg[q] = *(const int4*)(Vb + (size_t)srow[q] * 1024 + scol[q]);
  }
#pragma unroll
  for (int q = 0; q < 2; ++q) {
    *(int4*)&Kd[0][(q * 256 + tid) * 8] = kreg[q];
    *(int4*)&Vd[0][(q * 256 + tid) * 8] = vreg[q];
  }
  float m_ = -1e30f, Z_ = 0.f;
  f32x4 oacc[4];
#pragma unroll
  for (int it = 0; it < 4; ++it) oacc[it] = (f32x4){0.f, 0.f, 0.f, 0.f};
  __syncthreads();

  for (int t0 = 0; t0 < 16; ++t0) {
    const int cur = t0 & 1;
    if (t0 < 15) {    // T14: issue next tile's loads to regs before compute
      const int s1 = (t0 + 1) * 64;
#pragma unroll
      for (int q = 0; q < 2; ++q) {
        kreg[q] = *(const int4*)(Kb + (size_t)(s1 + srow[q]) * 64 + scol[q]);
        vreg[q] = *(const int4*)(Vb + (size_t)srow[q] * 1024 + s1 + scol[q]);
      }
    }
    // swapped QK^T: lane holds S[q=lr][s = st*16 + lk*4 + t]
    f32x4 sc[4];
#pragma unroll
    for (int st = 0; st < 4; ++st) {
      const int r = st * 16 + lr;
      const bf16x8 kb0 = *(const bf16x8*)&Kd[cur][r * 64 + ((lk ^ (r & 7)) << 3)];
      const bf16x8 kb1 = *(const bf16x8*)&Kd[cur][r * 64 + (((4 + lk) ^ (r & 7)) << 3)];
      f32x4 z = (f32x4){0.f, 0.f, 0.f, 0.f};
      z = __builtin_amdgcn_mfma_f32_16x16x32_bf16(kb0, qa0, z, 0, 0, 0);
      sc[st] = __builtin_amdgcn_mfma_f32_16x16x32_bf16(kb1, qa1, z, 0, 0, 0);
    }
    // online softmax; max3-friendly reduction tree
    const float a0 = MAX3(sc[0][0], sc[0][1], sc[0][2]);
    const float a1 = MAX3(sc[0][3], sc[1][0], sc[1][1]);
    const float a2 = MAX3(sc[1][2], sc[1][3], sc[2][0]);
    const float a3 = MAX3(sc[2][1], sc[2][2], sc[2][3]);
    const float a4 = MAX3(sc[3][0], sc[3][1], sc[3][2]);
    float tm = fmaxf(MAX3(a0, a1, a2), MAX3(a3, a4, sc[3][3]));
    tm = fmaxf(tm, __shfl_xor(tm, 16));
    tm = fmaxf(tm, __shfl_xor(tm, 32));
    const float mn = fmaxf(m_, tm);
    const float fac = __expf(m_ - mn);
    m_ = mn;
    float rs = 0.f;
    float p[4][4];
#pragma unroll
    for (int st = 0; st < 4; ++st)
#pragma unroll
      for (int t = 0; t < 4; ++t) {
        p[st][t] = __expf(sc[st][t] - mn);
        rs += p[st][t];
      }
    rs += __shfl_xor(rs, 16);
    rs += __shfl_xor(rs, 32);
    Z_ = Z_ * fac + rs;
    // P write: 4 packed b64 (s = st*16+lk*4..+3), 8B-chunk XOR swizzle
#pragma unroll
    for (int st = 0; st < 4; ++st) {
      ushort4 pk;
      pk.x = f2bf(p[st][0]); pk.y = f2bf(p[st][1]);
      pk.z = f2bf(p[st][2]); pk.w = f2bf(p[st][3]);
      const int c = (st * 4 + lk) ^ (swz << 1);
      *(ushort4*)&Ps[w][lr * 64 + c * 4] = pk;
    }
    float fr[4];
#pragma unroll
    for (int t = 0; t < 4; ++t) fr[t] = __shfl(fac, lk * 4 + t);
    const f32x4 facv = {fr[0], fr[1], fr[2], fr[3]};
    const bf16x8 pa0 = *(const bf16x8*)&Ps[w][lr * 64 + ((lk ^ swz) << 3)];
    const bf16x8 pa1 = *(const bf16x8*)&Ps[w][lr * 64 + (((4 + lk) ^ swz) << 3)];
#pragma unroll
    for (int it = 0; it < 4; ++it) {
      const int r = it * 16 + lr;
      const bf16x8 bv0 = *(const bf16x8*)&Vd[cur][r * 64 + ((lk ^ (r & 7)) << 3)];
      const bf16x8 bv1 = *(const bf16x8*)&Vd[cur][r * 64 + (((4 + lk) ^ (r & 7)) << 3)];
      f32x4 o = oacc[it] * facv;
      o = __builtin_amdgcn_mfma_f32_16x16x32_bf16(pa0, bv0, o, 0, 0, 0);
      oacc[it] = __builtin_amdgcn_mfma_f32_16x16x32_bf16(pa1, bv1, o, 0, 0, 0);
    }
    // stage next tile into the other buffer, then sync
    if (t0 < 15) {
#pragma unroll
      for (int q = 0; q < 2; ++q) {
        *(int4*)&Kd[cur ^ 1][(q * 256 + tid) * 8] = kreg[q];
        *(int4*)&Vd[cur ^ 1][(q * 256 + tid) * 8] = vreg[q];
      }
    }
    __syncthreads();
  }

  if (lane < 16) {
    const size_t so = ((size_t)(n * 16 + k) * 1024 + l0 + w * 16 + lr) * 2;
    stats[so] = m_;
    stats[so + 1] = Z_;
  }
  const float iz = 1.f / Z_;
  float izr[4];
#pragma unroll
  for (int t = 0; t < 4; ++t) izr[t] = __shfl(iz, lk * 4 + t);
#pragma unroll
  for (int it = 0; it < 4; ++it)
#pragma unroll
    for (int t = 0; t < 4; ++t) {
      const int l = l0 + w * 16 + lk * 4 + t;
      const int i = it * 16 + lr;
      Obf[(size_t)(l * 4 + n) * 1024 + i * 16 + k] = f2bf(oacc[it][t] * izr[t]);
    }
}

// ---------------------------------------------------------------------------
// Wmap v4 (R11-proven, unchanged).
__global__ __launch_bounds__(256) void k_wmap(const unsigned short* __restrict__ Qbf,
    const unsigned short* __restrict__ Khbf, const float* __restrict__ stats,
    float* __restrict__ Wmap) {
  __shared__ unsigned short Kst[2][64 * 64];
  const int ob = blockIdx.x;
  const int b = (ob & 7) * 128 + (ob >> 3);
  const int st = b & 15, lt = (b >> 4) & 15, n = b >> 8;
  const int l0 = lt * 64, s0 = st * 64;
  const int tid = threadIdx.x, w = tid >> 6, lane = tid & 63;
  const int lr = lane & 15, lk = lane >> 4;
  int srow[2], scol[2];
#pragma unroll
  for (int q = 0; q < 2; ++q) {
    const int idx = q * 256 + tid;
    srow[q] = idx >> 3;
    scol[q] = (((idx & 7) ^ ((idx >> 3) & 7)) << 3);
  }
  int4 kreg[2];
#pragma unroll
  for (int q = 0; q < 2; ++q)
    kreg[q] = *(const int4*)(Khbf + (size_t)(n * 16) * 65536 +
                             (size_t)(s0 + srow[q]) * 64 + scol[q]);
#pragma unroll
  for (int q = 0; q < 2; ++q)
    *(int4*)&Kst[0][(q * 256 + tid) * 8] = kreg[q];
  f32x4 wsum[4];
#pragma unroll
  for (int i = 0; i < 4; ++i) wsum[i] = (f32x4){0.f, 0.f, 0.f, 0.f};
  __syncthreads();

  for (int k = 0; k < 16; ++k) {
    const int cur = k & 1;
    const size_t hb = (size_t)(n * 16 + k) * 65536;
    if (k < 15) {
      const size_t hb1 = (size_t)(n * 16 + k + 1) * 65536;
#pragma unroll
      for (int q = 0; q < 2; ++q)
        kreg[q] = *(const int4*)(Khbf + hb1 + (size_t)(s0 + srow[q]) * 64 + scol[q]);
    }
    const unsigned short* qrow = Qbf + hb + (size_t)(l0 + w * 16 + lr) * 64;
    const bf16x8 a0 = *(const bf16x8*)(qrow + lk * 8);
    const bf16x8 a1 = *(const bf16x8*)(qrow + 32 + lk * 8);
    float mv[4], izv[4];
#pragma unroll
    for (int t = 0; t < 4; ++t) {
      const float2 mz = *(const float2*)(stats +
          ((size_t)(n * 16 + k) * 1024 + l0 + w * 16 + lk * 4 + t) * 2);
      mv[t] = mz.x; izv[t] = 1.f / mz.y;
    }
#pragma unroll
    for (int st2 = 0; st2 < 4; ++st2) {
      const int r = st2 * 16 + lr;
      const bf16x8 kb0 = *(const bf16x8*)&Kst[cur][r * 64 + ((lk ^ (r & 7)) << 3)];
      const bf16x8 kb1 = *(const bf16x8*)&Kst[cur][r * 64 + (((4 + lk) ^ (r & 7)) << 3)];
      f32x4 z = (f32x4){0.f, 0.f, 0.f, 0.f};
      z = __builtin_amdgcn_mfma_f32_16x16x32_bf16(a0, kb0, z, 0, 0, 0);
      z = __builtin_amdgcn_mfma_f32_16x16x32_bf16(a1, kb1, z, 0, 0, 0);
#pragma unroll
      for (int t = 0; t < 4; ++t)
        wsum[st2][t] += __expf(z[t] - mv[t]) * izv[t];
    }
    if (k < 15) {
#pragma unroll
      for (int q = 0; q < 2; ++q)
        *(int4*)&Kst[cur ^ 1][(q * 256 + tid) * 8] = kreg[q];
    }
    __syncthreads();
  }
#pragma unroll
  for (int st2 = 0; st2 < 4; ++st2)
#pragma unroll
    for (int t = 0; t < 4; ++t) {
      const int l = l0 + w * 16 + lk * 4 + t;
      const int s = s0 + st2 * 16 + lr;
      Wmap[((size_t)l * 1024 + s) * 4 + n] = wsum[st2][t] * 0.0625f;
    }
}

// ---------------------------------------------------------------------------
extern "C" void kernel_launch(void* const* d_in, const int* in_sizes, int n_in,
                              void* d_out, int out_size, void* d_ws, size_t ws_size,
                              hipStream_t stream) {
  (void)in_sizes; (void)n_in; (void)out_size; (void)ws_size;
  const float* Q        = (const float*)d_in[0];
  const float* K        = (const float*)d_in[1];
  const float* V        = (const float*)d_in[2];
  const float* q_w      = (const float*)d_in[3];
  const float* k_w      = (const float*)d_in[4];
  const float* v_w      = (const float*)d_in[5];
  const float* out_w    = (const float*)d_in[6];
  const float* in_bias  = (const float*)d_in[7];
  const float* out_bias = (const float*)d_in[8];
  const float* attn_W   = (const float*)d_in[9];
  float* ws = (float*)d_ws;
  unsigned short* qw2bf = (unsigned short*)(ws + OFF_QW2BF);
  unsigned short* kwbf  = (unsigned short*)(ws + OFF_KWBF);
  unsigned short* vwbf  = (unsigned short*)(ws + OFF_VWBF);
  unsigned short* owtbf = (unsigned short*)(ws + OFF_OWTBF);
  float* qb2 = ws + OFF_QB2;
  unsigned short* Qwbf = (unsigned short*)(ws + OFF_QWBF);
  unsigned short* Khbf = (unsigned short*)(ws + OFF_KHBF);
  unsigned short* Vtbf = (unsigned short*)(ws + OFF_VTBF);
  float* st = ws + OFF_ST;
  unsigned short* Obf  = (unsigned short*)(ws + OFF_OBF);
  unsigned short* Abf  = (unsigned short*)(ws + OFF_ABF);
  float* out  = (float*)d_out;
  float* Wmap = out + 4194304;

  k_prep<<<5376, 256, 0, stream>>>(Q, K, V, q_w, k_w, v_w, out_w, attn_W,
                                   in_bias, qw2bf, qb2, kwbf, vwbf, owtbf, Abf);
  k_gemm_in<<<768, 256, 0, stream>>>(Abf, qw2bf, kwbf, vwbf,
                                     qb2, in_bias + 1024, in_bias + 2048,
                                     Qwbf, Khbf, Vtbf);
  k_flash<<<1024, 256, 0, stream>>>(Qwbf, Khbf, Vtbf, st, Obf);
  k_wmap<<<1024, 256, 0, stream>>>(Qwbf, Khbf, st, Wmap);
  k_gemm_out<<<512, 256, 0, stream>>>(Obf, owtbf, out_bias, out);
}

// Round 15
// 178.023 us; speedup vs baseline: 1.7746x; 1.0156x over previous
//
#include <hip/hip_runtime.h>
#include <cstdint>

// Problem constants: L=S=1024, N=4, E=1024, H=16, D=64
typedef __bf16 bf16x8 __attribute__((ext_vector_type(8)));
typedef float f32x4 __attribute__((ext_vector_type(4)));

#define GLOAD_LDS16(gptr, lptr)                                              \
  __builtin_amdgcn_global_load_lds(                                          \
      (const __attribute__((address_space(1))) void*)(gptr),                 \
      (__attribute__((address_space(3))) void*)(lptr), 16, 0, 0)

#define MAX3(a, b, c) fmaxf(fmaxf((a), (b)), (c))

// ws layout (float-unit offsets):
static const size_t OFF_QW2BF = 0;         // [k*64+i][j] bf16 (1M ushort)
static const size_t OFF_KWBF  = 524288;    // [k*64+i][j] bf16 (head-major)
static const size_t OFF_VWBF  = 1048576;   // [k*64+i][j] bf16 (head-major)
static const size_t OFF_OWTBF = 1572864;   // [o][j] bf16 (out_w^T)
static const size_t OFF_QB2   = 2097152;   // 1024 f32
static const size_t OFF_QWBF  = 2098176;   // [n][k][l][i] bf16 (4M ushort)
static const size_t OFF_KHBF  = 4195328;   // [n][k][s][i] bf16
static const size_t OFF_VTBF  = 6292480;   // [n][k][i][s] bf16 (V^T per head)
static const size_t OFF_ST    = 8389632;   // [n][k][l][{m,invZ}] f32 131072
static const size_t OFF_OBF   = 8520704;   // [l*4+n][e] bf16 (4M ushort)
static const size_t OFF_ABF   = 10617856;  // [3][4096][1024] bf16 (12M ushort)

// Native RNE cast -> v_cvt_pk_bf16_f32 pairs. R13 exonerated this path
// (the R12 failure was the flash staging race, not the cast).
__device__ inline unsigned short f2bf(float f) {
  return __builtin_bit_cast(unsigned short, (__bf16)f);
}

// ---------------------------------------------------------------------------
// Fused prep: blocks [0,1024) qw2-fold; [1024,2048) k_w/v_w cvt+permute;
// [2048,5120) Q/K/V f32->bf16; [5120,5376) out_w transpose.
__global__ __launch_bounds__(256) void k_prep(const float* __restrict__ Q,
    const float* __restrict__ K, const float* __restrict__ V,
    const float* __restrict__ qw, const float* __restrict__ kw,
    const float* __restrict__ vw, const float* __restrict__ ow,
    const float* __restrict__ attnW, const float* __restrict__ in_bias,
    unsigned short* __restrict__ qw2, float* __restrict__ qb2,
    unsigned short* __restrict__ kwbf, unsigned short* __restrict__ vwbf,
    unsigned short* __restrict__ owtbf, unsigned short* __restrict__ Abf) {
  __shared__ float sh[64 * 65];
  const int b = blockIdx.x;
  const int tid = threadIdx.x;
  if (b < 1024) {
    const int k = b >> 6, i = b & 63;
    if (tid < 64) sh[tid] = attnW[(tid * 64 + i) * 16 + k] * 0.03125f;
    __syncthreads();
    for (int j = tid; j < 1024; j += 256) {
      float acc = 0.f;
#pragma unroll 8
      for (int o = 0; o < 64; ++o) acc = fmaf(qw[(o * 16 + k) * 1024 + j], sh[o], acc);
      qw2[(size_t)b * 1024 + j] = f2bf(acc);
    }
    if (tid == 0) {
      float acc = 0.f;
      for (int o = 0; o < 64; ++o) acc = fmaf(in_bias[o * 16 + k], sh[o], acc);
      qb2[b] = acc;
    }
  } else if (b < 2048) {
    const int o = b - 1024;
    const int dst = (o & 15) * 64 + (o >> 4);
    const float4 va = ((const float4*)(kw + (size_t)o * 1024))[tid];
    ushort4 ha; ha.x = f2bf(va.x); ha.y = f2bf(va.y); ha.z = f2bf(va.z); ha.w = f2bf(va.w);
    ((ushort4*)(kwbf + (size_t)dst * 1024))[tid] = ha;
    const float4 vb = ((const float4*)(vw + (size_t)o * 1024))[tid];
    ushort4 hb; hb.x = f2bf(vb.x); hb.y = f2bf(vb.y); hb.z = f2bf(vb.z); hb.w = f2bf(vb.w);
    ((ushort4*)(vwbf + (size_t)dst * 1024))[tid] = hb;
  } else if (b < 5120) {
    const int bb = b - 2048;
    const int m = bb >> 10;
    const float* src = m == 0 ? Q : (m == 1 ? K : V);
    unsigned short* dst = Abf + (size_t)m * 4194304;
#pragma unroll
    for (int q = 0; q < 4; ++q) {
      const int idx = (bb & 1023) * 1024 + q * 256 + tid;
      const float4 v = ((const float4*)src)[idx];
      ushort4 h; h.x = f2bf(v.x); h.y = f2bf(v.y); h.z = f2bf(v.z); h.w = f2bf(v.w);
      ((ushort4*)dst)[idx] = h;
    }
  } else {
    float (*t)[65] = (float(*)[65])sh;
    const int tb = b - 5120;
    const int o0 = (tb & 15) * 64, j0 = (tb >> 4) * 64;
    const int r = tid >> 4, c4 = tid & 15;
#pragma unroll
    for (int q = 0; q < 4; ++q) {
      const int row = r + q * 16;
      const float4 v = *(const float4*)&ow[(size_t)(j0 + row) * 1024 + o0 + c4 * 4];
      t[row][c4 * 4 + 0] = v.x; t[row][c4 * 4 + 1] = v.y;
      t[row][c4 * 4 + 2] = v.z; t[row][c4 * 4 + 3] = v.w;
    }
    __syncthreads();
#pragma unroll
    for (int q = 0; q < 4; ++q) {
      const int orow = r + q * 16;
      ushort4 h;
      h.x = f2bf(t[c4 * 4 + 0][orow]); h.y = f2bf(t[c4 * 4 + 1][orow]);
      h.z = f2bf(t[c4 * 4 + 2][orow]); h.w = f2bf(t[c4 * 4 + 3][orow]);
      *(ushort4*)&owtbf[(size_t)(o0 + orow) * 1024 + j0 + c4 * 4] = h;
    }
  }
}

// ---------------------------------------------------------------------------
// Merged in-projection GEMMs v6 (R11-proven): global_load_lds + LDS double
// buffer with counted vmcnt(8).
__global__ __launch_bounds__(256) void k_gemm_in(
    const unsigned short* __restrict__ Abf, const unsigned short* __restrict__ Bq,
    const unsigned short* __restrict__ Bk, const unsigned short* __restrict__ Bv,
    const float* __restrict__ bq, const float* __restrict__ bk,
    const float* __restrict__ bv, unsigned short* __restrict__ Cq,
    unsigned short* __restrict__ Ck, unsigned short* __restrict__ Cv) {
  __shared__ unsigned short As[2][128 * 64];
  __shared__ unsigned short Bs[2][128 * 64];
  const int id = blockIdx.x;                     // 0..767
  const int g  = (id & 7) + ((id >> 6) << 3);    // 0..95 (A-panel group)
  const int bx = (id >> 3) & 7;                  // o-block
  const int by = g & 31, bz = g >> 5;
  const unsigned short* A = Abf + (size_t)bz * 4194304;
  const unsigned short* B = bz == 0 ? Bq : (bz == 1 ? Bk : Bv);
  const float* bias       = bz == 0 ? bq : (bz == 1 ? bk : bv);
  unsigned short* C       = bz == 0 ? Cq : (bz == 1 ? Ck : Cv);
  const int m0 = by * 128, o0 = bx * 128;
  const int tid = threadIdx.x;
  const int wid = tid >> 6, lane = tid & 63;
  const int wr = wid >> 1, wc = wid & 1;
  const int lr = lane & 15, lk = lane >> 4;
  int srow[4], scol[4];
#pragma unroll
  for (int q = 0; q < 4; ++q) {
    const int idx = q * 256 + tid;
    srow[q] = idx >> 3;
    scol[q] = (((idx & 7) ^ ((idx >> 3) & 7)) << 3);
  }
  f32x4 acc[4][4];
#pragma unroll
  for (int i = 0; i < 4; ++i)
#pragma unroll
    for (int j = 0; j < 4; ++j) acc[i][j] = (f32x4){0.f, 0.f, 0.f, 0.f};

#pragma unroll
  for (int q = 0; q < 4; ++q) {
    GLOAD_LDS16(&A[(size_t)(m0 + srow[q]) * 1024 + scol[q]], &As[0][(q * 256 + tid) * 8]);
    GLOAD_LDS16(&B[(size_t)(o0 + srow[q]) * 1024 + scol[q]], &Bs[0][(q * 256 + tid) * 8]);
  }

  for (int t = 0; t < 16; ++t) {
    const int cur = t & 1;
    if (t < 15) {
      const int kb = (t + 1) * 64;
#pragma unroll
      for (int q = 0; q < 4; ++q) {
        GLOAD_LDS16(&A[(size_t)(m0 + srow[q]) * 1024 + kb + scol[q]],
                    &As[cur ^ 1][(q * 256 + tid) * 8]);
        GLOAD_LDS16(&B[(size_t)(o0 + srow[q]) * 1024 + kb + scol[q]],
                    &Bs[cur ^ 1][(q * 256 + tid) * 8]);
      }
      asm volatile("s_waitcnt vmcnt(8)" ::: "memory");   // oldest 8 (cur tile) done
    } else {
      asm volatile("s_waitcnt vmcnt(0)" ::: "memory");
    }
    __builtin_amdgcn_s_barrier();
#pragma unroll
    for (int ph = 0; ph < 2; ++ph) {
      const int ck = ph * 4 + lk;
      bf16x8 af[4], bfr[4];
#pragma unroll
      for (int f = 0; f < 4; ++f) {
        const int ra = wr * 64 + f * 16 + lr;
        af[f] = *(const bf16x8*)&As[cur][ra * 64 + ((ck ^ (ra & 7)) << 3)];
        const int rb = wc * 64 + f * 16 + lr;
        bfr[f] = *(const bf16x8*)&Bs[cur][rb * 64 + ((ck ^ (rb & 7)) << 3)];
      }
#pragma unroll
      for (int i = 0; i < 4; ++i)
#pragma unroll
        for (int j = 0; j < 4; ++j)
          acc[i][j] = __builtin_amdgcn_mfma_f32_16x16x32_bf16(af[i], bfr[j], acc[i][j], 0, 0, 0);
    }
    __builtin_amdgcn_s_barrier();   // readers done before buf^1 gets overwritten
  }
#pragma unroll
  for (int fi = 0; fi < 4; ++fi)
#pragma unroll
    for (int fj = 0; fj < 4; ++fj) {
      const int o = o0 + wc * 64 + fj * 16 + lr;
      const int kk = o >> 6, ii = o & 63;
      const float bo = bz == 0 ? bias[o] : bias[ii * 16 + kk];
#pragma unroll
      for (int t = 0; t < 4; ++t) {
        const int m = m0 + wr * 64 + fi * 16 + lk * 4 + t;
        const float v = acc[fi][fj][t] + bo;
        const int l = m >> 2, nn = m & 3;
        if (bz <= 1) {
          C[(((size_t)(nn * 16 + kk) * 1024 + l) << 6) + ii] = f2bf(v);
        } else {
          C[(((size_t)(nn * 16 + kk) * 64 + ii) << 10) + l] = f2bf(v);
        }
      }
    }
}

// ---------------------------------------------------------------------------
// Out-projection GEMM v5 (R11-proven): counted-vmcnt dbuf, vmcnt(6).
__global__ __launch_bounds__(256) void k_gemm_out(
    const unsigned short* __restrict__ A, const unsigned short* __restrict__ B,
    const float* __restrict__ bias, float* __restrict__ C) {
  __shared__ unsigned short As[2][64 * 64];
  __shared__ unsigned short Bs[2][128 * 64];
  const int id = blockIdx.x;                     // 0..511
  const int g  = (id & 7) + ((id >> 6) << 3);    // 0..63 m-block
  const int bx = (id >> 3) & 7;                  // o-block
  const int m0 = g * 64, o0 = bx * 128;
  const int tid = threadIdx.x;
  const int wid = tid >> 6, lane = tid & 63;
  const int wr = wid >> 1, wc = wid & 1;
  const int lr = lane & 15, lk = lane >> 4;
  int srow[4], scol[4];
#pragma unroll
  for (int q = 0; q < 4; ++q) {
    const int idx = q * 256 + tid;
    srow[q] = idx >> 3;
    scol[q] = (((idx & 7) ^ ((idx >> 3) & 7)) << 3);
  }
  f32x4 acc[2][4];
#pragma unroll
  for (int i = 0; i < 2; ++i)
#pragma unroll
    for (int j = 0; j < 4; ++j) acc[i][j] = (f32x4){0.f, 0.f, 0.f, 0.f};

#pragma unroll
  for (int q = 0; q < 2; ++q)
    GLOAD_LDS16(&A[(size_t)(m0 + srow[q]) * 1024 + scol[q]], &As[0][(q * 256 + tid) * 8]);
#pragma unroll
  for (int q = 0; q < 4; ++q)
    GLOAD_LDS16(&B[(size_t)(o0 + srow[q]) * 1024 + scol[q]], &Bs[0][(q * 256 + tid) * 8]);

  for (int t = 0; t < 16; ++t) {
    const int cur = t & 1;
    if (t < 15) {
      const int kb = (t + 1) * 64;
#pragma unroll
      for (int q = 0; q < 2; ++q)
        GLOAD_LDS16(&A[(size_t)(m0 + srow[q]) * 1024 + kb + scol[q]],
                    &As[cur ^ 1][(q * 256 + tid) * 8]);
#pragma unroll
      for (int q = 0; q < 4; ++q)
        GLOAD_LDS16(&B[(size_t)(o0 + srow[q]) * 1024 + kb + scol[q]],
                    &Bs[cur ^ 1][(q * 256 + tid) * 8]);
      asm volatile("s_waitcnt vmcnt(6)" ::: "memory");
    } else {
      asm volatile("s_waitcnt vmcnt(0)" ::: "memory");
    }
    __builtin_amdgcn_s_barrier();
#pragma unroll
    for (int ph = 0; ph < 2; ++ph) {
      const int ck = ph * 4 + lk;
      bf16x8 af[2], bfr[4];
#pragma unroll
      for (int f = 0; f < 2; ++f) {
        const int ra = wr * 32 + f * 16 + lr;
        af[f] = *(const bf16x8*)&As[cur][ra * 64 + ((ck ^ (ra & 7)) << 3)];
      }
#pragma unroll
      for (int f = 0; f < 4; ++f) {
        const int rb = wc * 64 + f * 16 + lr;
        bfr[f] = *(const bf16x8*)&Bs[cur][rb * 64 + ((ck ^ (rb & 7)) << 3)];
      }
#pragma unroll
      for (int i = 0; i < 2; ++i)
#pragma unroll
        for (int j = 0; j < 4; ++j)
          acc[i][j] = __builtin_amdgcn_mfma_f32_16x16x32_bf16(af[i], bfr[j], acc[i][j], 0, 0, 0);
    }
    __builtin_amdgcn_s_barrier();
  }
#pragma unroll
  for (int fi = 0; fi < 2; ++fi)
#pragma unroll
    for (int fj = 0; fj < 4; ++fj) {
      const int o = o0 + wc * 64 + fj * 16 + lr;
      const float bo = bias[o];
#pragma unroll
      for (int t = 0; t < 4; ++t) {
        const int m = m0 + wr * 32 + fi * 16 + lk * 4 + t;
        C[(size_t)m * 1024 + o] = acc[fi][fj][t] + bo;
      }
    }
}

// ---------------------------------------------------------------------------
// MFMA flash v7: R14 structure (reg-staged dbuf + __syncthreads, proven) +
// defer-max rescale (T13, THR=8), tree rs-sum, native casts; stores
// (m, 1/Z) so wmap skips the rcp. (m,Z) consistent pair -> wmap unchanged.
__global__ __launch_bounds__(256) void k_flash(
    const unsigned short* __restrict__ Qbf, const unsigned short* __restrict__ Khbf,
    const unsigned short* __restrict__ Vtbf, float* __restrict__ stats,
    unsigned short* __restrict__ Obf) {
  __shared__ unsigned short Kd[2][64 * 64];
  __shared__ unsigned short Vd[2][64 * 64];
  __shared__ unsigned short Ps[4][16 * 64];
  const int ob = blockIdx.x;
  const int b = (ob & 7) * 128 + (ob >> 3);   // bijective XCD swizzle
  const int lt = b & 15, k = (b >> 4) & 15, n = b >> 8;
  const int l0 = lt * 64;
  const int tid = threadIdx.x, w = tid >> 6, lane = tid & 63;
  const int lr = lane & 15, lk = lane >> 4;
  const size_t hb = (size_t)(n * 16 + k) * 65536;
  const unsigned short* qrow = Qbf + hb + (size_t)(l0 + w * 16 + lr) * 64;
  const bf16x8 qa0 = *(const bf16x8*)(qrow + lk * 8);
  const bf16x8 qa1 = *(const bf16x8*)(qrow + 32 + lk * 8);
  const int swz = lr & 7;
  int srow[2], scol[2];
#pragma unroll
  for (int q = 0; q < 2; ++q) {
    const int idx = q * 256 + tid;
    srow[q] = idx >> 3;
    scol[q] = (((idx & 7) ^ ((idx >> 3) & 7)) << 3);
  }
  const unsigned short* Kb = Khbf + hb;
  const unsigned short* Vb = Vtbf + hb;
  int4 kreg[2], vreg[2];
#pragma unroll
  for (int q = 0; q < 2; ++q) {
    kreg[q] = *(const int4*)(Kb + (size_t)srow[q] * 64 + scol[q]);
    vreg[q] = *(const int4*)(Vb + (size_t)srow[q] * 1024 + scol[q]);
  }
#pragma unroll
  for (int q = 0; q < 2; ++q) {
    *(int4*)&Kd[0][(q * 256 + tid) * 8] = kreg[q];
    *(int4*)&Vd[0][(q * 256 + tid) * 8] = vreg[q];
  }
  float m_ = -1e30f, Z_ = 0.f;
  f32x4 oacc[4];
#pragma unroll
  for (int it = 0; it < 4; ++it) oacc[it] = (f32x4){0.f, 0.f, 0.f, 0.f};
  __syncthreads();

  for (int t0 = 0; t0 < 16; ++t0) {
    const int cur = t0 & 1;
    if (t0 < 15) {    // T14: issue next tile's loads to regs before compute
      const int s1 = (t0 + 1) * 64;
#pragma unroll
      for (int q = 0; q < 2; ++q) {
        kreg[q] = *(const int4*)(Kb + (size_t)(s1 + srow[q]) * 64 + scol[q]);
        vreg[q] = *(const int4*)(Vb + (size_t)srow[q] * 1024 + s1 + scol[q]);
      }
    }
    // swapped QK^T: lane holds S[q=lr][s = st*16 + lk*4 + t]
    f32x4 sc[4];
#pragma unroll
    for (int st = 0; st < 4; ++st) {
      const int r = st * 16 + lr;
      const bf16x8 kb0 = *(const bf16x8*)&Kd[cur][r * 64 + ((lk ^ (r & 7)) << 3)];
      const bf16x8 kb1 = *(const bf16x8*)&Kd[cur][r * 64 + (((4 + lk) ^ (r & 7)) << 3)];
      f32x4 z = (f32x4){0.f, 0.f, 0.f, 0.f};
      z = __builtin_amdgcn_mfma_f32_16x16x32_bf16(kb0, qa0, z, 0, 0, 0);
      sc[st] = __builtin_amdgcn_mfma_f32_16x16x32_bf16(kb1, qa1, z, 0, 0, 0);
    }
    // tile row-max (max3 tree + cross-group shfl)
    const float a0 = MAX3(sc[0][0], sc[0][1], sc[0][2]);
    const float a1 = MAX3(sc[0][3], sc[1][0], sc[1][1]);
    const float a2 = MAX3(sc[1][2], sc[1][3], sc[2][0]);
    const float a3 = MAX3(sc[2][1], sc[2][2], sc[2][3]);
    const float a4 = MAX3(sc[3][0], sc[3][1], sc[3][2]);
    float tm = fmaxf(MAX3(a0, a1, a2), MAX3(a3, a4, sc[3][3]));
    tm = fmaxf(tm, __shfl_xor(tm, 16));
    tm = fmaxf(tm, __shfl_xor(tm, 32));
    // defer-max (T13): only rescale when the max grew by > 8
    float fac = 1.f;
    if (!__all(tm <= m_ + 8.f)) {
      const float mn = fmaxf(m_, tm);
      fac = __expf(m_ - mn);
      m_ = mn;
      const float fr0 = __shfl(fac, lk * 4 + 0);
      const float fr1 = __shfl(fac, lk * 4 + 1);
      const float fr2 = __shfl(fac, lk * 4 + 2);
      const float fr3 = __shfl(fac, lk * 4 + 3);
      const f32x4 facv = {fr0, fr1, fr2, fr3};
#pragma unroll
      for (int it = 0; it < 4; ++it) oacc[it] *= facv;
    }
    float p[4][4];
#pragma unroll
    for (int st = 0; st < 4; ++st)
#pragma unroll
      for (int t = 0; t < 4; ++t) p[st][t] = __expf(sc[st][t] - m_);
    // tree sum (depth 4)
    const float r0 = (p[0][0] + p[0][1]) + (p[0][2] + p[0][3]);
    const float r1 = (p[1][0] + p[1][1]) + (p[1][2] + p[1][3]);
    const float r2 = (p[2][0] + p[2][1]) + (p[2][2] + p[2][3]);
    const float r3 = (p[3][0] + p[3][1]) + (p[3][2] + p[3][3]);
    float rs = (r0 + r1) + (r2 + r3);
    rs += __shfl_xor(rs, 16);
    rs += __shfl_xor(rs, 32);
    Z_ = Z_ * fac + rs;
    // P write: 4 packed b64 (s = st*16+lk*4..+3), 8B-chunk XOR swizzle
#pragma unroll
    for (int st = 0; st < 4; ++st) {
      ushort4 pk;
      pk.x = f2bf(p[st][0]); pk.y = f2bf(p[st][1]);
      pk.z = f2bf(p[st][2]); pk.w = f2bf(p[st][3]);
      const int c = (st * 4 + lk) ^ (swz << 1);
      *(ushort4*)&Ps[w][lr * 64 + c * 4] = pk;
    }
    const bf16x8 pa0 = *(const bf16x8*)&Ps[w][lr * 64 + ((lk ^ swz) << 3)];
    const bf16x8 pa1 = *(const bf16x8*)&Ps[w][lr * 64 + (((4 + lk) ^ swz) << 3)];
#pragma unroll
    for (int it = 0; it < 4; ++it) {
      const int r = it * 16 + lr;
      const bf16x8 bv0 = *(const bf16x8*)&Vd[cur][r * 64 + ((lk ^ (r & 7)) << 3)];
      const bf16x8 bv1 = *(const bf16x8*)&Vd[cur][r * 64 + (((4 + lk) ^ (r & 7)) << 3)];
      f32x4 o = oacc[it];
      o = __builtin_amdgcn_mfma_f32_16x16x32_bf16(pa0, bv0, o, 0, 0, 0);
      oacc[it] = __builtin_amdgcn_mfma_f32_16x16x32_bf16(pa1, bv1, o, 0, 0, 0);
    }
    // stage next tile into the other buffer, then sync
    if (t0 < 15) {
#pragma unroll
      for (int q = 0; q < 2; ++q) {
        *(int4*)&Kd[cur ^ 1][(q * 256 + tid) * 8] = kreg[q];
        *(int4*)&Vd[cur ^ 1][(q * 256 + tid) * 8] = vreg[q];
      }
    }
    __syncthreads();
  }

  const float iz = 1.f / Z_;
  if (lane < 16) {
    const size_t so = ((size_t)(n * 16 + k) * 1024 + l0 + w * 16 + lr) * 2;
    stats[so] = m_;
    stats[so + 1] = iz;    // store inverse: wmap consumes directly
  }
  float izr[4];
#pragma unroll
  for (int t = 0; t < 4; ++t) izr[t] = __shfl(iz, lk * 4 + t);
#pragma unroll
  for (int it = 0; it < 4; ++it)
#pragma unroll
    for (int t = 0; t < 4; ++t) {
      const int l = l0 + w * 16 + lk * 4 + t;
      const int i = it * 16 + lr;
      Obf[(size_t)(l * 4 + n) * 1024 + i * 16 + k] = f2bf(oacc[it][t] * izr[t]);
    }
}

// ---------------------------------------------------------------------------
// Wmap v5: stats now hold (m, 1/Z) -> no rcp. Structure unchanged (R11-proven
// reg-prefetch dbuf).
__global__ __launch_bounds__(256) void k_wmap(const unsigned short* __restrict__ Qbf,
    const unsigned short* __restrict__ Khbf, const float* __restrict__ stats,
    float* __restrict__ Wmap) {
  __shared__ unsigned short Kst[2][64 * 64];
  const int ob = blockIdx.x;
  const int b = (ob & 7) * 128 + (ob >> 3);
  const int st = b & 15, lt = (b >> 4) & 15, n = b >> 8;
  const int l0 = lt * 64, s0 = st * 64;
  const int tid = threadIdx.x, w = tid >> 6, lane = tid & 63;
  const int lr = lane & 15, lk = lane >> 4;
  int srow[2], scol[2];
#pragma unroll
  for (int q = 0; q < 2; ++q) {
    const int idx = q * 256 + tid;
    srow[q] = idx >> 3;
    scol[q] = (((idx & 7) ^ ((idx >> 3) & 7)) << 3);
  }
  int4 kreg[2];
#pragma unroll
  for (int q = 0; q < 2; ++q)
    kreg[q] = *(const int4*)(Khbf + (size_t)(n * 16) * 65536 +
                             (size_t)(s0 + srow[q]) * 64 + scol[q]);
#pragma unroll
  for (int q = 0; q < 2; ++q)
    *(int4*)&Kst[0][(q * 256 + tid) * 8] = kreg[q];
  f32x4 wsum[4];
#pragma unroll
  for (int i = 0; i < 4; ++i) wsum[i] = (f32x4){0.f, 0.f, 0.f, 0.f};
  __syncthreads();

  for (int k = 0; k < 16; ++k) {
    const int cur = k & 1;
    const size_t hb = (size_t)(n * 16 + k) * 65536;
    if (k < 15) {
      const size_t hb1 = (size_t)(n * 16 + k + 1) * 65536;
#pragma unroll
      for (int q = 0; q < 2; ++q)
        kreg[q] = *(const int4*)(Khbf + hb1 + (size_t)(s0 + srow[q]) * 64 + scol[q]);
    }
    const unsigned short* qrow = Qbf + hb + (size_t)(l0 + w * 16 + lr) * 64;
    const bf16x8 a0 = *(const bf16x8*)(qrow + lk * 8);
    const bf16x8 a1 = *(const bf16x8*)(qrow + 32 + lk * 8);
    float mv[4], izv[4];
#pragma unroll
    for (int t = 0; t < 4; ++t) {
      const float2 mz = *(const float2*)(stats +
          ((size_t)(n * 16 + k) * 1024 + l0 + w * 16 + lk * 4 + t) * 2);
      mv[t] = mz.x; izv[t] = mz.y;   // already inverse
    }
#pragma unroll
    for (int st2 = 0; st2 < 4; ++st2) {
      const int r = st2 * 16 + lr;
      const bf16x8 kb0 = *(const bf16x8*)&Kst[cur][r * 64 + ((lk ^ (r & 7)) << 3)];
      const bf16x8 kb1 = *(const bf16x8*)&Kst[cur][r * 64 + (((4 + lk) ^ (r & 7)) << 3)];
      f32x4 z = (f32x4){0.f, 0.f, 0.f, 0.f};
      z = __builtin_amdgcn_mfma_f32_16x16x32_bf16(a0, kb0, z, 0, 0, 0);
      z = __builtin_amdgcn_mfma_f32_16x16x32_bf16(a1, kb1, z, 0, 0, 0);
#pragma unroll
      for (int t = 0; t < 4; ++t)
        wsum[st2][t] += __expf(z[t] - mv[t]) * izv[t];
    }
    if (k < 15) {
#pragma unroll
      for (int q = 0; q < 2; ++q)
        *(int4*)&Kst[cur ^ 1][(q * 256 + tid) * 8] = kreg[q];
    }
    __syncthreads();
  }
#pragma unroll
  for (int st2 = 0; st2 < 4; ++st2)
#pragma unroll
    for (int t = 0; t < 4; ++t) {
      const int l = l0 + w * 16 + lk * 4 + t;
      const int s = s0 + st2 * 16 + lr;
      Wmap[((size_t)l * 1024 + s) * 4 + n] = wsum[st2][t] * 0.0625f;
    }
}

// ---------------------------------------------------------------------------
extern "C" void kernel_launch(void* const* d_in, const int* in_sizes, int n_in,
                              void* d_out, int out_size, void* d_ws, size_t ws_size,
                              hipStream_t stream) {
  (void)in_sizes; (void)n_in; (void)out_size; (void)ws_size;
  const float* Q        = (const float*)d_in[0];
  const float* K        = (const float*)d_in[1];
  const float* V        = (const float*)d_in[2];
  const float* q_w      = (const float*)d_in[3];
  const float* k_w      = (const float*)d_in[4];
  const float* v_w      = (const float*)d_in[5];
  const float* out_w    = (const float*)d_in[6];
  const float* in_bias  = (const float*)d_in[7];
  const float* out_bias = (const float*)d_in[8];
  const float* attn_W   = (const float*)d_in[9];
  float* ws = (float*)d_ws;
  unsigned short* qw2bf = (unsigned short*)(ws + OFF_QW2BF);
  unsigned short* kwbf  = (unsigned short*)(ws + OFF_KWBF);
  unsigned short* vwbf  = (unsigned short*)(ws + OFF_VWBF);
  unsigned short* owtbf = (unsigned short*)(ws + OFF_OWTBF);
  float* qb2 = ws + OFF_QB2;
  unsigned short* Qwbf = (unsigned short*)(ws + OFF_QWBF);
  unsigned short* Khbf = (unsigned short*)(ws + OFF_KHBF);
  unsigned short* Vtbf = (unsigned short*)(ws + OFF_VTBF);
  float* st = ws + OFF_ST;
  unsigned short* Obf  = (unsigned short*)(ws + OFF_OBF);
  unsigned short* Abf  = (unsigned short*)(ws + OFF_ABF);
  float* out  = (float*)d_out;
  float* Wmap = out + 4194304;

  k_prep<<<5376, 256, 0, stream>>>(Q, K, V, q_w, k_w, v_w, out_w, attn_W,
                                   in_bias, qw2bf, qb2, kwbf, vwbf, owtbf, Abf);
  k_gemm_in<<<768, 256, 0, stream>>>(Abf, qw2bf, kwbf, vwbf,
                                     qb2, in_bias + 1024, in_bias + 2048,
                                     Qwbf, Khbf, Vtbf);
  k_flash<<<1024, 256, 0, stream>>>(Qwbf, Khbf, Vtbf, st, Obf);
  k_wmap<<<1024, 256, 0, stream>>>(Qwbf, Khbf, st, Wmap);
  k_gemm_out<<<512, 256, 0, stream>>>(Obf, owtbf, out_bias, out);
}

// Round 16
// 173.876 us; speedup vs baseline: 1.8169x; 1.0238x over previous
//
#include <hip/hip_runtime.h>
#include <cstdint>

// Problem constants: L=S=1024, N=4, E=1024, H=16, D=64
typedef __bf16 bf16x8 __attribute__((ext_vector_type(8)));
typedef float f32x4 __attribute__((ext_vector_type(4)));

#define GLOAD_LDS16(gptr, lptr)                                              \
  __builtin_amdgcn_global_load_lds(                                          \
      (const __attribute__((address_space(1))) void*)(gptr),                 \
      (__attribute__((address_space(3))) void*)(lptr), 16, 0, 0)

#define MAX3(a, b, c) fmaxf(fmaxf((a), (b)), (c))

// ws layout (float-unit offsets):
static const size_t OFF_QW2BF = 0;         // [k*64+i][j] bf16 (1M ushort)
static const size_t OFF_KWBF  = 524288;    // [k*64+i][j] bf16 (head-major)
static const size_t OFF_VWBF  = 1048576;   // [k*64+i][j] bf16 (head-major)
static const size_t OFF_OWTBF = 1572864;   // [o][j] bf16 (out_w^T)
static const size_t OFF_QB2   = 2097152;   // 1024 f32
static const size_t OFF_QWBF  = 2098176;   // [n][k][l][i] bf16 (4M ushort)
static const size_t OFF_KHBF  = 4195328;   // [n][k][s][i] bf16
static const size_t OFF_VTBF  = 6292480;   // [n][k][i][s] bf16 (V^T per head)
static const size_t OFF_ST    = 8389632;   // [n][k][l][{m,invZ}] f32 131072
static const size_t OFF_OBF   = 8520704;   // [l*4+n][e] bf16 (4M ushort)
static const size_t OFF_ABF   = 10617856;  // [3][4096][1024] bf16 (12M ushort)

// Native RNE cast -> v_cvt_pk_bf16_f32 pairs (exonerated in R13/R14).
__device__ inline unsigned short f2bf(float f) {
  return __builtin_bit_cast(unsigned short, (__bf16)f);
}

// ---------------------------------------------------------------------------
// Fused prep: blocks [0,1024) qw2-fold; [1024,2048) k_w/v_w cvt+permute;
// [2048,5120) Q/K/V f32->bf16; [5120,5376) out_w transpose.
__global__ __launch_bounds__(256) void k_prep(const float* __restrict__ Q,
    const float* __restrict__ K, const float* __restrict__ V,
    const float* __restrict__ qw, const float* __restrict__ kw,
    const float* __restrict__ vw, const float* __restrict__ ow,
    const float* __restrict__ attnW, const float* __restrict__ in_bias,
    unsigned short* __restrict__ qw2, float* __restrict__ qb2,
    unsigned short* __restrict__ kwbf, unsigned short* __restrict__ vwbf,
    unsigned short* __restrict__ owtbf, unsigned short* __restrict__ Abf) {
  __shared__ float sh[64 * 65];
  const int b = blockIdx.x;
  const int tid = threadIdx.x;
  if (b < 1024) {
    const int k = b >> 6, i = b & 63;
    if (tid < 64) sh[tid] = attnW[(tid * 64 + i) * 16 + k] * 0.03125f;
    __syncthreads();
    for (int j = tid; j < 1024; j += 256) {
      float acc = 0.f;
#pragma unroll 8
      for (int o = 0; o < 64; ++o) acc = fmaf(qw[(o * 16 + k) * 1024 + j], sh[o], acc);
      qw2[(size_t)b * 1024 + j] = f2bf(acc);
    }
    if (tid == 0) {
      float acc = 0.f;
      for (int o = 0; o < 64; ++o) acc = fmaf(in_bias[o * 16 + k], sh[o], acc);
      qb2[b] = acc;
    }
  } else if (b < 2048) {
    const int o = b - 1024;
    const int dst = (o & 15) * 64 + (o >> 4);
    const float4 va = ((const float4*)(kw + (size_t)o * 1024))[tid];
    ushort4 ha; ha.x = f2bf(va.x); ha.y = f2bf(va.y); ha.z = f2bf(va.z); ha.w = f2bf(va.w);
    ((ushort4*)(kwbf + (size_t)dst * 1024))[tid] = ha;
    const float4 vb = ((const float4*)(vw + (size_t)o * 1024))[tid];
    ushort4 hb; hb.x = f2bf(vb.x); hb.y = f2bf(vb.y); hb.z = f2bf(vb.z); hb.w = f2bf(vb.w);
    ((ushort4*)(vwbf + (size_t)dst * 1024))[tid] = hb;
  } else if (b < 5120) {
    const int bb = b - 2048;
    const int m = bb >> 10;
    const float* src = m == 0 ? Q : (m == 1 ? K : V);
    unsigned short* dst = Abf + (size_t)m * 4194304;
#pragma unroll
    for (int q = 0; q < 4; ++q) {
      const int idx = (bb & 1023) * 1024 + q * 256 + tid;
      const float4 v = ((const float4*)src)[idx];
      ushort4 h; h.x = f2bf(v.x); h.y = f2bf(v.y); h.z = f2bf(v.z); h.w = f2bf(v.w);
      ((ushort4*)dst)[idx] = h;
    }
  } else {
    float (*t)[65] = (float(*)[65])sh;
    const int tb = b - 5120;
    const int o0 = (tb & 15) * 64, j0 = (tb >> 4) * 64;
    const int r = tid >> 4, c4 = tid & 15;
#pragma unroll
    for (int q = 0; q < 4; ++q) {
      const int row = r + q * 16;
      const float4 v = *(const float4*)&ow[(size_t)(j0 + row) * 1024 + o0 + c4 * 4];
      t[row][c4 * 4 + 0] = v.x; t[row][c4 * 4 + 1] = v.y;
      t[row][c4 * 4 + 2] = v.z; t[row][c4 * 4 + 3] = v.w;
    }
    __syncthreads();
#pragma unroll
    for (int q = 0; q < 4; ++q) {
      const int orow = r + q * 16;
      ushort4 h;
      h.x = f2bf(t[c4 * 4 + 0][orow]); h.y = f2bf(t[c4 * 4 + 1][orow]);
      h.z = f2bf(t[c4 * 4 + 2][orow]); h.w = f2bf(t[c4 * 4 + 3][orow]);
      *(ushort4*)&owtbf[(size_t)(o0 + orow) * 1024 + j0 + c4 * 4] = h;
    }
  }
}

// ---------------------------------------------------------------------------
// Merged in-projection GEMMs v6 (R11-proven): global_load_lds + LDS double
// buffer with counted vmcnt(8).
__global__ __launch_bounds__(256) void k_gemm_in(
    const unsigned short* __restrict__ Abf, const unsigned short* __restrict__ Bq,
    const unsigned short* __restrict__ Bk, const unsigned short* __restrict__ Bv,
    const float* __restrict__ bq, const float* __restrict__ bk,
    const float* __restrict__ bv, unsigned short* __restrict__ Cq,
    unsigned short* __restrict__ Ck, unsigned short* __restrict__ Cv) {
  __shared__ unsigned short As[2][128 * 64];
  __shared__ unsigned short Bs[2][128 * 64];
  const int id = blockIdx.x;                     // 0..767
  const int g  = (id & 7) + ((id >> 6) << 3);    // 0..95 (A-panel group)
  const int bx = (id >> 3) & 7;                  // o-block
  const int by = g & 31, bz = g >> 5;
  const unsigned short* A = Abf + (size_t)bz * 4194304;
  const unsigned short* B = bz == 0 ? Bq : (bz == 1 ? Bk : Bv);
  const float* bias       = bz == 0 ? bq : (bz == 1 ? bk : bv);
  unsigned short* C       = bz == 0 ? Cq : (bz == 1 ? Ck : Cv);
  const int m0 = by * 128, o0 = bx * 128;
  const int tid = threadIdx.x;
  const int wid = tid >> 6, lane = tid & 63;
  const int wr = wid >> 1, wc = wid & 1;
  const int lr = lane & 15, lk = lane >> 4;
  int srow[4], scol[4];
#pragma unroll
  for (int q = 0; q < 4; ++q) {
    const int idx = q * 256 + tid;
    srow[q] = idx >> 3;
    scol[q] = (((idx & 7) ^ ((idx >> 3) & 7)) << 3);
  }
  f32x4 acc[4][4];
#pragma unroll
  for (int i = 0; i < 4; ++i)
#pragma unroll
    for (int j = 0; j < 4; ++j) acc[i][j] = (f32x4){0.f, 0.f, 0.f, 0.f};

#pragma unroll
  for (int q = 0; q < 4; ++q) {
    GLOAD_LDS16(&A[(size_t)(m0 + srow[q]) * 1024 + scol[q]], &As[0][(q * 256 + tid) * 8]);
    GLOAD_LDS16(&B[(size_t)(o0 + srow[q]) * 1024 + scol[q]], &Bs[0][(q * 256 + tid) * 8]);
  }

  for (int t = 0; t < 16; ++t) {
    const int cur = t & 1;
    if (t < 15) {
      const int kb = (t + 1) * 64;
#pragma unroll
      for (int q = 0; q < 4; ++q) {
        GLOAD_LDS16(&A[(size_t)(m0 + srow[q]) * 1024 + kb + scol[q]],
                    &As[cur ^ 1][(q * 256 + tid) * 8]);
        GLOAD_LDS16(&B[(size_t)(o0 + srow[q]) * 1024 + kb + scol[q]],
                    &Bs[cur ^ 1][(q * 256 + tid) * 8]);
      }
      asm volatile("s_waitcnt vmcnt(8)" ::: "memory");   // oldest 8 (cur tile) done
    } else {
      asm volatile("s_waitcnt vmcnt(0)" ::: "memory");
    }
    __builtin_amdgcn_s_barrier();
#pragma unroll
    for (int ph = 0; ph < 2; ++ph) {
      const int ck = ph * 4 + lk;
      bf16x8 af[4], bfr[4];
#pragma unroll
      for (int f = 0; f < 4; ++f) {
        const int ra = wr * 64 + f * 16 + lr;
        af[f] = *(const bf16x8*)&As[cur][ra * 64 + ((ck ^ (ra & 7)) << 3)];
        const int rb = wc * 64 + f * 16 + lr;
        bfr[f] = *(const bf16x8*)&Bs[cur][rb * 64 + ((ck ^ (rb & 7)) << 3)];
      }
#pragma unroll
      for (int i = 0; i < 4; ++i)
#pragma unroll
        for (int j = 0; j < 4; ++j)
          acc[i][j] = __builtin_amdgcn_mfma_f32_16x16x32_bf16(af[i], bfr[j], acc[i][j], 0, 0, 0);
    }
    __builtin_amdgcn_s_barrier();   // readers done before buf^1 gets overwritten
  }
#pragma unroll
  for (int fi = 0; fi < 4; ++fi)
#pragma unroll
    for (int fj = 0; fj < 4; ++fj) {
      const int o = o0 + wc * 64 + fj * 16 + lr;
      const int kk = o >> 6, ii = o & 63;
      const float bo = bz == 0 ? bias[o] : bias[ii * 16 + kk];
#pragma unroll
      for (int t = 0; t < 4; ++t) {
        const int m = m0 + wr * 64 + fi * 16 + lk * 4 + t;
        const float v = acc[fi][fj][t] + bo;
        const int l = m >> 2, nn = m & 3;
        if (bz <= 1) {
          C[(((size_t)(nn * 16 + kk) * 1024 + l) << 6) + ii] = f2bf(v);
        } else {
          C[(((size_t)(nn * 16 + kk) * 64 + ii) << 10) + l] = f2bf(v);
        }
      }
    }
}

// ---------------------------------------------------------------------------
// Out-projection GEMM v5 (R11-proven): counted-vmcnt dbuf, vmcnt(6).
__global__ __launch_bounds__(256) void k_gemm_out(
    const unsigned short* __restrict__ A, const unsigned short* __restrict__ B,
    const float* __restrict__ bias, float* __restrict__ C) {
  __shared__ unsigned short As[2][64 * 64];
  __shared__ unsigned short Bs[2][128 * 64];
  const int id = blockIdx.x;                     // 0..511
  const int g  = (id & 7) + ((id >> 6) << 3);    // 0..63 m-block
  const int bx = (id >> 3) & 7;                  // o-block
  const int m0 = g * 64, o0 = bx * 128;
  const int tid = threadIdx.x;
  const int wid = tid >> 6, lane = tid & 63;
  const int wr = wid >> 1, wc = wid & 1;
  const int lr = lane & 15, lk = lane >> 4;
  int srow[4], scol[4];
#pragma unroll
  for (int q = 0; q < 4; ++q) {
    const int idx = q * 256 + tid;
    srow[q] = idx >> 3;
    scol[q] = (((idx & 7) ^ ((idx >> 3) & 7)) << 3);
  }
  f32x4 acc[2][4];
#pragma unroll
  for (int i = 0; i < 2; ++i)
#pragma unroll
    for (int j = 0; j < 4; ++j) acc[i][j] = (f32x4){0.f, 0.f, 0.f, 0.f};

#pragma unroll
  for (int q = 0; q < 2; ++q)
    GLOAD_LDS16(&A[(size_t)(m0 + srow[q]) * 1024 + scol[q]], &As[0][(q * 256 + tid) * 8]);
#pragma unroll
  for (int q = 0; q < 4; ++q)
    GLOAD_LDS16(&B[(size_t)(o0 + srow[q]) * 1024 + scol[q]], &Bs[0][(q * 256 + tid) * 8]);

  for (int t = 0; t < 16; ++t) {
    const int cur = t & 1;
    if (t < 15) {
      const int kb = (t + 1) * 64;
#pragma unroll
      for (int q = 0; q < 2; ++q)
        GLOAD_LDS16(&A[(size_t)(m0 + srow[q]) * 1024 + kb + scol[q]],
                    &As[cur ^ 1][(q * 256 + tid) * 8]);
#pragma unroll
      for (int q = 0; q < 4; ++q)
        GLOAD_LDS16(&B[(size_t)(o0 + srow[q]) * 1024 + kb + scol[q]],
                    &Bs[cur ^ 1][(q * 256 + tid) * 8]);
      asm volatile("s_waitcnt vmcnt(6)" ::: "memory");
    } else {
      asm volatile("s_waitcnt vmcnt(0)" ::: "memory");
    }
    __builtin_amdgcn_s_barrier();
#pragma unroll
    for (int ph = 0; ph < 2; ++ph) {
      const int ck = ph * 4 + lk;
      bf16x8 af[2], bfr[4];
#pragma unroll
      for (int f = 0; f < 2; ++f) {
        const int ra = wr * 32 + f * 16 + lr;
        af[f] = *(const bf16x8*)&As[cur][ra * 64 + ((ck ^ (ra & 7)) << 3)];
      }
#pragma unroll
      for (int f = 0; f < 4; ++f) {
        const int rb = wc * 64 + f * 16 + lr;
        bfr[f] = *(const bf16x8*)&Bs[cur][rb * 64 + ((ck ^ (rb & 7)) << 3)];
      }
#pragma unroll
      for (int i = 0; i < 2; ++i)
#pragma unroll
        for (int j = 0; j < 4; ++j)
          acc[i][j] = __builtin_amdgcn_mfma_f32_16x16x32_bf16(af[i], bfr[j], acc[i][j], 0, 0, 0);
    }
    __builtin_amdgcn_s_barrier();
  }
#pragma unroll
  for (int fi = 0; fi < 2; ++fi)
#pragma unroll
    for (int fj = 0; fj < 4; ++fj) {
      const int o = o0 + wc * 64 + fj * 16 + lr;
      const float bo = bias[o];
#pragma unroll
      for (int t = 0; t < 4; ++t) {
        const int m = m0 + wr * 32 + fi * 16 + lk * 4 + t;
        C[(size_t)m * 1024 + o] = acc[fi][fj][t] + bo;
      }
    }
}

// ---------------------------------------------------------------------------
// MFMA flash v8: l-tile 128 — each wave owns TWO independent 16-row q-groups
// (2x ILP on the serial QK->softmax->PV chain; K/V frag reads shared across
// groups; staging+barriers per unit work halved). Sync structure identical to
// the R14-proven reg-staged dbuf + __syncthreads (parameter-scale change).
__global__ __launch_bounds__(256) void k_flash(
    const unsigned short* __restrict__ Qbf, const unsigned short* __restrict__ Khbf,
    const unsigned short* __restrict__ Vtbf, float* __restrict__ stats,
    unsigned short* __restrict__ Obf) {
  __shared__ unsigned short Kd[2][64 * 64];
  __shared__ unsigned short Vd[2][64 * 64];
  __shared__ unsigned short Ps[4][32 * 64];
  const int ob = blockIdx.x;                  // 0..511
  const int b = (ob & 7) * 64 + (ob >> 3);    // bijective XCD swizzle (512%8==0)
  const int lt = b & 7, k = (b >> 3) & 15, n = b >> 7;
  const int l0 = lt * 128;
  const int tid = threadIdx.x, w = tid >> 6, lane = tid & 63;
  const int lr = lane & 15, lk = lane >> 4;
  const size_t hb = (size_t)(n * 16 + k) * 65536;
  bf16x8 qa0[2], qa1[2];
#pragma unroll
  for (int g = 0; g < 2; ++g) {
    const unsigned short* qrow = Qbf + hb + (size_t)(l0 + w * 32 + g * 16 + lr) * 64;
    qa0[g] = *(const bf16x8*)(qrow + lk * 8);
    qa1[g] = *(const bf16x8*)(qrow + 32 + lk * 8);
  }
  const int swz = lr & 7;
  int srow[2], scol[2];
#pragma unroll
  for (int q = 0; q < 2; ++q) {
    const int idx = q * 256 + tid;
    srow[q] = idx >> 3;
    scol[q] = (((idx & 7) ^ ((idx >> 3) & 7)) << 3);
  }
  const unsigned short* Kb = Khbf + hb;
  const unsigned short* Vb = Vtbf + hb;
  int4 kreg[2], vreg[2];
#pragma unroll
  for (int q = 0; q < 2; ++q) {
    kreg[q] = *(const int4*)(Kb + (size_t)srow[q] * 64 + scol[q]);
    vreg[q] = *(const int4*)(Vb + (size_t)srow[q] * 1024 + scol[q]);
  }
#pragma unroll
  for (int q = 0; q < 2; ++q) {
    *(int4*)&Kd[0][(q * 256 + tid) * 8] = kreg[q];
    *(int4*)&Vd[0][(q * 256 + tid) * 8] = vreg[q];
  }
  float m_[2] = {-1e30f, -1e30f}, Z_[2] = {0.f, 0.f};
  f32x4 oacc[2][4];
#pragma unroll
  for (int g = 0; g < 2; ++g)
#pragma unroll
    for (int it = 0; it < 4; ++it) oacc[g][it] = (f32x4){0.f, 0.f, 0.f, 0.f};
  __syncthreads();

  for (int t0 = 0; t0 < 16; ++t0) {
    const int cur = t0 & 1;
    if (t0 < 15) {    // T14: issue next tile's loads to regs before compute
      const int s1 = (t0 + 1) * 64;
#pragma unroll
      for (int q = 0; q < 2; ++q) {
        kreg[q] = *(const int4*)(Kb + (size_t)(s1 + srow[q]) * 64 + scol[q]);
        vreg[q] = *(const int4*)(Vb + (size_t)srow[q] * 1024 + s1 + scol[q]);
      }
    }
    // swapped QK^T for both groups: K-frags read ONCE, feed 2 MFMAs each
    f32x4 sc[2][4];
#pragma unroll
    for (int st = 0; st < 4; ++st) {
      const int r = st * 16 + lr;
      const bf16x8 kb0 = *(const bf16x8*)&Kd[cur][r * 64 + ((lk ^ (r & 7)) << 3)];
      const bf16x8 kb1 = *(const bf16x8*)&Kd[cur][r * 64 + (((4 + lk) ^ (r & 7)) << 3)];
#pragma unroll
      for (int g = 0; g < 2; ++g) {
        f32x4 z = (f32x4){0.f, 0.f, 0.f, 0.f};
        z = __builtin_amdgcn_mfma_f32_16x16x32_bf16(kb0, qa0[g], z, 0, 0, 0);
        sc[g][st] = __builtin_amdgcn_mfma_f32_16x16x32_bf16(kb1, qa1[g], z, 0, 0, 0);
      }
    }
    // two independent online-softmax chains (interleave to hide latency)
    float p[2][4][4];
#pragma unroll
    for (int g = 0; g < 2; ++g) {
      const float a0 = MAX3(sc[g][0][0], sc[g][0][1], sc[g][0][2]);
      const float a1 = MAX3(sc[g][0][3], sc[g][1][0], sc[g][1][1]);
      const float a2 = MAX3(sc[g][1][2], sc[g][1][3], sc[g][2][0]);
      const float a3 = MAX3(sc[g][2][1], sc[g][2][2], sc[g][2][3]);
      const float a4 = MAX3(sc[g][3][0], sc[g][3][1], sc[g][3][2]);
      float tm = fmaxf(MAX3(a0, a1, a2), MAX3(a3, a4, sc[g][3][3]));
      tm = fmaxf(tm, __shfl_xor(tm, 16));
      tm = fmaxf(tm, __shfl_xor(tm, 32));
      float fac = 1.f;
      if (!__all(tm <= m_[g] + 8.f)) {      // defer-max (T13)
        const float mn = fmaxf(m_[g], tm);
        fac = __expf(m_[g] - mn);
        m_[g] = mn;
        const float fr0 = __shfl(fac, lk * 4 + 0);
        const float fr1 = __shfl(fac, lk * 4 + 1);
        const float fr2 = __shfl(fac, lk * 4 + 2);
        const float fr3 = __shfl(fac, lk * 4 + 3);
        const f32x4 facv = {fr0, fr1, fr2, fr3};
#pragma unroll
        for (int it = 0; it < 4; ++it) oacc[g][it] *= facv;
      }
#pragma unroll
      for (int st = 0; st < 4; ++st)
#pragma unroll
        for (int t = 0; t < 4; ++t) p[g][st][t] = __expf(sc[g][st][t] - m_[g]);
      const float r0 = (p[g][0][0] + p[g][0][1]) + (p[g][0][2] + p[g][0][3]);
      const float r1 = (p[g][1][0] + p[g][1][1]) + (p[g][1][2] + p[g][1][3]);
      const float r2 = (p[g][2][0] + p[g][2][1]) + (p[g][2][2] + p[g][2][3]);
      const float r3 = (p[g][3][0] + p[g][3][1]) + (p[g][3][2] + p[g][3][3]);
      float rs = (r0 + r1) + (r2 + r3);
      rs += __shfl_xor(rs, 16);
      rs += __shfl_xor(rs, 32);
      Z_[g] = Z_[g] * fac + rs;
      // P write: rows g*16+lr, 8B-chunk XOR swizzle
#pragma unroll
      for (int st = 0; st < 4; ++st) {
        ushort4 pk;
        pk.x = f2bf(p[g][st][0]); pk.y = f2bf(p[g][st][1]);
        pk.z = f2bf(p[g][st][2]); pk.w = f2bf(p[g][st][3]);
        const int c = (st * 4 + lk) ^ (swz << 1);
        *(ushort4*)&Ps[w][(g * 16 + lr) * 64 + c * 4] = pk;
      }
    }
    // PV: V-frags read ONCE, feed both groups
    bf16x8 pa0[2], pa1[2];
#pragma unroll
    for (int g = 0; g < 2; ++g) {
      pa0[g] = *(const bf16x8*)&Ps[w][(g * 16 + lr) * 64 + ((lk ^ swz) << 3)];
      pa1[g] = *(const bf16x8*)&Ps[w][(g * 16 + lr) * 64 + (((4 + lk) ^ swz) << 3)];
    }
#pragma unroll
    for (int it = 0; it < 4; ++it) {
      const int r = it * 16 + lr;
      const bf16x8 bv0 = *(const bf16x8*)&Vd[cur][r * 64 + ((lk ^ (r & 7)) << 3)];
      const bf16x8 bv1 = *(const bf16x8*)&Vd[cur][r * 64 + (((4 + lk) ^ (r & 7)) << 3)];
#pragma unroll
      for (int g = 0; g < 2; ++g) {
        f32x4 o = oacc[g][it];
        o = __builtin_amdgcn_mfma_f32_16x16x32_bf16(pa0[g], bv0, o, 0, 0, 0);
        oacc[g][it] = __builtin_amdgcn_mfma_f32_16x16x32_bf16(pa1[g], bv1, o, 0, 0, 0);
      }
    }
    // stage next tile into the other buffer, then sync
    if (t0 < 15) {
#pragma unroll
      for (int q = 0; q < 2; ++q) {
        *(int4*)&Kd[cur ^ 1][(q * 256 + tid) * 8] = kreg[q];
        *(int4*)&Vd[cur ^ 1][(q * 256 + tid) * 8] = vreg[q];
      }
    }
    __syncthreads();
  }

#pragma unroll
  for (int g = 0; g < 2; ++g) {
    const float iz = 1.f / Z_[g];
    if (lane < 16) {
      const size_t so = ((size_t)(n * 16 + k) * 1024 + l0 + w * 32 + g * 16 + lr) * 2;
      stats[so] = m_[g];
      stats[so + 1] = iz;    // store inverse: wmap consumes directly
    }
    float izr[4];
#pragma unroll
    for (int t = 0; t < 4; ++t) izr[t] = __shfl(iz, lk * 4 + t);
#pragma unroll
    for (int it = 0; it < 4; ++it)
#pragma unroll
      for (int t = 0; t < 4; ++t) {
        const int l = l0 + w * 32 + g * 16 + lk * 4 + t;
        const int i = it * 16 + lr;
        Obf[(size_t)(l * 4 + n) * 1024 + i * 16 + k] = f2bf(oacc[g][it][t] * izr[t]);
      }
  }
}

// ---------------------------------------------------------------------------
// Wmap v5 (R15-proven): stats hold (m, 1/Z) -> no rcp; reg-prefetch dbuf.
__global__ __launch_bounds__(256) void k_wmap(const unsigned short* __restrict__ Qbf,
    const unsigned short* __restrict__ Khbf, const float* __restrict__ stats,
    float* __restrict__ Wmap) {
  __shared__ unsigned short Kst[2][64 * 64];
  const int ob = blockIdx.x;
  const int b = (ob & 7) * 128 + (ob >> 3);
  const int st = b & 15, lt = (b >> 4) & 15, n = b >> 8;
  const int l0 = lt * 64, s0 = st * 64;
  const int tid = threadIdx.x, w = tid >> 6, lane = tid & 63;
  const int lr = lane & 15, lk = lane >> 4;
  int srow[2], scol[2];
#pragma unroll
  for (int q = 0; q < 2; ++q) {
    const int idx = q * 256 + tid;
    srow[q] = idx >> 3;
    scol[q] = (((idx & 7) ^ ((idx >> 3) & 7)) << 3);
  }
  int4 kreg[2];
#pragma unroll
  for (int q = 0; q < 2; ++q)
    kreg[q] = *(const int4*)(Khbf + (size_t)(n * 16) * 65536 +
                             (size_t)(s0 + srow[q]) * 64 + scol[q]);
#pragma unroll
  for (int q = 0; q < 2; ++q)
    *(int4*)&Kst[0][(q * 256 + tid) * 8] = kreg[q];
  f32x4 wsum[4];
#pragma unroll
  for (int i = 0; i < 4; ++i) wsum[i] = (f32x4){0.f, 0.f, 0.f, 0.f};
  __syncthreads();

  for (int k = 0; k < 16; ++k) {
    const int cur = k & 1;
    const size_t hb = (size_t)(n * 16 + k) * 65536;
    if (k < 15) {
      const size_t hb1 = (size_t)(n * 16 + k + 1) * 65536;
#pragma unroll
      for (int q = 0; q < 2; ++q)
        kreg[q] = *(const int4*)(Khbf + hb1 + (size_t)(s0 + srow[q]) * 64 + scol[q]);
    }
    const unsigned short* qrow = Qbf + hb + (size_t)(l0 + w * 16 + lr) * 64;
    const bf16x8 a0 = *(const bf16x8*)(qrow + lk * 8);
    const bf16x8 a1 = *(const bf16x8*)(qrow + 32 + lk * 8);
    float mv[4], izv[4];
#pragma unroll
    for (int t = 0; t < 4; ++t) {
      const float2 mz = *(const float2*)(stats +
          ((size_t)(n * 16 + k) * 1024 + l0 + w * 16 + lk * 4 + t) * 2);
      mv[t] = mz.x; izv[t] = mz.y;   // already inverse
    }
#pragma unroll
    for (int st2 = 0; st2 < 4; ++st2) {
      const int r = st2 * 16 + lr;
      const bf16x8 kb0 = *(const bf16x8*)&Kst[cur][r * 64 + ((lk ^ (r & 7)) << 3)];
      const bf16x8 kb1 = *(const bf16x8*)&Kst[cur][r * 64 + (((4 + lk) ^ (r & 7)) << 3)];
      f32x4 z = (f32x4){0.f, 0.f, 0.f, 0.f};
      z = __builtin_amdgcn_mfma_f32_16x16x32_bf16(a0, kb0, z, 0, 0, 0);
      z = __builtin_amdgcn_mfma_f32_16x16x32_bf16(a1, kb1, z, 0, 0, 0);
#pragma unroll
      for (int t = 0; t < 4; ++t)
        wsum[st2][t] += __expf(z[t] - mv[t]) * izv[t];
    }
    if (k < 15) {
#pragma unroll
      for (int q = 0; q < 2; ++q)
        *(int4*)&Kst[cur ^ 1][(q * 256 + tid) * 8] = kreg[q];
    }
    __syncthreads();
  }
#pragma unroll
  for (int st2 = 0; st2 < 4; ++st2)
#pragma unroll
    for (int t = 0; t < 4; ++t) {
      const int l = l0 + w * 16 + lk * 4 + t;
      const int s = s0 + st2 * 16 + lr;
      Wmap[((size_t)l * 1024 + s) * 4 + n] = wsum[st2][t] * 0.0625f;
    }
}

// ---------------------------------------------------------------------------
extern "C" void kernel_launch(void* const* d_in, const int* in_sizes, int n_in,
                              void* d_out, int out_size, void* d_ws, size_t ws_size,
                              hipStream_t stream) {
  (void)in_sizes; (void)n_in; (void)out_size; (void)ws_size;
  const float* Q        = (const float*)d_in[0];
  const float* K        = (const float*)d_in[1];
  const float* V        = (const float*)d_in[2];
  const float* q_w      = (const float*)d_in[3];
  const float* k_w      = (const float*)d_in[4];
  const float* v_w      = (const float*)d_in[5];
  const float* out_w    = (const float*)d_in[6];
  const float* in_bias  = (const float*)d_in[7];
  const float* out_bias = (const float*)d_in[8];
  const float* attn_W   = (const float*)d_in[9];
  float* ws = (float*)d_ws;
  unsigned short* qw2bf = (unsigned short*)(ws + OFF_QW2BF);
  unsigned short* kwbf  = (unsigned short*)(ws + OFF_KWBF);
  unsigned short* vwbf  = (unsigned short*)(ws + OFF_VWBF);
  unsigned short* owtbf = (unsigned short*)(ws + OFF_OWTBF);
  float* qb2 = ws + OFF_QB2;
  unsigned short* Qwbf = (unsigned short*)(ws + OFF_QWBF);
  unsigned short* Khbf = (unsigned short*)(ws + OFF_KHBF);
  unsigned short* Vtbf = (unsigned short*)(ws + OFF_VTBF);
  float* st = ws + OFF_ST;
  unsigned short* Obf  = (unsigned short*)(ws + OFF_OBF);
  unsigned short* Abf  = (unsigned short*)(ws + OFF_ABF);
  float* out  = (float*)d_out;
  float* Wmap = out + 4194304;

  k_prep<<<5376, 256, 0, stream>>>(Q, K, V, q_w, k_w, v_w, out_w, attn_W,
                                   in_bias, qw2bf, qb2, kwbf, vwbf, owtbf, Abf);
  k_gemm_in<<<768, 256, 0, stream>>>(Abf, qw2bf, kwbf, vwbf,
                                     qb2, in_bias + 1024, in_bias + 2048,
                                     Qwbf, Khbf, Vtbf);
  k_flash<<<512, 256, 0, stream>>>(Qwbf, Khbf, Vtbf, st, Obf);
  k_wmap<<<1024, 256, 0, stream>>>(Qwbf, Khbf, st, Wmap);
  k_gemm_out<<<512, 256, 0, stream>>>(Obf, owtbf, out_bias, out);
}

// Round 20
// 173.565 us; speedup vs baseline: 1.8201x; 1.0018x over previous
//
#include <hip/hip_runtime.h>
#include <cstdint>

// Problem constants: L=S=1024, N=4, E=1024, H=16, D=64
typedef __bf16 bf16x8 __attribute__((ext_vector_type(8)));
typedef float f32x4 __attribute__((ext_vector_type(4)));

#define GLOAD_LDS16(gptr, lptr)                                              \
  __builtin_amdgcn_global_load_lds(                                          \
      (const __attribute__((address_space(1))) void*)(gptr),                 \
      (__attribute__((address_space(3))) void*)(lptr), 16, 0, 0)

#define MAX3(a, b, c) fmaxf(fmaxf((a), (b)), (c))

// ws layout (float-unit offsets):
static const size_t OFF_QW2BF = 0;         // [k*64+i][j] bf16 (1M ushort)
static const size_t OFF_KWBF  = 524288;    // [k*64+i][j] bf16 (head-major)
static const size_t OFF_VWBF  = 1048576;   // [k*64+i][j] bf16 (head-major)
static const size_t OFF_OWTBF = 1572864;   // [o][j] bf16 (out_w^T)
static const size_t OFF_QB2   = 2097152;   // 1024 f32
static const size_t OFF_QWBF  = 2098176;   // [n][k][l][i] bf16 (4M ushort)
static const size_t OFF_KHBF  = 4195328;   // [n][k][s][i] bf16
static const size_t OFF_VTBF  = 6292480;   // [n][k][i][s] bf16 (V^T per head)
static const size_t OFF_ST    = 8389632;   // [n][k][l][{m,invZ}] f32
static const size_t OFF_OBF   = 8520704;   // [l*4+n][e] bf16 (4M ushort)
static const size_t OFF_ABF   = 10617856;  // [3][4096][1024] bf16 (12M ushort)

// Native RNE cast -> v_cvt_pk_bf16_f32 pairs (exonerated R13/R14).
// SHELVED (2 failures each): exp2-domain fold (R18/R19-adjacent), k_tail
// launch merge (R18/R19 — counted-vmcnt breaks when compiler VMEM lands
// inside the counting window of the merged body).
__device__ inline unsigned short f2bf(float f) {
  return __builtin_bit_cast(unsigned short, (__bf16)f);
}

// ---------------------------------------------------------------------------
// Fused prep: blocks [0,1024) qw2-fold; [1024,2048) k_w/v_w cvt+permute;
// [2048,5120) Q/K/V f32->bf16; [5120,5376) out_w transpose.
__global__ __launch_bounds__(256) void k_prep(const float* __restrict__ Q,
    const float* __restrict__ K, const float* __restrict__ V,
    const float* __restrict__ qw, const float* __restrict__ kw,
    const float* __restrict__ vw, const float* __restrict__ ow,
    const float* __restrict__ attnW, const float* __restrict__ in_bias,
    unsigned short* __restrict__ qw2, float* __restrict__ qb2,
    unsigned short* __restrict__ kwbf, unsigned short* __restrict__ vwbf,
    unsigned short* __restrict__ owtbf, unsigned short* __restrict__ Abf) {
  __shared__ float sh[64 * 65];
  const int b = blockIdx.x;
  const int tid = threadIdx.x;
  if (b < 1024) {
    const int k = b >> 6, i = b & 63;
    if (tid < 64) sh[tid] = attnW[(tid * 64 + i) * 16 + k] * 0.03125f;
    __syncthreads();
    for (int j = tid; j < 1024; j += 256) {
      float acc = 0.f;
#pragma unroll 8
      for (int o = 0; o < 64; ++o) acc = fmaf(qw[(o * 16 + k) * 1024 + j], sh[o], acc);
      qw2[(size_t)b * 1024 + j] = f2bf(acc);
    }
    if (tid == 0) {
      float acc = 0.f;
      for (int o = 0; o < 64; ++o) acc = fmaf(in_bias[o * 16 + k], sh[o], acc);
      qb2[b] = acc;
    }
  } else if (b < 2048) {
    const int o = b - 1024;
    const int dst = (o & 15) * 64 + (o >> 4);
    const float4 va = ((const float4*)(kw + (size_t)o * 1024))[tid];
    ushort4 ha; ha.x = f2bf(va.x); ha.y = f2bf(va.y); ha.z = f2bf(va.z); ha.w = f2bf(va.w);
    ((ushort4*)(kwbf + (size_t)dst * 1024))[tid] = ha;
    const float4 vb = ((const float4*)(vw + (size_t)o * 1024))[tid];
    ushort4 hb; hb.x = f2bf(vb.x); hb.y = f2bf(vb.y); hb.z = f2bf(vb.z); hb.w = f2bf(vb.w);
    ((ushort4*)(vwbf + (size_t)dst * 1024))[tid] = hb;
  } else if (b < 5120) {
    const int bb = b - 2048;
    const int m = bb >> 10;
    const float* src = m == 0 ? Q : (m == 1 ? K : V);
    unsigned short* dst = Abf + (size_t)m * 4194304;
#pragma unroll
    for (int q = 0; q < 4; ++q) {
      const int idx = (bb & 1023) * 1024 + q * 256 + tid;
      const float4 v = ((const float4*)src)[idx];
      ushort4 h; h.x = f2bf(v.x); h.y = f2bf(v.y); h.z = f2bf(v.z); h.w = f2bf(v.w);
      ((ushort4*)dst)[idx] = h;
    }
  } else {
    float (*t)[65] = (float(*)[65])sh;
    const int tb = b - 5120;
    const int o0 = (tb & 15) * 64, j0 = (tb >> 4) * 64;
    const int r = tid >> 4, c4 = tid & 15;
#pragma unroll
    for (int q = 0; q < 4; ++q) {
      const int row = r + q * 16;
      const float4 v = *(const float4*)&ow[(size_t)(j0 + row) * 1024 + o0 + c4 * 4];
      t[row][c4 * 4 + 0] = v.x; t[row][c4 * 4 + 1] = v.y;
      t[row][c4 * 4 + 2] = v.z; t[row][c4 * 4 + 3] = v.w;
    }
    __syncthreads();
#pragma unroll
    for (int q = 0; q < 4; ++q) {
      const int orow = r + q * 16;
      ushort4 h;
      h.x = f2bf(t[c4 * 4 + 0][orow]); h.y = f2bf(t[c4 * 4 + 1][orow]);
      h.z = f2bf(t[c4 * 4 + 2][orow]); h.w = f2bf(t[c4 * 4 + 3][orow]);
      *(ushort4*)&owtbf[(size_t)(o0 + orow) * 1024 + j0 + c4 * 4] = h;
    }
  }
}

// ---------------------------------------------------------------------------
// Merged in-projection GEMMs v6 (R11-proven): global_load_lds + LDS double
// buffer with counted vmcnt(8).
__global__ __launch_bounds__(256) void k_gemm_in(
    const unsigned short* __restrict__ Abf, const unsigned short* __restrict__ Bq,
    const unsigned short* __restrict__ Bk, const unsigned short* __restrict__ Bv,
    const float* __restrict__ bq, const float* __restrict__ bk,
    const float* __restrict__ bv, unsigned short* __restrict__ Cq,
    unsigned short* __restrict__ Ck, unsigned short* __restrict__ Cv) {
  __shared__ unsigned short As[2][128 * 64];
  __shared__ unsigned short Bs[2][128 * 64];
  const int id = blockIdx.x;                     // 0..767
  const int g  = (id & 7) + ((id >> 6) << 3);    // 0..95 (A-panel group)
  const int bx = (id >> 3) & 7;                  // o-block
  const int by = g & 31, bz = g >> 5;
  const unsigned short* A = Abf + (size_t)bz * 4194304;
  const unsigned short* B = bz == 0 ? Bq : (bz == 1 ? Bk : Bv);
  const float* bias       = bz == 0 ? bq : (bz == 1 ? bk : bv);
  unsigned short* C       = bz == 0 ? Cq : (bz == 1 ? Ck : Cv);
  const int m0 = by * 128, o0 = bx * 128;
  const int tid = threadIdx.x;
  const int wid = tid >> 6, lane = tid & 63;
  const int wr = wid >> 1, wc = wid & 1;
  const int lr = lane & 15, lk = lane >> 4;
  int srow[4], scol[4];
#pragma unroll
  for (int q = 0; q < 4; ++q) {
    const int idx = q * 256 + tid;
    srow[q] = idx >> 3;
    scol[q] = (((idx & 7) ^ ((idx >> 3) & 7)) << 3);
  }
  f32x4 acc[4][4];
#pragma unroll
  for (int i = 0; i < 4; ++i)
#pragma unroll
    for (int j = 0; j < 4; ++j) acc[i][j] = (f32x4){0.f, 0.f, 0.f, 0.f};

#pragma unroll
  for (int q = 0; q < 4; ++q) {
    GLOAD_LDS16(&A[(size_t)(m0 + srow[q]) * 1024 + scol[q]], &As[0][(q * 256 + tid) * 8]);
    GLOAD_LDS16(&B[(size_t)(o0 + srow[q]) * 1024 + scol[q]], &Bs[0][(q * 256 + tid) * 8]);
  }

  for (int t = 0; t < 16; ++t) {
    const int cur = t & 1;
    if (t < 15) {
      const int kb = (t + 1) * 64;
#pragma unroll
      for (int q = 0; q < 4; ++q) {
        GLOAD_LDS16(&A[(size_t)(m0 + srow[q]) * 1024 + kb + scol[q]],
                    &As[cur ^ 1][(q * 256 + tid) * 8]);
        GLOAD_LDS16(&B[(size_t)(o0 + srow[q]) * 1024 + kb + scol[q]],
                    &Bs[cur ^ 1][(q * 256 + tid) * 8]);
      }
      asm volatile("s_waitcnt vmcnt(8)" ::: "memory");   // oldest 8 (cur tile) done
    } else {
      asm volatile("s_waitcnt vmcnt(0)" ::: "memory");
    }
    __builtin_amdgcn_s_barrier();
#pragma unroll
    for (int ph = 0; ph < 2; ++ph) {
      const int ck = ph * 4 + lk;
      bf16x8 af[4], bfr[4];
#pragma unroll
      for (int f = 0; f < 4; ++f) {
        const int ra = wr * 64 + f * 16 + lr;
        af[f] = *(const bf16x8*)&As[cur][ra * 64 + ((ck ^ (ra & 7)) << 3)];
        const int rb = wc * 64 + f * 16 + lr;
        bfr[f] = *(const bf16x8*)&Bs[cur][rb * 64 + ((ck ^ (rb & 7)) << 3)];
      }
#pragma unroll
      for (int i = 0; i < 4; ++i)
#pragma unroll
        for (int j = 0; j < 4; ++j)
          acc[i][j] = __builtin_amdgcn_mfma_f32_16x16x32_bf16(af[i], bfr[j], acc[i][j], 0, 0, 0);
    }
    __builtin_amdgcn_s_barrier();   // readers done before buf^1 gets overwritten
  }
#pragma unroll
  for (int fi = 0; fi < 4; ++fi)
#pragma unroll
    for (int fj = 0; fj < 4; ++fj) {
      const int o = o0 + wc * 64 + fj * 16 + lr;
      const int kk = o >> 6, ii = o & 63;
      const float bo = bz == 0 ? bias[o] : bias[ii * 16 + kk];
#pragma unroll
      for (int t = 0; t < 4; ++t) {
        const int m = m0 + wr * 64 + fi * 16 + lk * 4 + t;
        const float v = acc[fi][fj][t] + bo;
        const int l = m >> 2, nn = m & 3;
        if (bz <= 1) {
          C[(((size_t)(nn * 16 + kk) * 1024 + l) << 6) + ii] = f2bf(v);
        } else {
          C[(((size_t)(nn * 16 + kk) * 64 + ii) << 10) + l] = f2bf(v);
        }
      }
    }
}

// ---------------------------------------------------------------------------
// Out-projection GEMM v5 (R11-proven, standalone): counted-vmcnt dbuf, vmcnt(6).
__global__ __launch_bounds__(256) void k_gemm_out(
    const unsigned short* __restrict__ A, const unsigned short* __restrict__ B,
    const float* __restrict__ bias, float* __restrict__ C) {
  __shared__ unsigned short As[2][64 * 64];
  __shared__ unsigned short Bs[2][128 * 64];
  const int id = blockIdx.x;                     // 0..511
  const int g  = (id & 7) + ((id >> 6) << 3);    // 0..63 m-block
  const int bx = (id >> 3) & 7;                  // o-block
  const int m0 = g * 64, o0 = bx * 128;
  const int tid = threadIdx.x;
  const int wid = tid >> 6, lane = tid & 63;
  const int wr = wid >> 1, wc = wid & 1;
  const int lr = lane & 15, lk = lane >> 4;
  int srow[4], scol[4];
#pragma unroll
  for (int q = 0; q < 4; ++q) {
    const int idx = q * 256 + tid;
    srow[q] = idx >> 3;
    scol[q] = (((idx & 7) ^ ((idx >> 3) & 7)) << 3);
  }
  f32x4 acc[2][4];
#pragma unroll
  for (int i = 0; i < 2; ++i)
#pragma unroll
    for (int j = 0; j < 4; ++j) acc[i][j] = (f32x4){0.f, 0.f, 0.f, 0.f};

#pragma unroll
  for (int q = 0; q < 2; ++q)
    GLOAD_LDS16(&A[(size_t)(m0 + srow[q]) * 1024 + scol[q]], &As[0][(q * 256 + tid) * 8]);
#pragma unroll
  for (int q = 0; q < 4; ++q)
    GLOAD_LDS16(&B[(size_t)(o0 + srow[q]) * 1024 + scol[q]], &Bs[0][(q * 256 + tid) * 8]);

  for (int t = 0; t < 16; ++t) {
    const int cur = t & 1;
    if (t < 15) {
      const int kb = (t + 1) * 64;
#pragma unroll
      for (int q = 0; q < 2; ++q)
        GLOAD_LDS16(&A[(size_t)(m0 + srow[q]) * 1024 + kb + scol[q]],
                    &As[cur ^ 1][(q * 256 + tid) * 8]);
#pragma unroll
      for (int q = 0; q < 4; ++q)
        GLOAD_LDS16(&B[(size_t)(o0 + srow[q]) * 1024 + kb + scol[q]],
                    &Bs[cur ^ 1][(q * 256 + tid) * 8]);
      asm volatile("s_waitcnt vmcnt(6)" ::: "memory");
    } else {
      asm volatile("s_waitcnt vmcnt(0)" ::: "memory");
    }
    __builtin_amdgcn_s_barrier();
#pragma unroll
    for (int ph = 0; ph < 2; ++ph) {
      const int ck = ph * 4 + lk;
      bf16x8 af[2], bfr[4];
#pragma unroll
      for (int f = 0; f < 2; ++f) {
        const int ra = wr * 32 + f * 16 + lr;
        af[f] = *(const bf16x8*)&As[cur][ra * 64 + ((ck ^ (ra & 7)) << 3)];
      }
#pragma unroll
      for (int f = 0; f < 4; ++f) {
        const int rb = wc * 64 + f * 16 + lr;
        bfr[f] = *(const bf16x8*)&Bs[cur][rb * 64 + ((ck ^ (rb & 7)) << 3)];
      }
#pragma unroll
      for (int i = 0; i < 2; ++i)
#pragma unroll
        for (int j = 0; j < 4; ++j)
          acc[i][j] = __builtin_amdgcn_mfma_f32_16x16x32_bf16(af[i], bfr[j], acc[i][j], 0, 0, 0);
    }
    __builtin_amdgcn_s_barrier();
  }
#pragma unroll
  for (int fi = 0; fi < 2; ++fi)
#pragma unroll
    for (int fj = 0; fj < 4; ++fj) {
      const int o = o0 + wc * 64 + fj * 16 + lr;
      const float bo = bias[o];
#pragma unroll
      for (int t = 0; t < 4; ++t) {
        const int m = m0 + wr * 32 + fi * 16 + lk * 4 + t;
        C[(size_t)m * 1024 + o] = acc[fi][fj][t] + bo;
      }
    }
}

// ---------------------------------------------------------------------------
// MFMA flash v8 (R16-proven, e-domain): l-tile 128, 2 q-groups/wave,
// reg-staged dbuf + __syncthreads, defer-max THR=8, stats=(m, 1/Z).
__global__ __launch_bounds__(256) void k_flash(
    const unsigned short* __restrict__ Qbf, const unsigned short* __restrict__ Khbf,
    const unsigned short* __restrict__ Vtbf, float* __restrict__ stats,
    unsigned short* __restrict__ Obf) {
  __shared__ unsigned short Kd[2][64 * 64];
  __shared__ unsigned short Vd[2][64 * 64];
  __shared__ unsigned short Ps[4][32 * 64];
  const int ob = blockIdx.x;                  // 0..511
  const int b = (ob & 7) * 64 + (ob >> 3);    // bijective XCD swizzle (512%8==0)
  const int lt = b & 7, k = (b >> 3) & 15, n = b >> 7;
  const int l0 = lt * 128;
  const int tid = threadIdx.x, w = tid >> 6, lane = tid & 63;
  const int lr = lane & 15, lk = lane >> 4;
  const size_t hb = (size_t)(n * 16 + k) * 65536;
  bf16x8 qa0[2], qa1[2];
#pragma unroll
  for (int g = 0; g < 2; ++g) {
    const unsigned short* qrow = Qbf + hb + (size_t)(l0 + w * 32 + g * 16 + lr) * 64;
    qa0[g] = *(const bf16x8*)(qrow + lk * 8);
    qa1[g] = *(const bf16x8*)(qrow + 32 + lk * 8);
  }
  const int swz = lr & 7;
  int srow[2], scol[2];
#pragma unroll
  for (int q = 0; q < 2; ++q) {
    const int idx = q * 256 + tid;
    srow[q] = idx >> 3;
    scol[q] = (((idx & 7) ^ ((idx >> 3) & 7)) << 3);
  }
  const unsigned short* Kb = Khbf + hb;
  const unsigned short* Vb = Vtbf + hb;
  int4 kreg[2], vreg[2];
#pragma unroll
  for (int q = 0; q < 2; ++q) {
    kreg[q] = *(const int4*)(Kb + (size_t)srow[q] * 64 + scol[q]);
    vreg[q] = *(const int4*)(Vb + (size_t)srow[q] * 1024 + scol[q]);
  }
#pragma unroll
  for (int q = 0; q < 2; ++q) {
    *(int4*)&Kd[0][(q * 256 + tid) * 8] = kreg[q];
    *(int4*)&Vd[0][(q * 256 + tid) * 8] = vreg[q];
  }
  float m_[2] = {-1e30f, -1e30f}, Z_[2] = {0.f, 0.f};
  f32x4 oacc[2][4];
#pragma unroll
  for (int g = 0; g < 2; ++g)
#pragma unroll
    for (int it = 0; it < 4; ++it) oacc[g][it] = (f32x4){0.f, 0.f, 0.f, 0.f};
  __syncthreads();

  for (int t0 = 0; t0 < 16; ++t0) {
    const int cur = t0 & 1;
    if (t0 < 15) {    // T14: issue next tile's loads to regs before compute
      const int s1 = (t0 + 1) * 64;
#pragma unroll
      for (int q = 0; q < 2; ++q) {
        kreg[q] = *(const int4*)(Kb + (size_t)(s1 + srow[q]) * 64 + scol[q]);
        vreg[q] = *(const int4*)(Vb + (size_t)srow[q] * 1024 + s1 + scol[q]);
      }
    }
    // swapped QK^T for both groups: K-frags read ONCE, feed 2 MFMAs each
    f32x4 sc[2][4];
#pragma unroll
    for (int st = 0; st < 4; ++st) {
      const int r = st * 16 + lr;
      const bf16x8 kb0 = *(const bf16x8*)&Kd[cur][r * 64 + ((lk ^ (r & 7)) << 3)];
      const bf16x8 kb1 = *(const bf16x8*)&Kd[cur][r * 64 + (((4 + lk) ^ (r & 7)) << 3)];
#pragma unroll
      for (int g = 0; g < 2; ++g) {
        f32x4 z = (f32x4){0.f, 0.f, 0.f, 0.f};
        z = __builtin_amdgcn_mfma_f32_16x16x32_bf16(kb0, qa0[g], z, 0, 0, 0);
        sc[g][st] = __builtin_amdgcn_mfma_f32_16x16x32_bf16(kb1, qa1[g], z, 0, 0, 0);
      }
    }
    // two independent online-softmax chains (interleave to hide latency)
    float p[2][4][4];
#pragma unroll
    for (int g = 0; g < 2; ++g) {
      const float a0 = MAX3(sc[g][0][0], sc[g][0][1], sc[g][0][2]);
      const float a1 = MAX3(sc[g][0][3], sc[g][1][0], sc[g][1][1]);
      const float a2 = MAX3(sc[g][1][2], sc[g][1][3], sc[g][2][0]);
      const float a3 = MAX3(sc[g][2][1], sc[g][2][2], sc[g][2][3]);
      const float a4 = MAX3(sc[g][3][0], sc[g][3][1], sc[g][3][2]);
      float tm = fmaxf(MAX3(a0, a1, a2), MAX3(a3, a4, sc[g][3][3]));
      tm = fmaxf(tm, __shfl_xor(tm, 16));
      tm = fmaxf(tm, __shfl_xor(tm, 32));
      float fac = 1.f;
      if (!__all(tm <= m_[g] + 8.f)) {      // defer-max (T13)
        const float mn = fmaxf(m_[g], tm);
        fac = __expf(m_[g] - mn);
        m_[g] = mn;
        const float fr0 = __shfl(fac, lk * 4 + 0);
        const float fr1 = __shfl(fac, lk * 4 + 1);
        const float fr2 = __shfl(fac, lk * 4 + 2);
        const float fr3 = __shfl(fac, lk * 4 + 3);
        const f32x4 facv = {fr0, fr1, fr2, fr3};
#pragma unroll
        for (int it = 0; it < 4; ++it) oacc[g][it] *= facv;
      }
#pragma unroll
      for (int st = 0; st < 4; ++st)
#pragma unroll
        for (int t = 0; t < 4; ++t) p[g][st][t] = __expf(sc[g][st][t] - m_[g]);
      const float r0 = (p[g][0][0] + p[g][0][1]) + (p[g][0][2] + p[g][0][3]);
      const float r1 = (p[g][1][0] + p[g][1][1]) + (p[g][1][2] + p[g][1][3]);
      const float r2 = (p[g][2][0] + p[g][2][1]) + (p[g][2][2] + p[g][2][3]);
      const float r3 = (p[g][3][0] + p[g][3][1]) + (p[g][3][2] + p[g][3][3]);
      float rs = (r0 + r1) + (r2 + r3);
      rs += __shfl_xor(rs, 16);
      rs += __shfl_xor(rs, 32);
      Z_[g] = Z_[g] * fac + rs;
      // P write: rows g*16+lr, 8B-chunk XOR swizzle
#pragma unroll
      for (int st = 0; st < 4; ++st) {
        ushort4 pk;
        pk.x = f2bf(p[g][st][0]); pk.y = f2bf(p[g][st][1]);
        pk.z = f2bf(p[g][st][2]); pk.w = f2bf(p[g][st][3]);
        const int c = (st * 4 + lk) ^ (swz << 1);
        *(ushort4*)&Ps[w][(g * 16 + lr) * 64 + c * 4] = pk;
      }
    }
    // PV: V-frags read ONCE, feed both groups
    bf16x8 pa0[2], pa1[2];
#pragma unroll
    for (int g = 0; g < 2; ++g) {
      pa0[g] = *(const bf16x8*)&Ps[w][(g * 16 + lr) * 64 + ((lk ^ swz) << 3)];
      pa1[g] = *(const bf16x8*)&Ps[w][(g * 16 + lr) * 64 + (((4 + lk) ^ swz) << 3)];
    }
#pragma unroll
    for (int it = 0; it < 4; ++it) {
      const int r = it * 16 + lr;
      const bf16x8 bv0 = *(const bf16x8*)&Vd[cur][r * 64 + ((lk ^ (r & 7)) << 3)];
      const bf16x8 bv1 = *(const bf16x8*)&Vd[cur][r * 64 + (((4 + lk) ^ (r & 7)) << 3)];
#pragma unroll
      for (int g = 0; g < 2; ++g) {
        f32x4 o = oacc[g][it];
        o = __builtin_amdgcn_mfma_f32_16x16x32_bf16(pa0[g], bv0, o, 0, 0, 0);
        oacc[g][it] = __builtin_amdgcn_mfma_f32_16x16x32_bf16(pa1[g], bv1, o, 0, 0, 0);
      }
    }
    // stage next tile into the other buffer, then sync
    if (t0 < 15) {
#pragma unroll
      for (int q = 0; q < 2; ++q) {
        *(int4*)&Kd[cur ^ 1][(q * 256 + tid) * 8] = kreg[q];
        *(int4*)&Vd[cur ^ 1][(q * 256 + tid) * 8] = vreg[q];
      }
    }
    __syncthreads();
  }

#pragma unroll
  for (int g = 0; g < 2; ++g) {
    const float iz = 1.f / Z_[g];
    if (lane < 16) {
      const size_t so = ((size_t)(n * 16 + k) * 1024 + l0 + w * 32 + g * 16 + lr) * 2;
      stats[so] = m_[g];
      stats[so + 1] = iz;    // store inverse: wmap consumes directly
    }
    float izr[4];
#pragma unroll
    for (int t = 0; t < 4; ++t) izr[t] = __shfl(iz, lk * 4 + t);
#pragma unroll
    for (int it = 0; it < 4; ++it)
#pragma unroll
      for (int t = 0; t < 4; ++t) {
        const int l = l0 + w * 32 + g * 16 + lk * 4 + t;
        const int i = it * 16 + lr;
        Obf[(size_t)(l * 4 + n) * 1024 + i * 16 + k] = f2bf(oacc[g][it][t] * izr[t]);
      }
  }
}

// ---------------------------------------------------------------------------
// Wmap v5 (R15/R16-proven, standalone): stats hold (m, 1/Z) -> no rcp;
// reg-prefetch dbuf.
__global__ __launch_bounds__(256) void k_wmap(const unsigned short* __restrict__ Qbf,
    const unsigned short* __restrict__ Khbf, const float* __restrict__ stats,
    float* __restrict__ Wmap) {
  __shared__ unsigned short Kst[2][64 * 64];
  const int ob = blockIdx.x;
  const int b = (ob & 7) * 128 + (ob >> 3);
  const int st = b & 15, lt = (b >> 4) & 15, n = b >> 8;
  const int l0 = lt * 64, s0 = st * 64;
  const int tid = threadIdx.x, w = tid >> 6, lane = tid & 63;
  const int lr = lane & 15, lk = lane >> 4;
  int srow[2], scol[2];
#pragma unroll
  for (int q = 0; q < 2; ++q) {
    const int idx = q * 256 + tid;
    srow[q] = idx >> 3;
    scol[q] = (((idx & 7) ^ ((idx >> 3) & 7)) << 3);
  }
  int4 kreg[2];
#pragma unroll
  for (int q = 0; q < 2; ++q)
    kreg[q] = *(const int4*)(Khbf + (size_t)(n * 16) * 65536 +
                             (size_t)(s0 + srow[q]) * 64 + scol[q]);
#pragma unroll
  for (int q = 0; q < 2; ++q)
    *(int4*)&Kst[0][(q * 256 + tid) * 8] = kreg[q];
  f32x4 wsum[4];
#pragma unroll
  for (int i = 0; i < 4; ++i) wsum[i] = (f32x4){0.f, 0.f, 0.f, 0.f};
  __syncthreads();

  for (int k = 0; k < 16; ++k) {
    const int cur = k & 1;
    const size_t hb = (size_t)(n * 16 + k) * 65536;
    if (k < 15) {
      const size_t hb1 = (size_t)(n * 16 + k + 1) * 65536;
#pragma unroll
      for (int q = 0; q < 2; ++q)
        kreg[q] = *(const int4*)(Khbf + hb1 + (size_t)(s0 + srow[q]) * 64 + scol[q]);
    }
    const unsigned short* qrow = Qbf + hb + (size_t)(l0 + w * 16 + lr) * 64;
    const bf16x8 a0 = *(const bf16x8*)(qrow + lk * 8);
    const bf16x8 a1 = *(const bf16x8*)(qrow + 32 + lk * 8);
    float mv[4], izv[4];
#pragma unroll
    for (int t = 0; t < 4; ++t) {
      const float2 mz = *(const float2*)(stats +
          ((size_t)(n * 16 + k) * 1024 + l0 + w * 16 + lk * 4 + t) * 2);
      mv[t] = mz.x; izv[t] = mz.y;   // already inverse
    }
#pragma unroll
    for (int st2 = 0; st2 < 4; ++st2) {
      const int r = st2 * 16 + lr;
      const bf16x8 kb0 = *(const bf16x8*)&Kst[cur][r * 64 + ((lk ^ (r & 7)) << 3)];
      const bf16x8 kb1 = *(const bf16x8*)&Kst[cur][r * 64 + (((4 + lk) ^ (r & 7)) << 3)];
      f32x4 z = (f32x4){0.f, 0.f, 0.f, 0.f};
      z = __builtin_amdgcn_mfma_f32_16x16x32_bf16(a0, kb0, z, 0, 0, 0);
      z = __builtin_amdgcn_mfma_f32_16x16x32_bf16(a1, kb1, z, 0, 0, 0);
#pragma unroll
      for (int t = 0; t < 4; ++t)
        wsum[st2][t] += __expf(z[t] - mv[t]) * izv[t];
    }
    if (k < 15) {
#pragma unroll
      for (int q = 0; q < 2; ++q)
        *(int4*)&Kst[cur ^ 1][(q * 256 + tid) * 8] = kreg[q];
    }
    __syncthreads();
  }
#pragma unroll
  for (int st2 = 0; st2 < 4; ++st2)
#pragma unroll
    for (int t = 0; t < 4; ++t) {
      const int l = l0 + w * 16 + lk * 4 + t;
      const int s = s0 + st2 * 16 + lr;
      Wmap[((size_t)l * 1024 + s) * 4 + n] = wsum[st2][t] * 0.0625f;
    }
}

// ---------------------------------------------------------------------------
extern "C" void kernel_launch(void* const* d_in, const int* in_sizes, int n_in,
                              void* d_out, int out_size, void* d_ws, size_t ws_size,
                              hipStream_t stream) {
  (void)in_sizes; (void)n_in; (void)out_size; (void)ws_size;
  const float* Q        = (const float*)d_in[0];
  const float* K        = (const float*)d_in[1];
  const float* V        = (const float*)d_in[2];
  const float* q_w      = (const float*)d_in[3];
  const float* k_w      = (const float*)d_in[4];
  const float* v_w      = (const float*)d_in[5];
  const float* out_w    = (const float*)d_in[6];
  const float* in_bias  = (const float*)d_in[7];
  const float* out_bias = (const float*)d_in[8];
  const float* attn_W   = (const float*)d_in[9];
  float* ws = (float*)d_ws;
  unsigned short* qw2bf = (unsigned short*)(ws + OFF_QW2BF);
  unsigned short* kwbf  = (unsigned short*)(ws + OFF_KWBF);
  unsigned short* vwbf  = (unsigned short*)(ws + OFF_VWBF);
  unsigned short* owtbf = (unsigned short*)(ws + OFF_OWTBF);
  float* qb2 = ws + OFF_QB2;
  unsigned short* Qwbf = (unsigned short*)(ws + OFF_QWBF);
  unsigned short* Khbf = (unsigned short*)(ws + OFF_KHBF);
  unsigned short* Vtbf = (unsigned short*)(ws + OFF_VTBF);
  float* st = ws + OFF_ST;
  unsigned short* Obf  = (unsigned short*)(ws + OFF_OBF);
  unsigned short* Abf  = (unsigned short*)(ws + OFF_ABF);
  float* out  = (float*)d_out;
  float* Wmap = out + 4194304;

  k_prep<<<5376, 256, 0, stream>>>(Q, K, V, q_w, k_w, v_w, out_w, attn_W,
                                   in_bias, qw2bf, qb2, kwbf, vwbf, owtbf, Abf);
  k_gemm_in<<<768, 256, 0, stream>>>(Abf, qw2bf, kwbf, vwbf,
                                     qb2, in_bias + 1024, in_bias + 2048,
                                     Qwbf, Khbf, Vtbf);
  k_flash<<<512, 256, 0, stream>>>(Qwbf, Khbf, Vtbf, st, Obf);
  k_wmap<<<1024, 256, 0, stream>>>(Qwbf, Khbf, st, Wmap);
  k_gemm_out<<<512, 256, 0, stream>>>(Obf, owtbf, out_bias, out);
}